// Round 1
// baseline (2938.126 us; speedup 1.0000x reference)
//
#include <hip/hip_runtime.h>
#include <math.h>

#define B_     512
#define M_     196
#define N_     77
#define FEAT_  512
#define NCLS_  632
#define TDIM_  768
#define LDIM_  576
#define LS_EPS_ 0.1f
#define MARGIN_ 0.3f
#define BN_EPS_ 1e-5f
#define SINK_ITERS 40

// ---------------- generic tiled GEMM: C[M,N] = A[M,K] @ W[N,K]^T (+bias) ----
template<int BM, int BN, int BK, int TM, int TN>
__global__ __launch_bounds__(256) void gemm_nt(const float* __restrict__ A,
                                               const float* __restrict__ W,
                                               const float* __restrict__ bias,
                                               float* __restrict__ C,
                                               int M, int N, int K) {
  __shared__ float As[BM][BK + 1];
  __shared__ float Ws[BN][BK + 1];
  const int tid = threadIdx.x;
  const int tx = tid & 15, ty = tid >> 4;
  const int row0 = blockIdx.y * BM;
  const int col0 = blockIdx.x * BN;
  float acc[TM][TN];
#pragma unroll
  for (int i = 0; i < TM; ++i)
#pragma unroll
    for (int j = 0; j < TN; ++j) acc[i][j] = 0.f;

  for (int k0 = 0; k0 < K; k0 += BK) {
#pragma unroll
    for (int e = tid; e < BM * BK; e += 256) {
      int r = e / BK, c = e % BK;
      int gr = row0 + r, gc = k0 + c;
      As[r][c] = (gr < M && gc < K) ? A[(size_t)gr * K + gc] : 0.f;
    }
#pragma unroll
    for (int e = tid; e < BN * BK; e += 256) {
      int r = e / BK, c = e % BK;
      int gr = col0 + r, gc = k0 + c;
      Ws[r][c] = (gr < N && gc < K) ? W[(size_t)gr * K + gc] : 0.f;
    }
    __syncthreads();
#pragma unroll
    for (int kk = 0; kk < BK; ++kk) {
      float a[TM], w[TN];
#pragma unroll
      for (int i = 0; i < TM; ++i) a[i] = As[ty * TM + i][kk];
#pragma unroll
      for (int j = 0; j < TN; ++j) w[j] = Ws[tx * TN + j][kk];
#pragma unroll
      for (int i = 0; i < TM; ++i)
#pragma unroll
        for (int j = 0; j < TN; ++j) acc[i][j] += a[i] * w[j];
    }
    __syncthreads();
  }
#pragma unroll
  for (int i = 0; i < TM; ++i) {
    int gr = row0 + ty * TM + i;
    if (gr >= M) continue;
#pragma unroll
    for (int j = 0; j < TN; ++j) {
      int gc = col0 + tx * TN + j;
      if (gc >= N) continue;
      float v = acc[i][j];
      if (bias) v += bias[gc];
      C[(size_t)gr * N + gc] = v;
    }
  }
}

// ---------------- batchnorm (train) over axis 0, one block per feature -----
__global__ __launch_bounds__(256) void bn_kernel(const float* __restrict__ X,
                                                 float* __restrict__ Y,
                                                 const float* __restrict__ g,
                                                 const float* __restrict__ b) {
  const int j = blockIdx.x;
  const int tid = threadIdx.x;
  __shared__ float sf[256];
  float vals[2];
  float s = 0.f, s2 = 0.f;
  int idx = 0;
  for (int i = tid; i < B_; i += 256, ++idx) {
    float v = X[(size_t)i * FEAT_ + j];
    vals[idx] = v;
    s += v; s2 += v * v;
  }
  sf[tid] = s; __syncthreads();
  for (int k = 128; k > 0; k >>= 1) { if (tid < k) sf[tid] += sf[tid + k]; __syncthreads(); }
  float mu = sf[0] * (1.f / B_); __syncthreads();
  sf[tid] = s2; __syncthreads();
  for (int k = 128; k > 0; k >>= 1) { if (tid < k) sf[tid] += sf[tid + k]; __syncthreads(); }
  float var = sf[0] * (1.f / B_) - mu * mu;
  float scale = rsqrtf(var + BN_EPS_) * g[j];
  float shift = b[j];
  idx = 0;
  for (int i = tid; i < B_; i += 256, ++idx)
    Y[(size_t)i * FEAT_ + j] = (vals[idx] - mu) * scale + shift;
}

// ---------------- CE with label smoothing (+ optional argmax preds) --------
__global__ __launch_bounds__(256) void ce_kernel(const float* __restrict__ logits,
                                                 const int* __restrict__ label,
                                                 float* __restrict__ acc,
                                                 float* __restrict__ preds) {
  const int row = blockIdx.x;
  const int tid = threadIdx.x;
  const float* x = logits + (size_t)row * NCLS_;
  __shared__ float sf[256];
  __shared__ int si[256];
  float mx = -INFINITY; int ai = NCLS_;
  float sumx = 0.f;
  for (int j = tid; j < NCLS_; j += 256) {
    float v = x[j];
    sumx += v;
    if (v > mx) { mx = v; ai = j; }
  }
  sf[tid] = mx; si[tid] = ai; __syncthreads();
  for (int k = 128; k > 0; k >>= 1) {
    if (tid < k) {
      float om = sf[tid + k]; int oi = si[tid + k];
      if (om > sf[tid] || (om == sf[tid] && oi < si[tid])) { sf[tid] = om; si[tid] = oi; }
    }
    __syncthreads();
  }
  float Mx = sf[0]; int amax = si[0]; __syncthreads();
  sf[tid] = sumx; __syncthreads();
  for (int k = 128; k > 0; k >>= 1) { if (tid < k) sf[tid] += sf[tid + k]; __syncthreads(); }
  float SX = sf[0]; __syncthreads();
  float se = 0.f;
  for (int j = tid; j < NCLS_; j += 256) se += expf(x[j] - Mx);
  sf[tid] = se; __syncthreads();
  for (int k = 128; k > 0; k >>= 1) { if (tid < k) sf[tid] += sf[tid + k]; __syncthreads(); }
  float lse = Mx + logf(sf[0]);
  if (tid == 0) {
    float xl = x[label[row]];
    float loss = -((1.f - LS_EPS_) * (xl - lse) + (LS_EPS_ / NCLS_) * (SX - NCLS_ * lse));
    atomicAdd(acc, loss * (1.f / B_));
    if (preds) preds[row] = (float)amax;
  }
}

// ---------------- triplet hard mining from Gram matrix ---------------------
__global__ __launch_bounds__(256) void triplet_kernel(const float* __restrict__ G,
                                                      const int* __restrict__ label,
                                                      float* __restrict__ acc) {
  const int i = blockIdx.x;
  const int tid = threadIdx.x;
  const int li = label[i];
  __shared__ float sap[256], san[256];
  const float sqi = G[(size_t)i * B_ + i];
  float ap = -INFINITY, an = INFINITY;
  for (int j = tid; j < B_; j += 256) {
    float sqj = G[(size_t)j * B_ + j];
    float d2 = sqi + sqj - 2.f * G[(size_t)i * B_ + j];
    float d = sqrtf(fmaxf(d2, 1e-12f));
    if (label[j] == li) ap = fmaxf(ap, d); else an = fminf(an, d);
  }
  sap[tid] = ap; san[tid] = an; __syncthreads();
  for (int k = 128; k > 0; k >>= 1) {
    if (tid < k) {
      sap[tid] = fmaxf(sap[tid], sap[tid + k]);
      san[tid] = fminf(san[tid], san[tid + k]);
    }
    __syncthreads();
  }
  if (tid == 0) atomicAdd(acc, fmaxf(sap[0] - san[0] + MARGIN_, 0.f) * (1.f / B_));
}

// ---------------- KL distillation (batchmean, T=2) -------------------------
__global__ __launch_bounds__(256) void kl_kernel(const float* __restrict__ TL,
                                                 const float* __restrict__ SL,
                                                 float* __restrict__ acc) {
  const int row = blockIdx.x;
  const int tid = threadIdx.x;
  const float* t = TL + (size_t)row * NCLS_;
  const float* s = SL + (size_t)row * NCLS_;
  __shared__ float sf[256];
  float mt = -INFINITY, ms = -INFINITY;
  for (int j = tid; j < NCLS_; j += 256) {
    mt = fmaxf(mt, t[j] * 0.5f);
    ms = fmaxf(ms, s[j] * 0.5f);
  }
  sf[tid] = mt; __syncthreads();
  for (int k = 128; k > 0; k >>= 1) { if (tid < k) sf[tid] = fmaxf(sf[tid], sf[tid + k]); __syncthreads(); }
  mt = sf[0]; __syncthreads();
  sf[tid] = ms; __syncthreads();
  for (int k = 128; k > 0; k >>= 1) { if (tid < k) sf[tid] = fmaxf(sf[tid], sf[tid + k]); __syncthreads(); }
  ms = sf[0]; __syncthreads();
  float set = 0.f, ses = 0.f;
  for (int j = tid; j < NCLS_; j += 256) {
    set += expf(t[j] * 0.5f - mt);
    ses += expf(s[j] * 0.5f - ms);
  }
  sf[tid] = set; __syncthreads();
  for (int k = 128; k > 0; k >>= 1) { if (tid < k) sf[tid] += sf[tid + k]; __syncthreads(); }
  set = sf[0]; __syncthreads();
  sf[tid] = ses; __syncthreads();
  for (int k = 128; k > 0; k >>= 1) { if (tid < k) sf[tid] += sf[tid + k]; __syncthreads(); }
  ses = sf[0]; __syncthreads();
  float lt = mt + logf(set), ls = ms + logf(ses);
  float part = 0.f;
  for (int j = tid; j < NCLS_; j += 256) {
    float tlp = t[j] * 0.5f - lt;
    float slp = s[j] * 0.5f - ls;
    part += expf(tlp) * (tlp - slp);
  }
  sf[tid] = part; __syncthreads();
  for (int k = 128; k > 0; k >>= 1) { if (tid < k) sf[tid] += sf[tid + k]; __syncthreads(); }
  if (tid == 0) atomicAdd(acc, sf[0] * (1.f / B_));
}

// ---------------- per-row inverse L2 norm (wave per row) -------------------
__global__ __launch_bounds__(256) void invnorm_rows(const float* __restrict__ X,
                                                    float* __restrict__ out,
                                                    int nrows, int D) {
  const int lane = threadIdx.x & 63;
  const int wv = threadIdx.x >> 6;
  const int row = blockIdx.x * 4 + wv;
  if (row >= nrows) return;
  const float* x = X + (size_t)row * D;
  float s = 0.f;
  for (int i = lane; i < D; i += 64) { float v = x[i]; s += v * v; }
#pragma unroll
  for (int off = 32; off > 0; off >>= 1) s += __shfl_down(s, off);
  if (lane == 0) out[row] = 1.f / fmaxf(sqrtf(s), 1e-12f);
}

// ---------------- batched cosine sim: sim[b,m,n] ---------------------------
__global__ __launch_bounds__(256) void sim_kernel(const float* __restrict__ S,
                                                  const float* __restrict__ T,
                                                  const float* __restrict__ sinv,
                                                  const float* __restrict__ tinv,
                                                  float* __restrict__ sim) {
  const int b = blockIdx.z;
  const int m0 = blockIdx.y * 32;
  const int n0 = blockIdx.x * 32;
  __shared__ float As[32][33], Bs[32][33];
  const int tid = threadIdx.x;
  const int tx = tid & 15, ty = tid >> 4;
  float acc00 = 0.f, acc01 = 0.f, acc10 = 0.f, acc11 = 0.f;
  const float* Sb = S + (size_t)b * M_ * LDIM_;
  const float* Tb = T + (size_t)b * N_ * LDIM_;
  for (int k0 = 0; k0 < LDIM_; k0 += 32) {
#pragma unroll
    for (int e = tid; e < 32 * 32; e += 256) {
      int r = e >> 5, c = e & 31;
      int gm = m0 + r;
      As[r][c] = (gm < M_) ? Sb[(size_t)gm * LDIM_ + k0 + c] : 0.f;
      int gn = n0 + r;
      Bs[r][c] = (gn < N_) ? Tb[(size_t)gn * LDIM_ + k0 + c] : 0.f;
    }
    __syncthreads();
#pragma unroll
    for (int kk = 0; kk < 32; ++kk) {
      float a0 = As[ty * 2][kk], a1 = As[ty * 2 + 1][kk];
      float b0 = Bs[tx * 2][kk], b1 = Bs[tx * 2 + 1][kk];
      acc00 += a0 * b0; acc01 += a0 * b1; acc10 += a1 * b0; acc11 += a1 * b1;
    }
    __syncthreads();
  }
  float accs[2][2] = {{acc00, acc01}, {acc10, acc11}};
#pragma unroll
  for (int i = 0; i < 2; ++i) {
    int gm = m0 + ty * 2 + i;
    if (gm >= M_) continue;
    float si = sinv[b * M_ + gm];
#pragma unroll
    for (int j = 0; j < 2; ++j) {
      int gn = n0 + tx * 2 + j;
      if (gn >= N_) continue;
      sim[((size_t)b * M_ + gm) * N_ + gn] = accs[i][j] * si * tinv[b * N_ + gn];
    }
  }
}

// ---------------- per-batch Sinkhorn in LDS + sim_op -----------------------
__global__ __launch_bounds__(256) void sinkhorn_kernel(const float* __restrict__ sim,
                                                       float* __restrict__ acc) {
  const int b = blockIdx.x;
  const int tid = threadIdx.x;
  __shared__ float Ks[M_ * N_];  // 60368 B
  __shared__ float r[M_];
  __shared__ float c[N_];
  __shared__ float sf[256];
  const float* simb = sim + (size_t)b * M_ * N_;
  for (int e = tid; e < M_ * N_; e += 256)
    Ks[e] = __expf((simb[e] - 1.f) * 10.f);  // exp(-(1-sim)/0.1)
  if (tid < N_) c[tid] = 1.f;
  __syncthreads();
  const float u = 1.f / M_, v = 1.f / N_;
  for (int it = 0; it < SINK_ITERS; ++it) {
    for (int m = tid; m < M_; m += 256) {
      const float* Km = Ks + m * N_;
      float s = 0.f;
      for (int n = 0; n < N_; ++n) s += Km[n] * c[n];
      r[m] = u / s;
    }
    __syncthreads();
    for (int n = tid; n < N_; n += 256) {
      float s = 0.f;
      for (int m = 0; m < M_; ++m) s += Ks[m * N_ + n] * r[m];
      c[n] = v / s;
    }
    __syncthreads();
  }
  float part = 0.f;
  for (int e = tid; e < M_ * N_; e += 256) {
    int m = e / N_, n = e % N_;
    part += r[m] * c[n] * Ks[e] * simb[e];
  }
  sf[tid] = part; __syncthreads();
  for (int k = 128; k > 0; k >>= 1) { if (tid < k) sf[tid] += sf[tid + k]; __syncthreads(); }
  if (tid == 0) atomicAdd(acc, sf[0] * (1.f / B_));
}

// ---------------- small utils ----------------------------------------------
__global__ void zero_kernel(float* p, int n) {
  int i = blockIdx.x * blockDim.x + threadIdx.x;
  if (i < n) p[i] = 0.f;
}

__global__ void finalize_kernel(const float* __restrict__ acc, float* __restrict__ out) {
  if (threadIdx.x == 0)
    out[0] = acc[0] + acc[1] + acc[2] + acc[3] + acc[4] + (1.f - acc[5]);
}

// ---------------------------------------------------------------------------
extern "C" void kernel_launch(void* const* d_in, const int* in_sizes, int n_in,
                              void* d_out, int out_size, void* d_ws, size_t ws_size,
                              hipStream_t stream) {
  const float* text_feat  = (const float*)d_in[0];
  const float* t_img_raw  = (const float*)d_in[1];
  const float* s_glob_raw = (const float*)d_in[2];
  const float* s_local    = (const float*)d_in[3];
  const int*   label      = (const int*)d_in[4];
  const float* W_tv = (const float*)d_in[5];
  const float* b_tv = (const float*)d_in[6];
  const float* W_tt = (const float*)d_in[7];
  const float* b_tt = (const float*)d_in[8];
  const float* W_sv = (const float*)d_in[9];
  const float* b_sv = (const float*)d_in[10];
  const float* bn_g = (const float*)d_in[11];
  const float* bn_b = (const float*)d_in[12];
  const float* W_ct = (const float*)d_in[13];
  const float* b_ct = (const float*)d_in[14];
  const float* W_cs = (const float*)d_in[15];
  const float* b_cs = (const float*)d_in[16];
  float* out = (float*)d_out;
  float* ws = (float*)d_ws;

  // workspace layout (floats)
  float* tlin   = ws;                       // 512*512
  float* timg   = tlin + 262144;            // 512*512
  float* sglob  = timg + 262144;            // 512*512
  float* tlog   = sglob + 262144;           // 512*632
  float* slog   = tlog + 323584;            // 512*632
  float* gram_t = slog + 323584;            // 512*512
  float* gram_s = gram_t + 262144;          // 512*512
  float* sinv   = gram_s + 262144;          // 512*196
  float* tinv   = sinv + 100352;            // 512*77
  float* acc    = tinv + 39424;             // 8
  float* ttext  = acc + 8;                  // 512*77*576
  float* sim    = ttext + 22708224;         // 512*196*77
  // total ≈ 130 MB

  dim3 blk(256);
  zero_kernel<<<1, 64, 0, stream>>>(acc, 8);

  // teacher image: linear + BN
  gemm_nt<64, 64, 32, 4, 4><<<dim3(8, 8), blk, 0, stream>>>(t_img_raw, W_tv, b_tv, tlin, 512, FEAT_, TDIM_);
  bn_kernel<<<FEAT_, blk, 0, stream>>>(tlin, timg, bn_g, bn_b);
  // student global linear
  gemm_nt<64, 64, 32, 4, 4><<<dim3(8, 8), blk, 0, stream>>>(s_glob_raw, W_sv, b_sv, sglob, 512, FEAT_, LDIM_);
  // classifier logits
  gemm_nt<64, 64, 32, 4, 4><<<dim3(10, 8), blk, 0, stream>>>(timg, W_ct, b_ct, tlog, 512, NCLS_, FEAT_);
  gemm_nt<64, 64, 32, 4, 4><<<dim3(10, 8), blk, 0, stream>>>(sglob, W_cs, b_cs, slog, 512, NCLS_, FEAT_);
  // CE losses (+ student preds)
  ce_kernel<<<B_, blk, 0, stream>>>(tlog, label, acc + 0, nullptr);
  ce_kernel<<<B_, blk, 0, stream>>>(slog, label, acc + 2, out + 1);
  // Gram matrices for triplet
  gemm_nt<64, 64, 32, 4, 4><<<dim3(8, 8), blk, 0, stream>>>(timg, timg, nullptr, gram_t, 512, 512, FEAT_);
  gemm_nt<64, 64, 32, 4, 4><<<dim3(8, 8), blk, 0, stream>>>(sglob, sglob, nullptr, gram_s, 512, 512, FEAT_);
  triplet_kernel<<<B_, blk, 0, stream>>>(gram_t, label, acc + 1);
  triplet_kernel<<<B_, blk, 0, stream>>>(gram_s, label, acc + 3);
  // KL distillation
  kl_kernel<<<B_, blk, 0, stream>>>(tlog, slog, acc + 4);
  // teacher text features (big GEMM): (512*77, 768) @ (576, 768)^T
  gemm_nt<64, 64, 32, 4, 4><<<dim3(9, 616), blk, 0, stream>>>(text_feat, W_tt, b_tt, ttext, B_ * N_, LDIM_, TDIM_);
  // inverse norms
  invnorm_rows<<<(B_ * M_ + 3) / 4, blk, 0, stream>>>(s_local, sinv, B_ * M_, LDIM_);
  invnorm_rows<<<(B_ * N_ + 3) / 4, blk, 0, stream>>>(ttext, tinv, B_ * N_, LDIM_);
  // batched cosine sim
  sim_kernel<<<dim3(3, 7, B_), blk, 0, stream>>>(s_local, ttext, sinv, tinv, sim);
  // sinkhorn + OT loss
  sinkhorn_kernel<<<B_, blk, 0, stream>>>(sim, acc + 5);
  // combine
  finalize_kernel<<<1, 1, 0, stream>>>(acc, out);
}

// Round 2
// 1265.136 us; speedup vs baseline: 2.3224x; 2.3224x over previous
//
#include <hip/hip_runtime.h>
#include <math.h>

#define B_     512
#define M_     196
#define N_     77
#define FEAT_  512
#define NCLS_  632
#define TDIM_  768
#define LDIM_  576
#define LS_EPS_ 0.1f
#define MARGIN_ 0.3f
#define BN_EPS_ 1e-5f
#define SINK_ITERS 40

typedef float fx4 __attribute__((ext_vector_type(4)));
typedef float fx8 __attribute__((ext_vector_type(8)));
typedef short sx8 __attribute__((ext_vector_type(8)));
typedef __bf16 bfx8 __attribute__((ext_vector_type(8)));

__device__ inline ushort f2bf(float f) {
  union { float f; uint u; } v; v.f = f;
  uint u = v.u;
  return (ushort)((u + 0x7FFFu + ((u >> 16) & 1u)) >> 16);
}
__device__ inline float bf2f(ushort b) {
  union { uint u; float f; } v; v.u = ((uint)b) << 16;
  return v.f;
}
__device__ inline sx8 cvt8(fx8 f) {
  sx8 u;
#pragma unroll
  for (int j = 0; j < 8; ++j) u[j] = (short)f2bf(f[j]);
  return u;
}
__device__ inline sx8 cvt8s(fx8 f, float s) {
  sx8 u;
#pragma unroll
  for (int j = 0; j < 8; ++j) u[j] = (short)f2bf(f[j] * s);
  return u;
}
__device__ inline fx4 mfma16(sx8 a, sx8 b, fx4 c) {
  return __builtin_amdgcn_mfma_f32_16x16x32_bf16(
      __builtin_bit_cast(bfx8, a), __builtin_bit_cast(bfx8, b), c, 0, 0, 0);
}

// ============ big GEMM: ttext = text_feat @ W_tt^T + b_tt, bf16 out =========
// A[M,768] f32, W[576,768] f32 -> C[M,576] bf16.  128x128 tile, BK=32.
__global__ __launch_bounds__(256) void gemm_ttext_mfma(const float* __restrict__ A,
                                                       const float* __restrict__ W,
                                                       const float* __restrict__ bias,
                                                       ushort* __restrict__ C) {
  __shared__ __align__(16) ushort ldsA[4096];  // 8 m-tiles * 64 lanes * 8 bf16
  __shared__ __align__(16) ushort ldsB[4096];
  const int tid = threadIdx.x;
  const int lane = tid & 63;
  const int w = tid >> 6;
  const int wr = w >> 1, wc = w & 1;
  const int row0 = blockIdx.y * 128;
  const int col0 = blockIdx.x * 128;
  const int l16 = lane & 15;
  const int ks = (lane >> 4) * 8;

  // staging sources: chunk tid -> tile (tid>>6), chunk tid+256 -> tile +4
  const int arow = row0 + ((tid >> 6) << 4) + l16;        // always < M
  const float* pA0 = A + (size_t)arow * TDIM_ + ks;
  const float* pA1 = pA0 + (size_t)64 * TDIM_;
  int nrow = col0 + ((tid >> 6) << 4) + l16;
  int nb0 = nrow < 576 ? nrow : 575;
  int nb1 = (nrow + 64) < 576 ? (nrow + 64) : 575;
  const float* pB0 = W + (size_t)nb0 * TDIM_ + ks;
  const float* pB1 = W + (size_t)nb1 * TDIM_ + ks;
  const int wo = tid * 8;

  fx4 acc[4][4];
  const fx4 zz = {0.f, 0.f, 0.f, 0.f};
#pragma unroll
  for (int i = 0; i < 4; ++i)
#pragma unroll
    for (int j = 0; j < 4; ++j) acc[i][j] = zz;

  fx8 fa0 = *(const fx8*)pA0, fa1 = *(const fx8*)pA1;
  fx8 fb0 = *(const fx8*)pB0, fb1 = *(const fx8*)pB1;
  sx8 ua0 = cvt8(fa0), ua1 = cvt8(fa1), ub0 = cvt8(fb0), ub1 = cvt8(fb1);

  for (int kt = 0; kt < 24; ++kt) {
    if (kt) __syncthreads();
    *(sx8*)&ldsA[wo] = ua0; *(sx8*)&ldsA[wo + 2048] = ua1;
    *(sx8*)&ldsB[wo] = ub0; *(sx8*)&ldsB[wo + 2048] = ub1;
    __syncthreads();
    if (kt < 23) {
      int off = (kt + 1) * 32;
      fa0 = *(const fx8*)(pA0 + off); fa1 = *(const fx8*)(pA1 + off);
      fb0 = *(const fx8*)(pB0 + off); fb1 = *(const fx8*)(pB1 + off);
    }
    sx8 af[4], bf[4];
#pragma unroll
    for (int mi = 0; mi < 4; ++mi) af[mi] = *(sx8*)&ldsA[(((wr * 4 + mi) << 6) + lane) * 8];
#pragma unroll
    for (int ni = 0; ni < 4; ++ni) bf[ni] = *(sx8*)&ldsB[(((wc * 4 + ni) << 6) + lane) * 8];
#pragma unroll
    for (int mi = 0; mi < 4; ++mi)
#pragma unroll
      for (int ni = 0; ni < 4; ++ni) acc[mi][ni] = mfma16(af[mi], bf[ni], acc[mi][ni]);
    if (kt < 23) { ua0 = cvt8(fa0); ua1 = cvt8(fa1); ub0 = cvt8(fb0); ub1 = cvt8(fb1); }
  }

#pragma unroll
  for (int mi = 0; mi < 4; ++mi) {
    int rbase = row0 + wr * 64 + mi * 16 + ((lane >> 4) << 2);
#pragma unroll
    for (int ni = 0; ni < 4; ++ni) {
      int col = col0 + wc * 64 + ni * 16 + l16;
      if (col < 576) {
        float bv = bias[col];
#pragma unroll
        for (int r = 0; r < 4; ++r)
          C[(size_t)(rbase + r) * 576 + col] = f2bf(acc[mi][ni][r] + bv);
      }
    }
  }
}

// ============ batched cosine sim via MFMA: one block per batch ==============
// S f32 [B,196,576] (unnormalized; sinv applied in staging), T bf16 [B,77,576]
__global__ __launch_bounds__(256) void sim_mfma(const float* __restrict__ S,
                                                const ushort* __restrict__ T,
                                                const float* __restrict__ sinv,
                                                const float* __restrict__ tinv,
                                                float* __restrict__ sim) {
  __shared__ __align__(16) ushort lds[9216];  // A: 832 chunks, B: 320 chunks, *8 ush
  const int b = blockIdx.x;
  const int tid = threadIdx.x;
  const int lane = tid & 63;
  const int w = tid >> 6;
  const int l16 = lane & 15;
  fx4 acc[4][5];
  const fx4 zz = {0.f, 0.f, 0.f, 0.f};
#pragma unroll
  for (int i = 0; i < 4; ++i)
#pragma unroll
    for (int j = 0; j < 5; ++j) acc[i][j] = zz;
  const float* Sb = S + (size_t)b * M_ * LDIM_;
  const ushort* Tb = T + (size_t)b * N_ * LDIM_;

  for (int kt = 0; kt < 18; ++kt) {
    const int k0 = kt * 32;
    if (kt) __syncthreads();
    for (int c = tid; c < 1152; c += 256) {
      if (c < 832) {
        int tile = c >> 6, cl = c & 63;
        int r = tile * 16 + (cl & 15);
        int ks = ((cl >> 4) & 3) * 8;
        int rr = r < 196 ? r : 195;
        fx8 f = *(const fx8*)(Sb + (size_t)rr * LDIM_ + k0 + ks);
        *(sx8*)&lds[c * 8] = cvt8s(f, sinv[b * M_ + rr]);
      } else {
        int cc = c - 832;
        int tile = cc >> 6, cl = cc & 63;
        int r = tile * 16 + (cl & 15);
        int ks = ((cl >> 4) & 3) * 8;
        int rr = r < 77 ? r : 76;
        *(sx8*)&lds[c * 8] = *(const sx8*)(Tb + (size_t)rr * LDIM_ + k0 + ks);
      }
    }
    __syncthreads();
    sx8 bfr[5];
#pragma unroll
    for (int ni = 0; ni < 5; ++ni) bfr[ni] = *(sx8*)&lds[(832 + ni * 64 + lane) * 8];
#pragma unroll
    for (int mi = 0; mi < 4; ++mi) {
      int mt = w + mi * 4;
      if (mt < 13) {
        sx8 af = *(sx8*)&lds[(mt * 64 + lane) * 8];
#pragma unroll
        for (int ni = 0; ni < 5; ++ni) acc[mi][ni] = mfma16(af, bfr[ni], acc[mi][ni]);
      }
    }
  }
#pragma unroll
  for (int mi = 0; mi < 4; ++mi) {
    int mt = w + mi * 4;
    if (mt >= 13) continue;
    int rbase = mt * 16 + ((lane >> 4) << 2);
#pragma unroll
    for (int ni = 0; ni < 5; ++ni) {
      int col = ni * 16 + l16;
      if (col < 77) {
        float tv = tinv[b * N_ + col];
#pragma unroll
        for (int r = 0; r < 4; ++r) {
          int row = rbase + r;
          if (row < 196) sim[((size_t)b * M_ + row) * N_ + col] = acc[mi][ni][r] * tv;
        }
      }
    }
  }
}

// ---------------- generic tiled GEMM: C[M,N] = A[M,K] @ W[N,K]^T (+bias) ----
template<int BM, int BN, int BK, int TM, int TN>
__global__ __launch_bounds__(256) void gemm_nt(const float* __restrict__ A,
                                               const float* __restrict__ W,
                                               const float* __restrict__ bias,
                                               float* __restrict__ C,
                                               int M, int N, int K) {
  __shared__ float As[BM][BK + 1];
  __shared__ float Ws[BN][BK + 1];
  const int tid = threadIdx.x;
  const int tx = tid & 15, ty = tid >> 4;
  const int row0 = blockIdx.y * BM;
  const int col0 = blockIdx.x * BN;
  float acc[TM][TN];
#pragma unroll
  for (int i = 0; i < TM; ++i)
#pragma unroll
    for (int j = 0; j < TN; ++j) acc[i][j] = 0.f;

  for (int k0 = 0; k0 < K; k0 += BK) {
#pragma unroll
    for (int e = tid; e < BM * BK; e += 256) {
      int r = e / BK, c = e % BK;
      int gr = row0 + r, gc = k0 + c;
      As[r][c] = (gr < M && gc < K) ? A[(size_t)gr * K + gc] : 0.f;
    }
#pragma unroll
    for (int e = tid; e < BN * BK; e += 256) {
      int r = e / BK, c = e % BK;
      int gr = col0 + r, gc = k0 + c;
      Ws[r][c] = (gr < N && gc < K) ? W[(size_t)gr * K + gc] : 0.f;
    }
    __syncthreads();
#pragma unroll
    for (int kk = 0; kk < BK; ++kk) {
      float a[TM], wv[TN];
#pragma unroll
      for (int i = 0; i < TM; ++i) a[i] = As[ty * TM + i][kk];
#pragma unroll
      for (int j = 0; j < TN; ++j) wv[j] = Ws[tx * TN + j][kk];
#pragma unroll
      for (int i = 0; i < TM; ++i)
#pragma unroll
        for (int j = 0; j < TN; ++j) acc[i][j] += a[i] * wv[j];
    }
    __syncthreads();
  }
#pragma unroll
  for (int i = 0; i < TM; ++i) {
    int gr = row0 + ty * TM + i;
    if (gr >= M) continue;
#pragma unroll
    for (int j = 0; j < TN; ++j) {
      int gc = col0 + tx * TN + j;
      if (gc >= N) continue;
      float v = acc[i][j];
      if (bias) v += bias[gc];
      C[(size_t)gr * N + gc] = v;
    }
  }
}

// ---------------- batchnorm (train) over axis 0, one block per feature -----
__global__ __launch_bounds__(256) void bn_kernel(const float* __restrict__ X,
                                                 float* __restrict__ Y,
                                                 const float* __restrict__ g,
                                                 const float* __restrict__ b) {
  const int j = blockIdx.x;
  const int tid = threadIdx.x;
  __shared__ float sf[256];
  float vals[2];
  float s = 0.f, s2 = 0.f;
  int idx = 0;
  for (int i = tid; i < B_; i += 256, ++idx) {
    float v = X[(size_t)i * FEAT_ + j];
    vals[idx] = v;
    s += v; s2 += v * v;
  }
  sf[tid] = s; __syncthreads();
  for (int k = 128; k > 0; k >>= 1) { if (tid < k) sf[tid] += sf[tid + k]; __syncthreads(); }
  float mu = sf[0] * (1.f / B_); __syncthreads();
  sf[tid] = s2; __syncthreads();
  for (int k = 128; k > 0; k >>= 1) { if (tid < k) sf[tid] += sf[tid + k]; __syncthreads(); }
  float var = sf[0] * (1.f / B_) - mu * mu;
  float scale = rsqrtf(var + BN_EPS_) * g[j];
  float shift = b[j];
  idx = 0;
  for (int i = tid; i < B_; i += 256, ++idx)
    Y[(size_t)i * FEAT_ + j] = (vals[idx] - mu) * scale + shift;
}

// ---------------- CE with label smoothing (+ optional argmax preds) --------
__global__ __launch_bounds__(256) void ce_kernel(const float* __restrict__ logits,
                                                 const int* __restrict__ label,
                                                 float* __restrict__ acc,
                                                 float* __restrict__ preds) {
  const int row = blockIdx.x;
  const int tid = threadIdx.x;
  const float* x = logits + (size_t)row * NCLS_;
  __shared__ float sf[256];
  __shared__ int si[256];
  float mx = -INFINITY; int ai = NCLS_;
  float sumx = 0.f;
  for (int j = tid; j < NCLS_; j += 256) {
    float v = x[j];
    sumx += v;
    if (v > mx) { mx = v; ai = j; }
  }
  sf[tid] = mx; si[tid] = ai; __syncthreads();
  for (int k = 128; k > 0; k >>= 1) {
    if (tid < k) {
      float om = sf[tid + k]; int oi = si[tid + k];
      if (om > sf[tid] || (om == sf[tid] && oi < si[tid])) { sf[tid] = om; si[tid] = oi; }
    }
    __syncthreads();
  }
  float Mx = sf[0]; int amax = si[0]; __syncthreads();
  sf[tid] = sumx; __syncthreads();
  for (int k = 128; k > 0; k >>= 1) { if (tid < k) sf[tid] += sf[tid + k]; __syncthreads(); }
  float SX = sf[0]; __syncthreads();
  float se = 0.f;
  for (int j = tid; j < NCLS_; j += 256) se += expf(x[j] - Mx);
  sf[tid] = se; __syncthreads();
  for (int k = 128; k > 0; k >>= 1) { if (tid < k) sf[tid] += sf[tid + k]; __syncthreads(); }
  float lse = Mx + logf(sf[0]);
  if (tid == 0) {
    float xl = x[label[row]];
    float loss = -((1.f - LS_EPS_) * (xl - lse) + (LS_EPS_ / NCLS_) * (SX - NCLS_ * lse));
    atomicAdd(acc, loss * (1.f / B_));
    if (preds) preds[row] = (float)amax;
  }
}

// ---------------- triplet hard mining from Gram matrix ---------------------
__global__ __launch_bounds__(256) void triplet_kernel(const float* __restrict__ G,
                                                      const int* __restrict__ label,
                                                      float* __restrict__ acc) {
  const int i = blockIdx.x;
  const int tid = threadIdx.x;
  const int li = label[i];
  __shared__ float sap[256], san[256];
  const float sqi = G[(size_t)i * B_ + i];
  float ap = -INFINITY, an = INFINITY;
  for (int j = tid; j < B_; j += 256) {
    float sqj = G[(size_t)j * B_ + j];
    float d2 = sqi + sqj - 2.f * G[(size_t)i * B_ + j];
    float d = sqrtf(fmaxf(d2, 1e-12f));
    if (label[j] == li) ap = fmaxf(ap, d); else an = fminf(an, d);
  }
  sap[tid] = ap; san[tid] = an; __syncthreads();
  for (int k = 128; k > 0; k >>= 1) {
    if (tid < k) {
      sap[tid] = fmaxf(sap[tid], sap[tid + k]);
      san[tid] = fminf(san[tid], san[tid + k]);
    }
    __syncthreads();
  }
  if (tid == 0) atomicAdd(acc, fmaxf(sap[0] - san[0] + MARGIN_, 0.f) * (1.f / B_));
}

// ---------------- KL distillation (batchmean, T=2) -------------------------
__global__ __launch_bounds__(256) void kl_kernel(const float* __restrict__ TL,
                                                 const float* __restrict__ SL,
                                                 float* __restrict__ acc) {
  const int row = blockIdx.x;
  const int tid = threadIdx.x;
  const float* t = TL + (size_t)row * NCLS_;
  const float* s = SL + (size_t)row * NCLS_;
  __shared__ float sf[256];
  float mt = -INFINITY, ms = -INFINITY;
  for (int j = tid; j < NCLS_; j += 256) {
    mt = fmaxf(mt, t[j] * 0.5f);
    ms = fmaxf(ms, s[j] * 0.5f);
  }
  sf[tid] = mt; __syncthreads();
  for (int k = 128; k > 0; k >>= 1) { if (tid < k) sf[tid] = fmaxf(sf[tid], sf[tid + k]); __syncthreads(); }
  mt = sf[0]; __syncthreads();
  sf[tid] = ms; __syncthreads();
  for (int k = 128; k > 0; k >>= 1) { if (tid < k) sf[tid] = fmaxf(sf[tid], sf[tid + k]); __syncthreads(); }
  ms = sf[0]; __syncthreads();
  float set = 0.f, ses = 0.f;
  for (int j = tid; j < NCLS_; j += 256) {
    set += expf(t[j] * 0.5f - mt);
    ses += expf(s[j] * 0.5f - ms);
  }
  sf[tid] = set; __syncthreads();
  for (int k = 128; k > 0; k >>= 1) { if (tid < k) sf[tid] += sf[tid + k]; __syncthreads(); }
  set = sf[0]; __syncthreads();
  sf[tid] = ses; __syncthreads();
  for (int k = 128; k > 0; k >>= 1) { if (tid < k) sf[tid] += sf[tid + k]; __syncthreads(); }
  ses = sf[0]; __syncthreads();
  float lt = mt + logf(set), ls = ms + logf(ses);
  float part = 0.f;
  for (int j = tid; j < NCLS_; j += 256) {
    float tlp = t[j] * 0.5f - lt;
    float slp = s[j] * 0.5f - ls;
    part += expf(tlp) * (tlp - slp);
  }
  sf[tid] = part; __syncthreads();
  for (int k = 128; k > 0; k >>= 1) { if (tid < k) sf[tid] += sf[tid + k]; __syncthreads(); }
  if (tid == 0) atomicAdd(acc, sf[0] * (1.f / B_));
}

// ---------------- per-row inverse L2 norm (wave per row), f32 --------------
__global__ __launch_bounds__(256) void invnorm_rows(const float* __restrict__ X,
                                                    float* __restrict__ out,
                                                    int nrows, int D) {
  const int lane = threadIdx.x & 63;
  const int wv = threadIdx.x >> 6;
  const int row = blockIdx.x * 4 + wv;
  if (row >= nrows) return;
  const float* x = X + (size_t)row * D;
  float s = 0.f;
  for (int i = lane; i < D; i += 64) { float v = x[i]; s += v * v; }
#pragma unroll
  for (int off = 32; off > 0; off >>= 1) s += __shfl_down(s, off);
  if (lane == 0) out[row] = 1.f / fmaxf(sqrtf(s), 1e-12f);
}

// ---------------- per-row inverse L2 norm, bf16 input ----------------------
__global__ __launch_bounds__(256) void invnorm_bf16(const ushort* __restrict__ X,
                                                    float* __restrict__ out,
                                                    int nrows) {
  const int lane = threadIdx.x & 63;
  const int wv = threadIdx.x >> 6;
  const int row = blockIdx.x * 4 + wv;
  if (row >= nrows) return;
  const ushort* x = X + (size_t)row * LDIM_;
  float s = 0.f;
  for (int i = lane; i < LDIM_; i += 64) { float v = bf2f(x[i]); s += v * v; }
#pragma unroll
  for (int off = 32; off > 0; off >>= 1) s += __shfl_down(s, off);
  if (lane == 0) out[row] = 1.f / fmaxf(sqrtf(s), 1e-12f);
}

// ---------------- per-batch Sinkhorn in LDS + sim_op -----------------------
__global__ __launch_bounds__(256) void sinkhorn_kernel(const float* __restrict__ sim,
                                                       float* __restrict__ acc) {
  const int b = blockIdx.x;
  const int tid = threadIdx.x;
  __shared__ float Ks[M_ * N_];
  __shared__ float r[M_];
  __shared__ float c[N_];
  __shared__ float sf[256];
  const float* simb = sim + (size_t)b * M_ * N_;
  for (int e = tid; e < M_ * N_; e += 256)
    Ks[e] = __expf((simb[e] - 1.f) * 10.f);
  if (tid < N_) c[tid] = 1.f;
  __syncthreads();
  const float u = 1.f / M_, v = 1.f / N_;
  for (int it = 0; it < SINK_ITERS; ++it) {
    for (int m = tid; m < M_; m += 256) {
      const float* Km = Ks + m * N_;
      float s = 0.f;
      for (int n = 0; n < N_; ++n) s += Km[n] * c[n];
      r[m] = u / s;
    }
    __syncthreads();
    for (int n = tid; n < N_; n += 256) {
      float s = 0.f;
      for (int m = 0; m < M_; ++m) s += Ks[m * N_ + n] * r[m];
      c[n] = v / s;
    }
    __syncthreads();
  }
  float part = 0.f;
  for (int e = tid; e < M_ * N_; e += 256) {
    int m = e / N_, n = e % N_;
    part += r[m] * c[n] * Ks[e] * simb[e];
  }
  sf[tid] = part; __syncthreads();
  for (int k = 128; k > 0; k >>= 1) { if (tid < k) sf[tid] += sf[tid + k]; __syncthreads(); }
  if (tid == 0) atomicAdd(acc, sf[0] * (1.f / B_));
}

// ---------------- small utils ----------------------------------------------
__global__ void zero_kernel(float* p, int n) {
  int i = blockIdx.x * blockDim.x + threadIdx.x;
  if (i < n) p[i] = 0.f;
}

__global__ void finalize_kernel(const float* __restrict__ acc, float* __restrict__ out) {
  if (threadIdx.x == 0)
    out[0] = acc[0] + acc[1] + acc[2] + acc[3] + acc[4] + (1.f - acc[5]);
}

// ---------------------------------------------------------------------------
extern "C" void kernel_launch(void* const* d_in, const int* in_sizes, int n_in,
                              void* d_out, int out_size, void* d_ws, size_t ws_size,
                              hipStream_t stream) {
  const float* text_feat  = (const float*)d_in[0];
  const float* t_img_raw  = (const float*)d_in[1];
  const float* s_glob_raw = (const float*)d_in[2];
  const float* s_local    = (const float*)d_in[3];
  const int*   label      = (const int*)d_in[4];
  const float* W_tv = (const float*)d_in[5];
  const float* b_tv = (const float*)d_in[6];
  const float* W_tt = (const float*)d_in[7];
  const float* b_tt = (const float*)d_in[8];
  const float* W_sv = (const float*)d_in[9];
  const float* b_sv = (const float*)d_in[10];
  const float* bn_g = (const float*)d_in[11];
  const float* bn_b = (const float*)d_in[12];
  const float* W_ct = (const float*)d_in[13];
  const float* b_ct = (const float*)d_in[14];
  const float* W_cs = (const float*)d_in[15];
  const float* b_cs = (const float*)d_in[16];
  float* out = (float*)d_out;
  float* ws = (float*)d_ws;

  // workspace layout (floats) — total ≈ 85 MB
  float* tlin   = ws;                       // 512*512
  float* timg   = tlin + 262144;
  float* sglob  = timg + 262144;
  float* tlog   = sglob + 262144;           // 512*632
  float* slog   = tlog + 323584;
  float* gram_t = slog + 323584;            // 512*512
  float* gram_s = gram_t + 262144;
  float* sinv   = gram_s + 262144;          // 512*196
  float* tinvp  = sinv + 100352;            // 512*77
  float* acc    = tinvp + 39424;            // 8
  ushort* ttext = (ushort*)(acc + 8);       // 512*77*576 bf16
  float* sim    = (float*)(ttext + 22708224); // 512*196*77 f32

  dim3 blk(256);
  zero_kernel<<<1, 64, 0, stream>>>(acc, 8);

  // teacher image: linear + BN (f32)
  gemm_nt<64, 64, 32, 4, 4><<<dim3(8, 8), blk, 0, stream>>>(t_img_raw, W_tv, b_tv, tlin, 512, FEAT_, TDIM_);
  bn_kernel<<<FEAT_, blk, 0, stream>>>(tlin, timg, bn_g, bn_b);
  // student global linear (f32 — preds depend on this path)
  gemm_nt<64, 64, 32, 4, 4><<<dim3(8, 8), blk, 0, stream>>>(s_glob_raw, W_sv, b_sv, sglob, 512, FEAT_, LDIM_);
  // classifier logits
  gemm_nt<64, 64, 32, 4, 4><<<dim3(10, 8), blk, 0, stream>>>(timg, W_ct, b_ct, tlog, 512, NCLS_, FEAT_);
  gemm_nt<64, 64, 32, 4, 4><<<dim3(10, 8), blk, 0, stream>>>(sglob, W_cs, b_cs, slog, 512, NCLS_, FEAT_);
  // CE losses (+ student preds)
  ce_kernel<<<B_, blk, 0, stream>>>(tlog, label, acc + 0, nullptr);
  ce_kernel<<<B_, blk, 0, stream>>>(slog, label, acc + 2, out + 1);
  // Gram matrices + triplet
  gemm_nt<64, 64, 32, 4, 4><<<dim3(8, 8), blk, 0, stream>>>(timg, timg, nullptr, gram_t, 512, 512, FEAT_);
  gemm_nt<64, 64, 32, 4, 4><<<dim3(8, 8), blk, 0, stream>>>(sglob, sglob, nullptr, gram_s, 512, 512, FEAT_);
  triplet_kernel<<<B_, blk, 0, stream>>>(gram_t, label, acc + 1);
  triplet_kernel<<<B_, blk, 0, stream>>>(gram_s, label, acc + 3);
  // KL distillation
  kl_kernel<<<B_, blk, 0, stream>>>(tlog, slog, acc + 4);
  // teacher text features: bf16 MFMA GEMM (fused f32->bf16 staging), bf16 out
  gemm_ttext_mfma<<<dim3(5, 308), blk, 0, stream>>>(text_feat, W_tt, b_tt, ttext);
  // inverse norms
  invnorm_rows<<<(B_ * M_ + 3) / 4, blk, 0, stream>>>(s_local, sinv, B_ * M_, LDIM_);
  invnorm_bf16<<<(B_ * N_ + 3) / 4, blk, 0, stream>>>(ttext, tinvp, B_ * N_);
  // batched cosine sim via MFMA (one block per batch)
  sim_mfma<<<dim3(B_), blk, 0, stream>>>(s_local, ttext, sinv, tinvp, sim);
  // sinkhorn + OT loss
  sinkhorn_kernel<<<B_, blk, 0, stream>>>(sim, acc + 5);
  // combine
  finalize_kernel<<<1, 1, 0, stream>>>(acc, out);
}

// Round 3
// 846.159 us; speedup vs baseline: 3.4723x; 1.4952x over previous
//
#include <hip/hip_runtime.h>
#include <math.h>

#define B_     512
#define M_     196
#define N_     77
#define FEAT_  512
#define NCLS_  632
#define TDIM_  768
#define LDIM_  576
#define LS_EPS_ 0.1f
#define MARGIN_ 0.3f
#define BN_EPS_ 1e-5f
#define SINK_ITERS 40

typedef float fx4 __attribute__((ext_vector_type(4)));
typedef float fx8 __attribute__((ext_vector_type(8)));
typedef short sx8 __attribute__((ext_vector_type(8)));
typedef __bf16 bfx8 __attribute__((ext_vector_type(8)));

__device__ inline ushort f2bf(float f) {
  union { float f; uint u; } v; v.f = f;
  uint u = v.u;
  return (ushort)((u + 0x7FFFu + ((u >> 16) & 1u)) >> 16);
}
__device__ inline float bf2f(ushort b) {
  union { uint u; float f; } v; v.u = ((uint)b) << 16;
  return v.f;
}
__device__ inline sx8 cvt8(fx8 f) {
  sx8 u;
#pragma unroll
  for (int j = 0; j < 8; ++j) u[j] = (short)f2bf(f[j]);
  return u;
}
__device__ inline sx8 cvt8s(fx8 f, float s) {
  sx8 u;
#pragma unroll
  for (int j = 0; j < 8; ++j) u[j] = (short)f2bf(f[j] * s);
  return u;
}
__device__ inline fx4 mfma16(sx8 a, sx8 b, fx4 c) {
  return __builtin_amdgcn_mfma_f32_16x16x32_bf16(
      __builtin_bit_cast(bfx8, a), __builtin_bit_cast(bfx8, b), c, 0, 0, 0);
}

// ============ ttext = text_feat @ W_tt^T + b_tt, bf16 out ===================
// Block: 64 rows x all 576 cols. A staged ONCE to LDS (bf16, fragment order).
// W streamed per 32-K step (L2-resident), register-prefetched.
__global__ __launch_bounds__(512) void gemm_ttext_v2(const float* __restrict__ A,
                                                     const float* __restrict__ W,
                                                     const float* __restrict__ bias,
                                                     ushort* __restrict__ C) {
  __shared__ __align__(16) ushort ldsA[49152];  // 64 rows x 768 k, frag order
  __shared__ __align__(16) ushort ldsW[18432];  // 576 cols x 32 k, frag order
  const int tid = threadIdx.x;
  const int lane = tid & 63;
  const int wv = tid >> 6;
  const int wrow = wv & 1;       // 2 row groups of 32
  const int wcol = wv >> 1;      // 4 col groups of 144
  const int row0 = blockIdx.x * 64;

  // ---- stage A tile (64x768 f32 -> bf16 fragment order), once ----
  {
    const int tr = tid >> 3;          // row 0..63
    const int kc0 = (tid & 7) * 12;   // k-chunk base (8 floats each)
    const int mt = tr >> 4, l16r = tr & 15;
    const float* pa = A + (size_t)(row0 + tr) * TDIM_ + kc0 * 8;
#pragma unroll
    for (int j = 0; j < 12; ++j) {
      fx8 f = *(const fx8*)(pa + j * 8);
      int kc = kc0 + j;
      int ksl = kc >> 2, k8 = kc & 3;
      int chunk = (mt * 24 + ksl) * 64 + (l16r + 16 * k8);
      *(sx8*)&ldsA[chunk * 8] = cvt8(f);
    }
  }

  // W chunk addressing for this thread (5 chunks: 4 full + 1 for tid<256)
  // chunk c: ct=c>>6, l=c&63, col=ct*16+(l&15), k8=l>>4
  int wcol_addr[5], wk8[5];
#pragma unroll
  for (int j = 0; j < 4; ++j) {
    int c = tid + j * 512;
    wcol_addr[j] = (c >> 6) * 16 + (c & 15);
    wk8[j] = (c >> 4) & 3;
  }
  { int c = 2048 + tid; wcol_addr[4] = (c >> 6) * 16 + (c & 15); wk8[4] = (c >> 4) & 3; }
  const bool has5 = tid < 256;

  fx4 acc[2][9];
  const fx4 zz = {0.f, 0.f, 0.f, 0.f};
#pragma unroll
  for (int i = 0; i < 2; ++i)
#pragma unroll
    for (int j = 0; j < 9; ++j) acc[i][j] = zz;

  // prefetch W for kt=0
  sx8 uw[5];
#pragma unroll
  for (int j = 0; j < 4; ++j)
    uw[j] = cvt8(*(const fx8*)(W + (size_t)wcol_addr[j] * TDIM_ + wk8[j] * 8));
  if (has5) uw[4] = cvt8(*(const fx8*)(W + (size_t)wcol_addr[4] * TDIM_ + wk8[4] * 8));

  for (int kt = 0; kt < 24; ++kt) {
    if (kt) __syncthreads();
    *(sx8*)&ldsW[tid * 8] = uw[0];
    *(sx8*)&ldsW[(tid + 512) * 8] = uw[1];
    *(sx8*)&ldsW[(tid + 1024) * 8] = uw[2];
    *(sx8*)&ldsW[(tid + 1536) * 8] = uw[3];
    if (has5) *(sx8*)&ldsW[(tid + 2048) * 8] = uw[4];
    __syncthreads();
    if (kt < 23) {
      const float* Wk = W + (kt + 1) * 32;
#pragma unroll
      for (int j = 0; j < 4; ++j)
        uw[j] = cvt8(*(const fx8*)(Wk + (size_t)wcol_addr[j] * TDIM_ + wk8[j] * 8));
      if (has5) uw[4] = cvt8(*(const fx8*)(Wk + (size_t)wcol_addr[4] * TDIM_ + wk8[4] * 8));
    }
    sx8 af[2], bf[9];
#pragma unroll
    for (int mi = 0; mi < 2; ++mi)
      af[mi] = *(sx8*)&ldsA[(((2 * wrow + mi) * 24 + kt) * 64 + lane) * 8];
#pragma unroll
    for (int ni = 0; ni < 9; ++ni)
      bf[ni] = *(sx8*)&ldsW[((wcol * 9 + ni) * 64 + lane) * 8];
#pragma unroll
    for (int mi = 0; mi < 2; ++mi)
#pragma unroll
      for (int ni = 0; ni < 9; ++ni) acc[mi][ni] = mfma16(af[mi], bf[ni], acc[mi][ni]);
  }

#pragma unroll
  for (int mi = 0; mi < 2; ++mi) {
    int rbase = row0 + (2 * wrow + mi) * 16 + ((lane >> 4) << 2);
#pragma unroll
    for (int ni = 0; ni < 9; ++ni) {
      int col = wcol * 144 + ni * 16 + (lane & 15);
      float bv = bias[col];
#pragma unroll
      for (int r = 0; r < 4; ++r)
        C[(size_t)(rbase + r) * 576 + col] = f2bf(acc[mi][ni][r] + bv);
    }
  }
}

// ============ small bf16 MFMA GEMM: C[M,N] f32 = A[M,K] @ W[N,K]^T ==========
// BM=BN=64, BK=32, 256 threads (4 waves, each 32x32). M%64==0, K%32==0.
__global__ __launch_bounds__(256) void gemm_small_mfma(const float* __restrict__ A,
                                                       const float* __restrict__ Wm,
                                                       const float* __restrict__ bias,
                                                       float* __restrict__ C,
                                                       int N, int K) {
  __shared__ __align__(16) ushort ldsA[2048];
  __shared__ __align__(16) ushort ldsW[2048];
  const int tid = threadIdx.x;
  const int lane = tid & 63;
  const int wv = tid >> 6;
  const int wr = wv >> 1, wc = wv & 1;
  const int row0 = blockIdx.y * 64;
  const int col0 = blockIdx.x * 64;
  const int mt = tid >> 6;
  const int l16 = lane & 15;
  const int k8 = lane >> 4;

  const float* pA = A + (size_t)(row0 + mt * 16 + l16) * K + k8 * 8;
  int wcl = col0 + mt * 16 + l16;
  if (wcl >= N) wcl = N - 1;
  const float* pW = Wm + (size_t)wcl * K + k8 * 8;

  fx4 acc[2][2];
  const fx4 zz = {0.f, 0.f, 0.f, 0.f};
  acc[0][0] = zz; acc[0][1] = zz; acc[1][0] = zz; acc[1][1] = zz;

  sx8 ua = cvt8(*(const fx8*)pA);
  sx8 uw = cvt8(*(const fx8*)pW);
  const int NT = K >> 5;
  for (int kt = 0; kt < NT; ++kt) {
    if (kt) __syncthreads();
    *(sx8*)&ldsA[tid * 8] = ua;
    *(sx8*)&ldsW[tid * 8] = uw;
    __syncthreads();
    if (kt + 1 < NT) {
      ua = cvt8(*(const fx8*)(pA + (kt + 1) * 32));
      uw = cvt8(*(const fx8*)(pW + (kt + 1) * 32));
    }
    sx8 af[2], bf[2];
#pragma unroll
    for (int mi = 0; mi < 2; ++mi) af[mi] = *(sx8*)&ldsA[((wr * 2 + mi) * 64 + lane) * 8];
#pragma unroll
    for (int ni = 0; ni < 2; ++ni) bf[ni] = *(sx8*)&ldsW[((wc * 2 + ni) * 64 + lane) * 8];
#pragma unroll
    for (int mi = 0; mi < 2; ++mi)
#pragma unroll
      for (int ni = 0; ni < 2; ++ni) acc[mi][ni] = mfma16(af[mi], bf[ni], acc[mi][ni]);
  }
#pragma unroll
  for (int mi = 0; mi < 2; ++mi) {
    int rbase = row0 + (wr * 2 + mi) * 16 + ((lane >> 4) << 2);
#pragma unroll
    for (int ni = 0; ni < 2; ++ni) {
      int col = col0 + (wc * 2 + ni) * 16 + l16;
      if (col < N) {
        float bv = bias ? bias[col] : 0.f;
#pragma unroll
        for (int r = 0; r < 4; ++r)
          C[(size_t)(rbase + r) * N + col] = acc[mi][ni][r] + bv;
      }
    }
  }
}

// ============ batched cosine sim via MFMA: one block per batch ==============
__global__ __launch_bounds__(256) void sim_mfma(const float* __restrict__ S,
                                                const ushort* __restrict__ T,
                                                const float* __restrict__ sinv,
                                                const float* __restrict__ tinv,
                                                float* __restrict__ sim) {
  __shared__ __align__(16) ushort lds[9216];
  const int b = blockIdx.x;
  const int tid = threadIdx.x;
  const int lane = tid & 63;
  const int w = tid >> 6;
  const int l16 = lane & 15;
  fx4 acc[4][5];
  const fx4 zz = {0.f, 0.f, 0.f, 0.f};
#pragma unroll
  for (int i = 0; i < 4; ++i)
#pragma unroll
    for (int j = 0; j < 5; ++j) acc[i][j] = zz;
  const float* Sb = S + (size_t)b * M_ * LDIM_;
  const ushort* Tb = T + (size_t)b * N_ * LDIM_;

  for (int kt = 0; kt < 18; ++kt) {
    const int k0 = kt * 32;
    if (kt) __syncthreads();
    for (int c = tid; c < 1152; c += 256) {
      if (c < 832) {
        int tile = c >> 6, cl = c & 63;
        int r = tile * 16 + (cl & 15);
        int ks = ((cl >> 4) & 3) * 8;
        int rr = r < 196 ? r : 195;
        fx8 f = *(const fx8*)(Sb + (size_t)rr * LDIM_ + k0 + ks);
        *(sx8*)&lds[c * 8] = cvt8s(f, sinv[b * M_ + rr]);
      } else {
        int cc = c - 832;
        int tile = cc >> 6, cl = cc & 63;
        int r = tile * 16 + (cl & 15);
        int ks = ((cl >> 4) & 3) * 8;
        int rr = r < 77 ? r : 76;
        *(sx8*)&lds[c * 8] = *(const sx8*)(Tb + (size_t)rr * LDIM_ + k0 + ks);
      }
    }
    __syncthreads();
    sx8 bfr[5];
#pragma unroll
    for (int ni = 0; ni < 5; ++ni) bfr[ni] = *(sx8*)&lds[(832 + ni * 64 + lane) * 8];
#pragma unroll
    for (int mi = 0; mi < 4; ++mi) {
      int mt = w + mi * 4;
      if (mt < 13) {
        sx8 af = *(sx8*)&lds[(mt * 64 + lane) * 8];
#pragma unroll
        for (int ni = 0; ni < 5; ++ni) acc[mi][ni] = mfma16(af, bfr[ni], acc[mi][ni]);
      }
    }
  }
#pragma unroll
  for (int mi = 0; mi < 4; ++mi) {
    int mt = w + mi * 4;
    if (mt >= 13) continue;
    int rbase = mt * 16 + ((lane >> 4) << 2);
#pragma unroll
    for (int ni = 0; ni < 5; ++ni) {
      int col = ni * 16 + l16;
      if (col < 77) {
        float tv = tinv[b * N_ + col];
#pragma unroll
        for (int r = 0; r < 4; ++r) {
          int row = rbase + r;
          if (row < 196) sim[((size_t)b * M_ + row) * N_ + col] = acc[mi][ni][r] * tv;
        }
      }
    }
  }
}

// ---------------- generic tiled f32 GEMM (student path, exact) -------------
template<int BM, int BN, int BK, int TM, int TN>
__global__ __launch_bounds__(256) void gemm_nt(const float* __restrict__ A,
                                               const float* __restrict__ W,
                                               const float* __restrict__ bias,
                                               float* __restrict__ C,
                                               int M, int N, int K) {
  __shared__ float As[BM][BK + 1];
  __shared__ float Ws[BN][BK + 1];
  const int tid = threadIdx.x;
  const int tx = tid & 15, ty = tid >> 4;
  const int row0 = blockIdx.y * BM;
  const int col0 = blockIdx.x * BN;
  float acc[TM][TN];
#pragma unroll
  for (int i = 0; i < TM; ++i)
#pragma unroll
    for (int j = 0; j < TN; ++j) acc[i][j] = 0.f;

  for (int k0 = 0; k0 < K; k0 += BK) {
#pragma unroll
    for (int e = tid; e < BM * BK; e += 256) {
      int r = e / BK, c = e % BK;
      int gr = row0 + r, gc = k0 + c;
      As[r][c] = (gr < M && gc < K) ? A[(size_t)gr * K + gc] : 0.f;
    }
#pragma unroll
    for (int e = tid; e < BN * BK; e += 256) {
      int r = e / BK, c = e % BK;
      int gr = col0 + r, gc = k0 + c;
      Ws[r][c] = (gr < N && gc < K) ? W[(size_t)gr * K + gc] : 0.f;
    }
    __syncthreads();
#pragma unroll
    for (int kk = 0; kk < BK; ++kk) {
      float a[TM], wv[TN];
#pragma unroll
      for (int i = 0; i < TM; ++i) a[i] = As[ty * TM + i][kk];
#pragma unroll
      for (int j = 0; j < TN; ++j) wv[j] = Ws[tx * TN + j][kk];
#pragma unroll
      for (int i = 0; i < TM; ++i)
#pragma unroll
        for (int j = 0; j < TN; ++j) acc[i][j] += a[i] * wv[j];
    }
    __syncthreads();
  }
#pragma unroll
  for (int i = 0; i < TM; ++i) {
    int gr = row0 + ty * TM + i;
    if (gr >= M) continue;
#pragma unroll
    for (int j = 0; j < TN; ++j) {
      int gc = col0 + tx * TN + j;
      if (gc >= N) continue;
      float v = acc[i][j];
      if (bias) v += bias[gc];
      C[(size_t)gr * N + gc] = v;
    }
  }
}

// ---------------- batchnorm (train) over axis 0 ----------------------------
__global__ __launch_bounds__(256) void bn_kernel(const float* __restrict__ X,
                                                 float* __restrict__ Y,
                                                 const float* __restrict__ g,
                                                 const float* __restrict__ b) {
  const int j = blockIdx.x;
  const int tid = threadIdx.x;
  __shared__ float sf[256];
  float vals[2];
  float s = 0.f, s2 = 0.f;
  int idx = 0;
  for (int i = tid; i < B_; i += 256, ++idx) {
    float v = X[(size_t)i * FEAT_ + j];
    vals[idx] = v;
    s += v; s2 += v * v;
  }
  sf[tid] = s; __syncthreads();
  for (int k = 128; k > 0; k >>= 1) { if (tid < k) sf[tid] += sf[tid + k]; __syncthreads(); }
  float mu = sf[0] * (1.f / B_); __syncthreads();
  sf[tid] = s2; __syncthreads();
  for (int k = 128; k > 0; k >>= 1) { if (tid < k) sf[tid] += sf[tid + k]; __syncthreads(); }
  float var = sf[0] * (1.f / B_) - mu * mu;
  float scale = rsqrtf(var + BN_EPS_) * g[j];
  float shift = b[j];
  idx = 0;
  for (int i = tid; i < B_; i += 256, ++idx)
    Y[(size_t)i * FEAT_ + j] = (vals[idx] - mu) * scale + shift;
}

// ---------------- CE with label smoothing (+ optional argmax preds) --------
__global__ __launch_bounds__(256) void ce_kernel(const float* __restrict__ logits,
                                                 const int* __restrict__ label,
                                                 float* __restrict__ acc,
                                                 float* __restrict__ preds) {
  const int row = blockIdx.x;
  const int tid = threadIdx.x;
  const float* x = logits + (size_t)row * NCLS_;
  __shared__ float sf[256];
  __shared__ int si[256];
  float mx = -INFINITY; int ai = NCLS_;
  float sumx = 0.f;
  for (int j = tid; j < NCLS_; j += 256) {
    float v = x[j];
    sumx += v;
    if (v > mx) { mx = v; ai = j; }
  }
  sf[tid] = mx; si[tid] = ai; __syncthreads();
  for (int k = 128; k > 0; k >>= 1) {
    if (tid < k) {
      float om = sf[tid + k]; int oi = si[tid + k];
      if (om > sf[tid] || (om == sf[tid] && oi < si[tid])) { sf[tid] = om; si[tid] = oi; }
    }
    __syncthreads();
  }
  float Mx = sf[0]; int amax = si[0]; __syncthreads();
  sf[tid] = sumx; __syncthreads();
  for (int k = 128; k > 0; k >>= 1) { if (tid < k) sf[tid] += sf[tid + k]; __syncthreads(); }
  float SX = sf[0]; __syncthreads();
  float se = 0.f;
  for (int j = tid; j < NCLS_; j += 256) se += expf(x[j] - Mx);
  sf[tid] = se; __syncthreads();
  for (int k = 128; k > 0; k >>= 1) { if (tid < k) sf[tid] += sf[tid + k]; __syncthreads(); }
  float lse = Mx + logf(sf[0]);
  if (tid == 0) {
    float xl = x[label[row]];
    float loss = -((1.f - LS_EPS_) * (xl - lse) + (LS_EPS_ / NCLS_) * (SX - NCLS_ * lse));
    atomicAdd(acc, loss * (1.f / B_));
    if (preds) preds[row] = (float)amax;
  }
}

// ---------------- triplet hard mining from Gram matrix ---------------------
__global__ __launch_bounds__(256) void triplet_kernel(const float* __restrict__ G,
                                                      const int* __restrict__ label,
                                                      float* __restrict__ acc) {
  const int i = blockIdx.x;
  const int tid = threadIdx.x;
  const int li = label[i];
  __shared__ float sap[256], san[256];
  const float sqi = G[(size_t)i * B_ + i];
  float ap = -INFINITY, an = INFINITY;
  for (int j = tid; j < B_; j += 256) {
    float sqj = G[(size_t)j * B_ + j];
    float d2 = sqi + sqj - 2.f * G[(size_t)i * B_ + j];
    float d = sqrtf(fmaxf(d2, 1e-12f));
    if (label[j] == li) ap = fmaxf(ap, d); else an = fminf(an, d);
  }
  sap[tid] = ap; san[tid] = an; __syncthreads();
  for (int k = 128; k > 0; k >>= 1) {
    if (tid < k) {
      sap[tid] = fmaxf(sap[tid], sap[tid + k]);
      san[tid] = fminf(san[tid], san[tid + k]);
    }
    __syncthreads();
  }
  if (tid == 0) atomicAdd(acc, fmaxf(sap[0] - san[0] + MARGIN_, 0.f) * (1.f / B_));
}

// ---------------- KL distillation (batchmean, T=2) -------------------------
__global__ __launch_bounds__(256) void kl_kernel(const float* __restrict__ TL,
                                                 const float* __restrict__ SL,
                                                 float* __restrict__ acc) {
  const int row = blockIdx.x;
  const int tid = threadIdx.x;
  const float* t = TL + (size_t)row * NCLS_;
  const float* s = SL + (size_t)row * NCLS_;
  __shared__ float sf[256];
  float mt = -INFINITY, ms = -INFINITY;
  for (int j = tid; j < NCLS_; j += 256) {
    mt = fmaxf(mt, t[j] * 0.5f);
    ms = fmaxf(ms, s[j] * 0.5f);
  }
  sf[tid] = mt; __syncthreads();
  for (int k = 128; k > 0; k >>= 1) { if (tid < k) sf[tid] = fmaxf(sf[tid], sf[tid + k]); __syncthreads(); }
  mt = sf[0]; __syncthreads();
  sf[tid] = ms; __syncthreads();
  for (int k = 128; k > 0; k >>= 1) { if (tid < k) sf[tid] = fmaxf(sf[tid], sf[tid + k]); __syncthreads(); }
  ms = sf[0]; __syncthreads();
  float set = 0.f, ses = 0.f;
  for (int j = tid; j < NCLS_; j += 256) {
    set += expf(t[j] * 0.5f - mt);
    ses += expf(s[j] * 0.5f - ms);
  }
  sf[tid] = set; __syncthreads();
  for (int k = 128; k > 0; k >>= 1) { if (tid < k) sf[tid] += sf[tid + k]; __syncthreads(); }
  set = sf[0]; __syncthreads();
  sf[tid] = ses; __syncthreads();
  for (int k = 128; k > 0; k >>= 1) { if (tid < k) sf[tid] += sf[tid + k]; __syncthreads(); }
  ses = sf[0]; __syncthreads();
  float lt = mt + logf(set), ls = ms + logf(ses);
  float part = 0.f;
  for (int j = tid; j < NCLS_; j += 256) {
    float tlp = t[j] * 0.5f - lt;
    float slp = s[j] * 0.5f - ls;
    part += expf(tlp) * (tlp - slp);
  }
  sf[tid] = part; __syncthreads();
  for (int k = 128; k > 0; k >>= 1) { if (tid < k) sf[tid] += sf[tid + k]; __syncthreads(); }
  if (tid == 0) atomicAdd(acc, sf[0] * (1.f / B_));
}

// ---------------- per-row inverse L2 norms ---------------------------------
__global__ __launch_bounds__(256) void invnorm_rows(const float* __restrict__ X,
                                                    float* __restrict__ out,
                                                    int nrows, int D) {
  const int lane = threadIdx.x & 63;
  const int wv = threadIdx.x >> 6;
  const int row = blockIdx.x * 4 + wv;
  if (row >= nrows) return;
  const float* x = X + (size_t)row * D;
  float s = 0.f;
  for (int i = lane; i < D; i += 64) { float v = x[i]; s += v * v; }
#pragma unroll
  for (int off = 32; off > 0; off >>= 1) s += __shfl_down(s, off);
  if (lane == 0) out[row] = 1.f / fmaxf(sqrtf(s), 1e-12f);
}

__global__ __launch_bounds__(256) void invnorm_bf16(const ushort* __restrict__ X,
                                                    float* __restrict__ out,
                                                    int nrows) {
  const int lane = threadIdx.x & 63;
  const int wv = threadIdx.x >> 6;
  const int row = blockIdx.x * 4 + wv;
  if (row >= nrows) return;
  const ushort* x = X + (size_t)row * LDIM_;
  float s = 0.f;
  for (int i = lane; i < LDIM_; i += 64) { float v = bf2f(x[i]); s += v * v; }
#pragma unroll
  for (int off = 32; off > 0; off >>= 1) s += __shfl_down(s, off);
  if (lane == 0) out[row] = 1.f / fmaxf(sqrtf(s), 1e-12f);
}

// ---------------- per-batch Sinkhorn in LDS + sim_op -----------------------
__global__ __launch_bounds__(256) void sinkhorn_kernel(const float* __restrict__ sim,
                                                       float* __restrict__ acc) {
  const int b = blockIdx.x;
  const int tid = threadIdx.x;
  __shared__ float Ks[M_ * N_];
  __shared__ float r[M_];
  __shared__ float c[N_];
  __shared__ float sf[256];
  const float* simb = sim + (size_t)b * M_ * N_;
  for (int e = tid; e < M_ * N_; e += 256)
    Ks[e] = __expf((simb[e] - 1.f) * 10.f);
  if (tid < N_) c[tid] = 1.f;
  __syncthreads();
  const float u = 1.f / M_, v = 1.f / N_;
  for (int it = 0; it < SINK_ITERS; ++it) {
    for (int m = tid; m < M_; m += 256) {
      const float* Km = Ks + m * N_;
      float s = 0.f;
      for (int n = 0; n < N_; ++n) s += Km[n] * c[n];
      r[m] = u / s;
    }
    __syncthreads();
    for (int n = tid; n < N_; n += 256) {
      float s = 0.f;
      for (int m = 0; m < M_; ++m) s += Ks[m * N_ + n] * r[m];
      c[n] = v / s;
    }
    __syncthreads();
  }
  float part = 0.f;
  for (int e = tid; e < M_ * N_; e += 256) {
    int m = e / N_, n = e % N_;
    part += r[m] * c[n] * Ks[e] * simb[e];
  }
  sf[tid] = part; __syncthreads();
  for (int k = 128; k > 0; k >>= 1) { if (tid < k) sf[tid] += sf[tid + k]; __syncthreads(); }
  if (tid == 0) atomicAdd(acc, sf[0] * (1.f / B_));
}

// ---------------- small utils ----------------------------------------------
__global__ void zero_kernel(float* p, int n) {
  int i = blockIdx.x * blockDim.x + threadIdx.x;
  if (i < n) p[i] = 0.f;
}

__global__ void finalize_kernel(const float* __restrict__ acc, float* __restrict__ out) {
  if (threadIdx.x == 0)
    out[0] = acc[0] + acc[1] + acc[2] + acc[3] + acc[4] + (1.f - acc[5]);
}

// ---------------------------------------------------------------------------
extern "C" void kernel_launch(void* const* d_in, const int* in_sizes, int n_in,
                              void* d_out, int out_size, void* d_ws, size_t ws_size,
                              hipStream_t stream) {
  const float* text_feat  = (const float*)d_in[0];
  const float* t_img_raw  = (const float*)d_in[1];
  const float* s_glob_raw = (const float*)d_in[2];
  const float* s_local    = (const float*)d_in[3];
  const int*   label      = (const int*)d_in[4];
  const float* W_tv = (const float*)d_in[5];
  const float* b_tv = (const float*)d_in[6];
  const float* W_tt = (const float*)d_in[7];
  const float* b_tt = (const float*)d_in[8];
  const float* W_sv = (const float*)d_in[9];
  const float* b_sv = (const float*)d_in[10];
  const float* bn_g = (const float*)d_in[11];
  const float* bn_b = (const float*)d_in[12];
  const float* W_ct = (const float*)d_in[13];
  const float* b_ct = (const float*)d_in[14];
  const float* W_cs = (const float*)d_in[15];
  const float* b_cs = (const float*)d_in[16];
  float* out = (float*)d_out;
  float* ws = (float*)d_ws;

  float* tlin   = ws;
  float* timg   = tlin + 262144;
  float* sglob  = timg + 262144;
  float* tlog   = sglob + 262144;
  float* slog   = tlog + 323584;
  float* gram_t = slog + 323584;
  float* gram_s = gram_t + 262144;
  float* sinv   = gram_s + 262144;
  float* tinvp  = sinv + 100352;
  float* acc    = tinvp + 39424;
  ushort* ttext = (ushort*)(acc + 8);
  float* sim    = (float*)(ttext + 22708224);

  dim3 blk(256);
  zero_kernel<<<1, 64, 0, stream>>>(acc, 8);

  // teacher image: bf16 MFMA linear + BN
  gemm_small_mfma<<<dim3(8, 8), blk, 0, stream>>>(t_img_raw, W_tv, b_tv, tlin, FEAT_, TDIM_);
  bn_kernel<<<FEAT_, blk, 0, stream>>>(tlin, timg, bn_g, bn_b);
  // student global linear (f32 exact — preds path), 256-block grid
  gemm_nt<32, 32, 32, 2, 2><<<dim3(16, 16), blk, 0, stream>>>(s_glob_raw, W_sv, b_sv, sglob, 512, FEAT_, LDIM_);
  // classifier logits: teacher bf16, student f32 (preds path)
  gemm_small_mfma<<<dim3(10, 8), blk, 0, stream>>>(timg, W_ct, b_ct, tlog, NCLS_, FEAT_);
  gemm_nt<32, 32, 32, 2, 2><<<dim3(20, 16), blk, 0, stream>>>(sglob, W_cs, b_cs, slog, 512, NCLS_, FEAT_);
  // CE losses (+ student preds)
  ce_kernel<<<B_, blk, 0, stream>>>(tlog, label, acc + 0, nullptr);
  ce_kernel<<<B_, blk, 0, stream>>>(slog, label, acc + 2, out + 1);
  // Gram matrices (bf16 MFMA) + triplet
  gemm_small_mfma<<<dim3(8, 8), blk, 0, stream>>>(timg, timg, nullptr, gram_t, 512, FEAT_);
  gemm_small_mfma<<<dim3(8, 8), blk, 0, stream>>>(sglob, sglob, nullptr, gram_s, 512, LDIM_);
  triplet_kernel<<<B_, blk, 0, stream>>>(gram_t, label, acc + 1);
  triplet_kernel<<<B_, blk, 0, stream>>>(gram_s, label, acc + 3);
  // KL distillation
  kl_kernel<<<B_, blk, 0, stream>>>(tlog, slog, acc + 4);
  // teacher text features: A-read-once MFMA GEMM, bf16 out
  gemm_ttext_v2<<<dim3(616), dim3(512), 0, stream>>>(text_feat, W_tt, b_tt, ttext);
  // inverse norms
  invnorm_rows<<<(B_ * M_ + 3) / 4, blk, 0, stream>>>(s_local, sinv, B_ * M_, LDIM_);
  invnorm_bf16<<<(B_ * N_ + 3) / 4, blk, 0, stream>>>(ttext, tinvp, B_ * N_);
  // batched cosine sim via MFMA
  sim_mfma<<<dim3(B_), blk, 0, stream>>>(s_local, ttext, sinv, tinvp, sim);
  // sinkhorn + OT loss
  sinkhorn_kernel<<<B_, blk, 0, stream>>>(sim, acc + 5);
  // combine
  finalize_kernel<<<1, 1, 0, stream>>>(acc, out);
}

// Round 4
// 697.399 us; speedup vs baseline: 4.2130x; 1.2133x over previous
//
#include <hip/hip_runtime.h>
#include <math.h>

#define B_     512
#define M_     196
#define N_     77
#define FEAT_  512
#define NCLS_  632
#define TDIM_  768
#define LDIM_  576
#define LS_EPS_ 0.1f
#define MARGIN_ 0.3f
#define BN_EPS_ 1e-5f
#define SINK_ITERS 40

typedef float fx4 __attribute__((ext_vector_type(4)));
typedef float fx8 __attribute__((ext_vector_type(8)));
typedef short sx8 __attribute__((ext_vector_type(8)));
typedef __bf16 bfx8 __attribute__((ext_vector_type(8)));

__device__ inline ushort f2bf(float f) {
  union { float f; uint u; } v; v.f = f;
  uint u = v.u;
  return (ushort)((u + 0x7FFFu + ((u >> 16) & 1u)) >> 16);
}
__device__ inline float bf2f(ushort b) {
  union { uint u; float f; } v; v.u = ((uint)b) << 16;
  return v.f;
}
__device__ inline sx8 cvt8(fx8 f) {
  bfx8 h = __builtin_convertvector(f, bfx8);
  return __builtin_bit_cast(sx8, h);
}
__device__ inline fx8 b2f8(sx8 s) {
  bfx8 h = __builtin_bit_cast(bfx8, s);
  return __builtin_convertvector(h, fx8);
}
__device__ inline sx8 cvt8s(fx8 f, float s) {
  fx8 g = f * s;
  return cvt8(g);
}
__device__ inline fx4 mfma16(sx8 a, sx8 b, fx4 c) {
  return __builtin_amdgcn_mfma_f32_16x16x32_bf16(
      __builtin_bit_cast(bfx8, a), __builtin_bit_cast(bfx8, b), c, 0, 0, 0);
}
// CK-style addrspace cast pattern for global_load_lds (16B per lane)
__device__ inline void gload_lds16(const void* g, void* l) {
  auto gp = (const __attribute__((address_space(1))) uint*)(uintptr_t)g;
  auto lp = (__attribute__((address_space(3))) uint*)(uintptr_t)l;
  __builtin_amdgcn_global_load_lds(gp, lp, 16, 0, 0);
}

// ---------------- f32 -> bf16 conversions ----------------------------------
__global__ __launch_bounds__(256) void cvt_bf16_kernel(const float* __restrict__ X,
                                                       ushort* __restrict__ Y) {
  size_t i = (size_t)blockIdx.x * 256 + threadIdx.x;   // one 8-chunk per thread
  fx8 f = *(const fx8*)(X + i * 8);
  *(sx8*)(Y + i * 8) = cvt8(f);
}

__global__ __launch_bounds__(256) void cvt_w_pad(const float* __restrict__ W,
                                                 ushort* __restrict__ Y) {
  // Y[640][768] bf16; rows >= 576 are zero
  int i = blockIdx.x * 256 + threadIdx.x;  // chunk of 8; 640*96 chunks
  int row = i / 96;
  if (row < 576) {
    fx8 f = *(const fx8*)(W + (size_t)i * 8);
    *(sx8*)(Y + (size_t)i * 8) = cvt8(f);
  } else {
    sx8 z = {0, 0, 0, 0, 0, 0, 0, 0};
    *(sx8*)(Y + (size_t)i * 8) = z;
  }
}

// ============ ttext GEMM (m97 structure): C[39424,576] = A @ Wb^T + bias ====
// A bf16 [39424][768], Wb bf16 [640][768] (pad rows zero). 128x128, BK=32.
__global__ __launch_bounds__(256) void gemm_bf16_128(const ushort* __restrict__ A,
                                                     const ushort* __restrict__ Bm,
                                                     const float* __restrict__ bias,
                                                     ushort* __restrict__ C) {
  __shared__ __align__(16) ushort ldsA[4096];
  __shared__ __align__(16) ushort ldsB[4096];
  const int tid = threadIdx.x;
  const int lane = tid & 63;
  const int w = tid >> 6;
  const int wr = w >> 1, wc = w & 1;
  const int row0 = blockIdx.y * 128;
  const int col0 = blockIdx.x * 128;
  const int l16 = lane & 15, k8 = (lane >> 4) * 8;

  const ushort* gA0 = A + (size_t)(row0 + (2 * w) * 16 + l16) * TDIM_ + k8;
  const ushort* gA1 = A + (size_t)(row0 + (2 * w + 1) * 16 + l16) * TDIM_ + k8;
  const ushort* gB0 = Bm + (size_t)(col0 + (2 * w) * 16 + l16) * TDIM_ + k8;
  const ushort* gB1 = Bm + (size_t)(col0 + (2 * w + 1) * 16 + l16) * TDIM_ + k8;
  ushort* lA0 = &ldsA[(2 * w) * 512];
  ushort* lA1 = &ldsA[(2 * w + 1) * 512];
  ushort* lB0 = &ldsB[(2 * w) * 512];
  ushort* lB1 = &ldsB[(2 * w + 1) * 512];

  fx4 acc[4][4];
  const fx4 zz = {0.f, 0.f, 0.f, 0.f};
#pragma unroll
  for (int i = 0; i < 4; ++i)
#pragma unroll
    for (int j = 0; j < 4; ++j) acc[i][j] = zz;

  for (int kt = 0; kt < 24; ++kt) {
    if (kt) __syncthreads();
    const int ko = kt * 32;
    gload_lds16(gA0 + ko, lA0);
    gload_lds16(gA1 + ko, lA1);
    gload_lds16(gB0 + ko, lB0);
    gload_lds16(gB1 + ko, lB1);
    asm volatile("s_waitcnt vmcnt(0)" ::: "memory");
    __syncthreads();
    sx8 af[4], bf[4];
#pragma unroll
    for (int mi = 0; mi < 4; ++mi) af[mi] = *(sx8*)&ldsA[((wr * 4 + mi) * 64 + lane) * 8];
#pragma unroll
    for (int ni = 0; ni < 4; ++ni) bf[ni] = *(sx8*)&ldsB[((wc * 4 + ni) * 64 + lane) * 8];
#pragma unroll
    for (int mi = 0; mi < 4; ++mi)
#pragma unroll
      for (int ni = 0; ni < 4; ++ni) acc[mi][ni] = mfma16(af[mi], bf[ni], acc[mi][ni]);
  }

#pragma unroll
  for (int mi = 0; mi < 4; ++mi) {
    int rbase = row0 + wr * 64 + mi * 16 + ((lane >> 4) << 2);
#pragma unroll
    for (int ni = 0; ni < 4; ++ni) {
      int col = col0 + wc * 64 + ni * 16 + l16;
      if (col < 576) {
        float bv = bias[col];
#pragma unroll
        for (int r = 0; r < 4; ++r)
          C[(size_t)(rbase + r) * 576 + col] = f2bf(acc[mi][ni][r] + bv);
      }
    }
  }
}

// ============ small bf16 MFMA GEMM: C[M,N] f32 = A[M,K] @ W[N,K]^T ==========
__global__ __launch_bounds__(256) void gemm_small_mfma(const float* __restrict__ A,
                                                       const float* __restrict__ Wm,
                                                       const float* __restrict__ bias,
                                                       float* __restrict__ C,
                                                       int N, int K) {
  __shared__ __align__(16) ushort ldsA[2048];
  __shared__ __align__(16) ushort ldsW[2048];
  const int tid = threadIdx.x;
  const int lane = tid & 63;
  const int wv = tid >> 6;
  const int wr = wv >> 1, wc = wv & 1;
  const int row0 = blockIdx.y * 64;
  const int col0 = blockIdx.x * 64;
  const int mt = tid >> 6;
  const int l16 = lane & 15;
  const int k8 = lane >> 4;

  const float* pA = A + (size_t)(row0 + mt * 16 + l16) * K + k8 * 8;
  int wcl = col0 + mt * 16 + l16;
  if (wcl >= N) wcl = N - 1;
  const float* pW = Wm + (size_t)wcl * K + k8 * 8;

  fx4 acc[2][2];
  const fx4 zz = {0.f, 0.f, 0.f, 0.f};
  acc[0][0] = zz; acc[0][1] = zz; acc[1][0] = zz; acc[1][1] = zz;

  sx8 ua = cvt8(*(const fx8*)pA);
  sx8 uw = cvt8(*(const fx8*)pW);
  const int NT = K >> 5;
  for (int kt = 0; kt < NT; ++kt) {
    if (kt) __syncthreads();
    *(sx8*)&ldsA[tid * 8] = ua;
    *(sx8*)&ldsW[tid * 8] = uw;
    __syncthreads();
    if (kt + 1 < NT) {
      ua = cvt8(*(const fx8*)(pA + (kt + 1) * 32));
      uw = cvt8(*(const fx8*)(pW + (kt + 1) * 32));
    }
    sx8 af[2], bf[2];
#pragma unroll
    for (int mi = 0; mi < 2; ++mi) af[mi] = *(sx8*)&ldsA[((wr * 2 + mi) * 64 + lane) * 8];
#pragma unroll
    for (int ni = 0; ni < 2; ++ni) bf[ni] = *(sx8*)&ldsW[((wc * 2 + ni) * 64 + lane) * 8];
#pragma unroll
    for (int mi = 0; mi < 2; ++mi)
#pragma unroll
      for (int ni = 0; ni < 2; ++ni) acc[mi][ni] = mfma16(af[mi], bf[ni], acc[mi][ni]);
  }
#pragma unroll
  for (int mi = 0; mi < 2; ++mi) {
    int rbase = row0 + (wr * 2 + mi) * 16 + ((lane >> 4) << 2);
#pragma unroll
    for (int ni = 0; ni < 2; ++ni) {
      int col = col0 + (wc * 2 + ni) * 16 + l16;
      if (col < N) {
        float bv = bias ? bias[col] : 0.f;
#pragma unroll
        for (int r = 0; r < 4; ++r)
          C[(size_t)(rbase + r) * N + col] = acc[mi][ni][r] + bv;
      }
    }
  }
}

// ============ batched cosine sim via MFMA, norms fused =====================
__global__ __launch_bounds__(256) void sim_mfma(const float* __restrict__ S,
                                                const ushort* __restrict__ T,
                                                float* __restrict__ sim) {
  __shared__ __align__(16) ushort lds[9216];
  __shared__ float sinv_s[196];
  __shared__ float tinv_s[80];
  const int b = blockIdx.x;
  const int tid = threadIdx.x;
  const int lane = tid & 63;
  const int w = tid >> 6;
  const int l16 = lane & 15;
  const float* Sb = S + (size_t)b * M_ * LDIM_;
  const ushort* Tb = T + (size_t)b * N_ * LDIM_;

  // ---- pre-pass: row inverse-norms into LDS ----
  for (int row = w; row < M_; row += 4) {
    const float* x = Sb + (size_t)row * LDIM_;
    float s = 0.f;
#pragma unroll
    for (int i = 0; i < 9; ++i) { float v = x[lane + i * 64]; s += v * v; }
#pragma unroll
    for (int off = 32; off > 0; off >>= 1) s += __shfl_down(s, off);
    if (lane == 0) sinv_s[row] = 1.f / fmaxf(sqrtf(s), 1e-12f);
  }
  for (int row = w; row < N_; row += 4) {
    const ushort* x = Tb + (size_t)row * LDIM_;
    float s = 0.f;
#pragma unroll
    for (int i = 0; i < 9; ++i) { float v = bf2f(x[lane + i * 64]); s += v * v; }
#pragma unroll
    for (int off = 32; off > 0; off >>= 1) s += __shfl_down(s, off);
    if (lane == 0) tinv_s[row] = 1.f / fmaxf(sqrtf(s), 1e-12f);
  }
  __syncthreads();

  fx4 acc[4][5];
  const fx4 zz = {0.f, 0.f, 0.f, 0.f};
#pragma unroll
  for (int i = 0; i < 4; ++i)
#pragma unroll
    for (int j = 0; j < 5; ++j) acc[i][j] = zz;

  for (int kt = 0; kt < 18; ++kt) {
    const int k0 = kt * 32;
    __syncthreads();
    for (int c = tid; c < 1152; c += 256) {
      if (c < 832) {
        int tile = c >> 6, cl = c & 63;
        int r = tile * 16 + (cl & 15);
        int ks = ((cl >> 4) & 3) * 8;
        int rr = r < 196 ? r : 195;
        fx8 f = *(const fx8*)(Sb + (size_t)rr * LDIM_ + k0 + ks);
        *(sx8*)&lds[c * 8] = cvt8s(f, sinv_s[rr]);
      } else {
        int cc = c - 832;
        int tile = cc >> 6, cl = cc & 63;
        int r = tile * 16 + (cl & 15);
        int ks = ((cl >> 4) & 3) * 8;
        int rr = r < 77 ? r : 76;
        *(sx8*)&lds[c * 8] = *(const sx8*)(Tb + (size_t)rr * LDIM_ + k0 + ks);
      }
    }
    __syncthreads();
    sx8 bfr[5];
#pragma unroll
    for (int ni = 0; ni < 5; ++ni) bfr[ni] = *(sx8*)&lds[(832 + ni * 64 + lane) * 8];
#pragma unroll
    for (int mi = 0; mi < 4; ++mi) {
      int mt = w + mi * 4;
      if (mt < 13) {
        sx8 af = *(sx8*)&lds[(mt * 64 + lane) * 8];
#pragma unroll
        for (int ni = 0; ni < 5; ++ni) acc[mi][ni] = mfma16(af, bfr[ni], acc[mi][ni]);
      }
    }
  }
#pragma unroll
  for (int mi = 0; mi < 4; ++mi) {
    int mt = w + mi * 4;
    if (mt >= 13) continue;
    int rbase = mt * 16 + ((lane >> 4) << 2);
#pragma unroll
    for (int ni = 0; ni < 5; ++ni) {
      int col = ni * 16 + l16;
      if (col < 77) {
        float tv = tinv_s[col];
#pragma unroll
        for (int r = 0; r < 4; ++r) {
          int row = rbase + r;
          if (row < 196) sim[((size_t)b * M_ + row) * N_ + col] = acc[mi][ni][r] * tv;
        }
      }
    }
  }
}

// ---------------- generic tiled f32 GEMM (student path, exact) -------------
template<int BM, int BN, int BK, int TM, int TN>
__global__ __launch_bounds__(256) void gemm_nt(const float* __restrict__ A,
                                               const float* __restrict__ W,
                                               const float* __restrict__ bias,
                                               float* __restrict__ C,
                                               int M, int N, int K) {
  __shared__ float As[BM][BK + 1];
  __shared__ float Ws[BN][BK + 1];
  const int tid = threadIdx.x;
  const int tx = tid & 15, ty = tid >> 4;
  const int row0 = blockIdx.y * BM;
  const int col0 = blockIdx.x * BN;
  float acc[TM][TN];
#pragma unroll
  for (int i = 0; i < TM; ++i)
#pragma unroll
    for (int j = 0; j < TN; ++j) acc[i][j] = 0.f;

  for (int k0 = 0; k0 < K; k0 += BK) {
#pragma unroll
    for (int e = tid; e < BM * BK; e += 256) {
      int r = e / BK, c = e % BK;
      int gr = row0 + r, gc = k0 + c;
      As[r][c] = (gr < M && gc < K) ? A[(size_t)gr * K + gc] : 0.f;
    }
#pragma unroll
    for (int e = tid; e < BN * BK; e += 256) {
      int r = e / BK, c = e % BK;
      int gr = col0 + r, gc = k0 + c;
      Ws[r][c] = (gr < N && gc < K) ? W[(size_t)gr * K + gc] : 0.f;
    }
    __syncthreads();
#pragma unroll
    for (int kk = 0; kk < BK; ++kk) {
      float a[TM], wv[TN];
#pragma unroll
      for (int i = 0; i < TM; ++i) a[i] = As[ty * TM + i][kk];
#pragma unroll
      for (int j = 0; j < TN; ++j) wv[j] = Ws[tx * TN + j][kk];
#pragma unroll
      for (int i = 0; i < TM; ++i)
#pragma unroll
        for (int j = 0; j < TN; ++j) acc[i][j] += a[i] * wv[j];
    }
    __syncthreads();
  }
#pragma unroll
  for (int i = 0; i < TM; ++i) {
    int gr = row0 + ty * TM + i;
    if (gr >= M) continue;
#pragma unroll
    for (int j = 0; j < TN; ++j) {
      int gc = col0 + tx * TN + j;
      if (gc >= N) continue;
      float v = acc[i][j];
      if (bias) v += bias[gc];
      C[(size_t)gr * N + gc] = v;
    }
  }
}

// ---------------- batchnorm (train) over axis 0 ----------------------------
__global__ __launch_bounds__(256) void bn_kernel(const float* __restrict__ X,
                                                 float* __restrict__ Y,
                                                 const float* __restrict__ g,
                                                 const float* __restrict__ b) {
  const int j = blockIdx.x;
  const int tid = threadIdx.x;
  __shared__ float sf[256];
  float vals[2];
  float s = 0.f, s2 = 0.f;
  int idx = 0;
  for (int i = tid; i < B_; i += 256, ++idx) {
    float v = X[(size_t)i * FEAT_ + j];
    vals[idx] = v;
    s += v; s2 += v * v;
  }
  sf[tid] = s; __syncthreads();
  for (int k = 128; k > 0; k >>= 1) { if (tid < k) sf[tid] += sf[tid + k]; __syncthreads(); }
  float mu = sf[0] * (1.f / B_); __syncthreads();
  sf[tid] = s2; __syncthreads();
  for (int k = 128; k > 0; k >>= 1) { if (tid < k) sf[tid] += sf[tid + k]; __syncthreads(); }
  float var = sf[0] * (1.f / B_) - mu * mu;
  float scale = rsqrtf(var + BN_EPS_) * g[j];
  float shift = b[j];
  idx = 0;
  for (int i = tid; i < B_; i += 256, ++idx)
    Y[(size_t)i * FEAT_ + j] = (vals[idx] - mu) * scale + shift;
}

// ---------------- CE with label smoothing (+ optional argmax preds) --------
__global__ __launch_bounds__(256) void ce_kernel(const float* __restrict__ logits,
                                                 const int* __restrict__ label,
                                                 float* __restrict__ acc,
                                                 float* __restrict__ preds) {
  const int row = blockIdx.x;
  const int tid = threadIdx.x;
  const float* x = logits + (size_t)row * NCLS_;
  __shared__ float sf[256];
  __shared__ int si[256];
  float mx = -INFINITY; int ai = NCLS_;
  float sumx = 0.f;
  for (int j = tid; j < NCLS_; j += 256) {
    float v = x[j];
    sumx += v;
    if (v > mx) { mx = v; ai = j; }
  }
  sf[tid] = mx; si[tid] = ai; __syncthreads();
  for (int k = 128; k > 0; k >>= 1) {
    if (tid < k) {
      float om = sf[tid + k]; int oi = si[tid + k];
      if (om > sf[tid] || (om == sf[tid] && oi < si[tid])) { sf[tid] = om; si[tid] = oi; }
    }
    __syncthreads();
  }
  float Mx = sf[0]; int amax = si[0]; __syncthreads();
  sf[tid] = sumx; __syncthreads();
  for (int k = 128; k > 0; k >>= 1) { if (tid < k) sf[tid] += sf[tid + k]; __syncthreads(); }
  float SX = sf[0]; __syncthreads();
  float se = 0.f;
  for (int j = tid; j < NCLS_; j += 256) se += expf(x[j] - Mx);
  sf[tid] = se; __syncthreads();
  for (int k = 128; k > 0; k >>= 1) { if (tid < k) sf[tid] += sf[tid + k]; __syncthreads(); }
  float lse = Mx + logf(sf[0]);
  if (tid == 0) {
    float xl = x[label[row]];
    float loss = -((1.f - LS_EPS_) * (xl - lse) + (LS_EPS_ / NCLS_) * (SX - NCLS_ * lse));
    atomicAdd(acc, loss * (1.f / B_));
    if (preds) preds[row] = (float)amax;
  }
}

// ---------------- triplet hard mining from Gram matrix ---------------------
__global__ __launch_bounds__(256) void triplet_kernel(const float* __restrict__ G,
                                                      const int* __restrict__ label,
                                                      float* __restrict__ acc) {
  const int i = blockIdx.x;
  const int tid = threadIdx.x;
  const int li = label[i];
  __shared__ float sap[256], san[256];
  const float sqi = G[(size_t)i * B_ + i];
  float ap = -INFINITY, an = INFINITY;
  for (int j = tid; j < B_; j += 256) {
    float sqj = G[(size_t)j * B_ + j];
    float d2 = sqi + sqj - 2.f * G[(size_t)i * B_ + j];
    float d = sqrtf(fmaxf(d2, 1e-12f));
    if (label[j] == li) ap = fmaxf(ap, d); else an = fminf(an, d);
  }
  sap[tid] = ap; san[tid] = an; __syncthreads();
  for (int k = 128; k > 0; k >>= 1) {
    if (tid < k) {
      sap[tid] = fmaxf(sap[tid], sap[tid + k]);
      san[tid] = fminf(san[tid], san[tid + k]);
    }
    __syncthreads();
  }
  if (tid == 0) atomicAdd(acc, fmaxf(sap[0] - san[0] + MARGIN_, 0.f) * (1.f / B_));
}

// ---------------- KL distillation (batchmean, T=2) -------------------------
__global__ __launch_bounds__(256) void kl_kernel(const float* __restrict__ TL,
                                                 const float* __restrict__ SL,
                                                 float* __restrict__ acc) {
  const int row = blockIdx.x;
  const int tid = threadIdx.x;
  const float* t = TL + (size_t)row * NCLS_;
  const float* s = SL + (size_t)row * NCLS_;
  __shared__ float sf[256];
  float mt = -INFINITY, ms = -INFINITY;
  for (int j = tid; j < NCLS_; j += 256) {
    mt = fmaxf(mt, t[j] * 0.5f);
    ms = fmaxf(ms, s[j] * 0.5f);
  }
  sf[tid] = mt; __syncthreads();
  for (int k = 128; k > 0; k >>= 1) { if (tid < k) sf[tid] = fmaxf(sf[tid], sf[tid + k]); __syncthreads(); }
  mt = sf[0]; __syncthreads();
  sf[tid] = ms; __syncthreads();
  for (int k = 128; k > 0; k >>= 1) { if (tid < k) sf[tid] = fmaxf(sf[tid], sf[tid + k]); __syncthreads(); }
  ms = sf[0]; __syncthreads();
  float set = 0.f, ses = 0.f;
  for (int j = tid; j < NCLS_; j += 256) {
    set += expf(t[j] * 0.5f - mt);
    ses += expf(s[j] * 0.5f - ms);
  }
  sf[tid] = set; __syncthreads();
  for (int k = 128; k > 0; k >>= 1) { if (tid < k) sf[tid] += sf[tid + k]; __syncthreads(); }
  set = sf[0]; __syncthreads();
  sf[tid] = ses; __syncthreads();
  for (int k = 128; k > 0; k >>= 1) { if (tid < k) sf[tid] += sf[tid + k]; __syncthreads(); }
  ses = sf[0]; __syncthreads();
  float lt = mt + logf(set), ls = ms + logf(ses);
  float part = 0.f;
  for (int j = tid; j < NCLS_; j += 256) {
    float tlp = t[j] * 0.5f - lt;
    float slp = s[j] * 0.5f - ls;
    part += expf(tlp) * (tlp - slp);
  }
  sf[tid] = part; __syncthreads();
  for (int k = 128; k > 0; k >>= 1) { if (tid < k) sf[tid] += sf[tid + k]; __syncthreads(); }
  if (tid == 0) atomicAdd(acc, sf[0] * (1.f / B_));
}

// ---------------- per-batch Sinkhorn (bf16 K in LDS) + sim_op --------------
#define SKLD 88
__global__ __launch_bounds__(256) void sinkhorn_kernel(const float* __restrict__ sim,
                                                       float* __restrict__ acc) {
  const int b = blockIdx.x;
  const int tid = threadIdx.x;
  __shared__ __align__(16) ushort Kb[196 * SKLD];  // 34496 B
  __shared__ float r[196];
  __shared__ float c[SKLD];
  __shared__ float cs1[80];
  __shared__ float sf[256];
  const float* simb = sim + (size_t)b * (M_ * N_);
  for (int e = tid; e < 196 * SKLD; e += 256) {
    int m = e / SKLD, n = e - m * SKLD;
    float kv = 0.f;
    if (n < 77) kv = __expf((simb[m * 77 + n] - 1.f) * 10.f);
    Kb[e] = f2bf(kv);
  }
  if (tid < SKLD) c[tid] = (tid < 77) ? 1.f : 0.f;
  __syncthreads();
  const float uu = 1.f / 196.f, vv = 1.f / 77.f;
  for (int it = 0; it < SINK_ITERS; ++it) {
    if (tid < 196) {
      const ushort* Km = &Kb[tid * SKLD];
      float s = 0.f;
#pragma unroll
      for (int j = 0; j < 11; ++j) {
        fx8 kf = b2f8(*(const sx8*)&Km[j * 8]);
#pragma unroll
        for (int q = 0; q < 8; ++q) s += kf[q] * c[j * 8 + q];
      }
      r[tid] = uu / s;
    }
    __syncthreads();
    {
      int half = tid >> 7;
      int n = tid & 127;
      if (n < 77) {
        int m0 = half * 98;
        float s = 0.f;
        for (int m = m0; m < m0 + 98; ++m) s += bf2f(Kb[m * SKLD + n]) * r[m];
        if (half) cs1[n] = s; else sf[n] = s;
      }
    }
    __syncthreads();
    if (tid < 77) c[tid] = vv / (sf[tid] + cs1[tid]);
    __syncthreads();
  }
  float part = 0.f;
  for (int e = tid; e < M_ * N_; e += 256) {
    int m = e / 77, n = e - m * 77;
    part += r[m] * c[n] * bf2f(Kb[m * SKLD + n]) * simb[e];
  }
  sf[tid] = part; __syncthreads();
  for (int k = 128; k > 0; k >>= 1) { if (tid < k) sf[tid] += sf[tid + k]; __syncthreads(); }
  if (tid == 0) atomicAdd(acc, sf[0] * (1.f / B_));
}

// ---------------- small utils ----------------------------------------------
__global__ void zero_kernel(float* p, int n) {
  int i = blockIdx.x * blockDim.x + threadIdx.x;
  if (i < n) p[i] = 0.f;
}

__global__ void finalize_kernel(const float* __restrict__ acc, float* __restrict__ out) {
  if (threadIdx.x == 0)
    out[0] = acc[0] + acc[1] + acc[2] + acc[3] + acc[4] + (1.f - acc[5]);
}

// ---------------------------------------------------------------------------
extern "C" void kernel_launch(void* const* d_in, const int* in_sizes, int n_in,
                              void* d_out, int out_size, void* d_ws, size_t ws_size,
                              hipStream_t stream) {
  const float* text_feat  = (const float*)d_in[0];
  const float* t_img_raw  = (const float*)d_in[1];
  const float* s_glob_raw = (const float*)d_in[2];
  const float* s_local    = (const float*)d_in[3];
  const int*   label      = (const int*)d_in[4];
  const float* W_tv = (const float*)d_in[5];
  const float* b_tv = (const float*)d_in[6];
  const float* W_tt = (const float*)d_in[7];
  const float* b_tt = (const float*)d_in[8];
  const float* W_sv = (const float*)d_in[9];
  const float* b_sv = (const float*)d_in[10];
  const float* bn_g = (const float*)d_in[11];
  const float* bn_b = (const float*)d_in[12];
  const float* W_ct = (const float*)d_in[13];
  const float* b_ct = (const float*)d_in[14];
  const float* W_cs = (const float*)d_in[15];
  const float* b_cs = (const float*)d_in[16];
  float* out = (float*)d_out;
  float* ws = (float*)d_ws;

  // workspace layout — ~115 MB total (sim aliases dead Abuf)
  float* tlin   = ws;
  float* timg   = tlin + 262144;
  float* sglob  = timg + 262144;
  float* tlog   = sglob + 262144;
  float* slog   = tlog + 323584;
  float* gram_t = slog + 323584;
  float* gram_s = gram_t + 262144;
  float* acc    = gram_s + 262144;              // 8 floats
  ushort* Wbuf  = (ushort*)(acc + 8);           // 640*768
  ushort* ttext = Wbuf + 491520;                // 39424*576
  ushort* Abuf  = ttext + 22708224;             // 39424*768 (60.6 MB)
  float* sim    = (float*)Abuf;                 // 30.9 MB, alias (Abuf dead by then)

  dim3 blk(256);
  zero_kernel<<<1, 64, 0, stream>>>(acc, 8);

  // bf16 pre-conversions for the big GEMM
  cvt_bf16_kernel<<<14784, blk, 0, stream>>>(text_feat, Abuf);   // 39424*768/8/256
  cvt_w_pad<<<240, blk, 0, stream>>>(W_tt, Wbuf);                // 640*96/256

  // teacher image: bf16 MFMA linear + BN
  gemm_small_mfma<<<dim3(8, 8), blk, 0, stream>>>(t_img_raw, W_tv, b_tv, tlin, FEAT_, TDIM_);
  bn_kernel<<<FEAT_, blk, 0, stream>>>(tlin, timg, bn_g, bn_b);
  // student global linear (f32 exact — preds path)
  gemm_nt<32, 32, 32, 2, 2><<<dim3(16, 16), blk, 0, stream>>>(s_glob_raw, W_sv, b_sv, sglob, 512, FEAT_, LDIM_);
  // classifier logits
  gemm_small_mfma<<<dim3(10, 8), blk, 0, stream>>>(timg, W_ct, b_ct, tlog, NCLS_, FEAT_);
  gemm_nt<32, 32, 32, 2, 2><<<dim3(20, 16), blk, 0, stream>>>(sglob, W_cs, b_cs, slog, 512, NCLS_, FEAT_);
  // CE losses (+ student preds)
  ce_kernel<<<B_, blk, 0, stream>>>(tlog, label, acc + 0, nullptr);
  ce_kernel<<<B_, blk, 0, stream>>>(slog, label, acc + 2, out + 1);
  // Gram matrices + triplet
  gemm_small_mfma<<<dim3(8, 8), blk, 0, stream>>>(timg, timg, nullptr, gram_t, 512, FEAT_);
  gemm_small_mfma<<<dim3(8, 8), blk, 0, stream>>>(sglob, sglob, nullptr, gram_s, 512, LDIM_);
  triplet_kernel<<<B_, blk, 0, stream>>>(gram_t, label, acc + 1);
  triplet_kernel<<<B_, blk, 0, stream>>>(gram_s, label, acc + 3);
  // KL distillation
  kl_kernel<<<B_, blk, 0, stream>>>(tlog, slog, acc + 4);
  // teacher text features: m97-structure bf16 GEMM
  gemm_bf16_128<<<dim3(5, 308), blk, 0, stream>>>(Abuf, Wbuf, b_tt, ttext);
  // batched cosine sim (norms fused)
  sim_mfma<<<dim3(B_), blk, 0, stream>>>(s_local, ttext, sim);
  // sinkhorn + OT loss
  sinkhorn_kernel<<<B_, blk, 0, stream>>>(sim, acc + 5);
  // combine
  finalize_kernel<<<1, 1, 0, stream>>>(acc, out);
}

// Round 5
// 588.380 us; speedup vs baseline: 4.9936x; 1.1853x over previous
//
#include <hip/hip_runtime.h>
#include <math.h>

#define B_     512
#define M_     196
#define N_     77
#define FEAT_  512
#define NCLS_  632
#define TDIM_  768
#define LDIM_  576
#define LS_EPS_ 0.1f
#define MARGIN_ 0.3f
#define BN_EPS_ 1e-5f
#define SINK_ITERS 12

typedef float fx4 __attribute__((ext_vector_type(4)));
typedef float fx8 __attribute__((ext_vector_type(8)));
typedef short sx8 __attribute__((ext_vector_type(8)));
typedef __bf16 bfx8 __attribute__((ext_vector_type(8)));

__device__ inline ushort f2bf(float f) {
  union { float f; uint u; } v; v.f = f;
  uint u = v.u;
  return (ushort)((u + 0x7FFFu + ((u >> 16) & 1u)) >> 16);
}
__device__ inline float bf2f(ushort b) {
  union { uint u; float f; } v; v.u = ((uint)b) << 16;
  return v.f;
}
__device__ inline sx8 cvt8(fx8 f) {
  bfx8 h = __builtin_convertvector(f, bfx8);
  return __builtin_bit_cast(sx8, h);
}
__device__ inline fx8 b2f8(sx8 s) {
  bfx8 h = __builtin_bit_cast(bfx8, s);
  return __builtin_convertvector(h, fx8);
}
__device__ inline sx8 cvt8s(fx8 f, float s) {
  fx8 g = f * s;
  return cvt8(g);
}
__device__ inline fx4 mfma16(sx8 a, sx8 b, fx4 c) {
  return __builtin_amdgcn_mfma_f32_16x16x32_bf16(
      __builtin_bit_cast(bfx8, a), __builtin_bit_cast(bfx8, b), c, 0, 0, 0);
}
__device__ inline void gload_lds16(const void* g, void* l) {
  auto gp = (const __attribute__((address_space(1))) uint*)(uintptr_t)g;
  auto lp = (__attribute__((address_space(3))) uint*)(uintptr_t)l;
  __builtin_amdgcn_global_load_lds(gp, lp, 16, 0, 0);
}

// ---------------- f32 -> bf16 conversions ----------------------------------
__global__ __launch_bounds__(256) void cvt_bf16_kernel(const float* __restrict__ X,
                                                       ushort* __restrict__ Y) {
  size_t i = (size_t)blockIdx.x * 256 + threadIdx.x;
  fx8 f = *(const fx8*)(X + i * 8);
  *(sx8*)(Y + i * 8) = cvt8(f);
}

__global__ __launch_bounds__(256) void cvt_w_pad(const float* __restrict__ W,
                                                 ushort* __restrict__ Y) {
  int i = blockIdx.x * 256 + threadIdx.x;  // chunk of 8; 640*96 chunks
  int row = i / 96;
  if (row < 576) {
    fx8 f = *(const fx8*)(W + (size_t)i * 8);
    *(sx8*)(Y + (size_t)i * 8) = cvt8(f);
  } else {
    sx8 z = {0, 0, 0, 0, 0, 0, 0, 0};
    *(sx8*)(Y + (size_t)i * 8) = z;
  }
}

// ============ ttext GEMM (m97 structure): C[39424,576] = A @ Wb^T + bias ====
__global__ __launch_bounds__(256) void gemm_bf16_128(const ushort* __restrict__ A,
                                                     const ushort* __restrict__ Bm,
                                                     const float* __restrict__ bias,
                                                     ushort* __restrict__ C) {
  __shared__ __align__(16) ushort ldsA[4096];
  __shared__ __align__(16) ushort ldsB[4096];
  const int tid = threadIdx.x;
  const int lane = tid & 63;
  const int w = tid >> 6;
  const int wr = w >> 1, wc = w & 1;
  const int row0 = blockIdx.y * 128;
  const int col0 = blockIdx.x * 128;
  const int l16 = lane & 15, k8 = (lane >> 4) * 8;

  const ushort* gA0 = A + (size_t)(row0 + (2 * w) * 16 + l16) * TDIM_ + k8;
  const ushort* gA1 = A + (size_t)(row0 + (2 * w + 1) * 16 + l16) * TDIM_ + k8;
  const ushort* gB0 = Bm + (size_t)(col0 + (2 * w) * 16 + l16) * TDIM_ + k8;
  const ushort* gB1 = Bm + (size_t)(col0 + (2 * w + 1) * 16 + l16) * TDIM_ + k8;
  ushort* lA0 = &ldsA[(2 * w) * 512];
  ushort* lA1 = &ldsA[(2 * w + 1) * 512];
  ushort* lB0 = &ldsB[(2 * w) * 512];
  ushort* lB1 = &ldsB[(2 * w + 1) * 512];

  fx4 acc[4][4];
  const fx4 zz = {0.f, 0.f, 0.f, 0.f};
#pragma unroll
  for (int i = 0; i < 4; ++i)
#pragma unroll
    for (int j = 0; j < 4; ++j) acc[i][j] = zz;

  for (int kt = 0; kt < 24; ++kt) {
    if (kt) __syncthreads();
    const int ko = kt * 32;
    gload_lds16(gA0 + ko, lA0);
    gload_lds16(gA1 + ko, lA1);
    gload_lds16(gB0 + ko, lB0);
    gload_lds16(gB1 + ko, lB1);
    asm volatile("s_waitcnt vmcnt(0)" ::: "memory");
    __syncthreads();
    sx8 af[4], bf[4];
#pragma unroll
    for (int mi = 0; mi < 4; ++mi) af[mi] = *(sx8*)&ldsA[((wr * 4 + mi) * 64 + lane) * 8];
#pragma unroll
    for (int ni = 0; ni < 4; ++ni) bf[ni] = *(sx8*)&ldsB[((wc * 4 + ni) * 64 + lane) * 8];
#pragma unroll
    for (int mi = 0; mi < 4; ++mi)
#pragma unroll
      for (int ni = 0; ni < 4; ++ni) acc[mi][ni] = mfma16(af[mi], bf[ni], acc[mi][ni]);
  }

#pragma unroll
  for (int mi = 0; mi < 4; ++mi) {
    int rbase = row0 + wr * 64 + mi * 16 + ((lane >> 4) << 2);
#pragma unroll
    for (int ni = 0; ni < 4; ++ni) {
      int col = col0 + wc * 64 + ni * 16 + l16;
      if (col < 576) {
        float bv = bias[col];
#pragma unroll
        for (int r = 0; r < 4; ++r)
          C[(size_t)(rbase + r) * 576 + col] = f2bf(acc[mi][ni][r] + bv);
      }
    }
  }
}

// ============ small bf16 MFMA GEMM ==========================================
__global__ __launch_bounds__(256) void gemm_small_mfma(const float* __restrict__ A,
                                                       const float* __restrict__ Wm,
                                                       const float* __restrict__ bias,
                                                       float* __restrict__ C,
                                                       int N, int K) {
  __shared__ __align__(16) ushort ldsA[2048];
  __shared__ __align__(16) ushort ldsW[2048];
  const int tid = threadIdx.x;
  const int lane = tid & 63;
  const int wv = tid >> 6;
  const int wr = wv >> 1, wc = wv & 1;
  const int row0 = blockIdx.y * 64;
  const int col0 = blockIdx.x * 64;
  const int mt = tid >> 6;
  const int l16 = lane & 15;
  const int k8 = lane >> 4;

  const float* pA = A + (size_t)(row0 + mt * 16 + l16) * K + k8 * 8;
  int wcl = col0 + mt * 16 + l16;
  if (wcl >= N) wcl = N - 1;
  const float* pW = Wm + (size_t)wcl * K + k8 * 8;

  fx4 acc[2][2];
  const fx4 zz = {0.f, 0.f, 0.f, 0.f};
  acc[0][0] = zz; acc[0][1] = zz; acc[1][0] = zz; acc[1][1] = zz;

  sx8 ua = cvt8(*(const fx8*)pA);
  sx8 uw = cvt8(*(const fx8*)pW);
  const int NT = K >> 5;
  for (int kt = 0; kt < NT; ++kt) {
    if (kt) __syncthreads();
    *(sx8*)&ldsA[tid * 8] = ua;
    *(sx8*)&ldsW[tid * 8] = uw;
    __syncthreads();
    if (kt + 1 < NT) {
      ua = cvt8(*(const fx8*)(pA + (kt + 1) * 32));
      uw = cvt8(*(const fx8*)(pW + (kt + 1) * 32));
    }
    sx8 af[2], bf[2];
#pragma unroll
    for (int mi = 0; mi < 2; ++mi) af[mi] = *(sx8*)&ldsA[((wr * 2 + mi) * 64 + lane) * 8];
#pragma unroll
    for (int ni = 0; ni < 2; ++ni) bf[ni] = *(sx8*)&ldsW[((wc * 2 + ni) * 64 + lane) * 8];
#pragma unroll
    for (int mi = 0; mi < 2; ++mi)
#pragma unroll
      for (int ni = 0; ni < 2; ++ni) acc[mi][ni] = mfma16(af[mi], bf[ni], acc[mi][ni]);
  }
#pragma unroll
  for (int mi = 0; mi < 2; ++mi) {
    int rbase = row0 + (wr * 2 + mi) * 16 + ((lane >> 4) << 2);
#pragma unroll
    for (int ni = 0; ni < 2; ++ni) {
      int col = col0 + (wc * 2 + ni) * 16 + l16;
      if (col < N) {
        float bv = bias ? bias[col] : 0.f;
#pragma unroll
        for (int r = 0; r < 4; ++r)
          C[(size_t)(rbase + r) * N + col] = acc[mi][ni][r] + bv;
      }
    }
  }
}

// ============ batched cosine sim, M-split halves, reg-prefetch ==============
template<int H>
__device__ void sim_body(int b, const float* __restrict__ S, const ushort* __restrict__ T,
                         float* __restrict__ sim, ushort* lds, float* sinv_s, float* tinv_s) {
  constexpr int NTILE = (H == 0) ? 7 : 6;
  constexpr int NS = NTILE * 64;
  constexpr int NC = NS + 320;
  constexpr int RCNT = (H == 0) ? 112 : 84;
  constexpr int M0 = H * 112;
  const int tid = threadIdx.x;
  const int lane = tid & 63;
  const int w = tid >> 6;
  const float* Sb = S + ((size_t)b * M_ + M0) * LDIM_;
  const ushort* Tb = T + (size_t)b * N_ * LDIM_;

  // prepass: inverse norms into LDS
  for (int row = w; row < RCNT; row += 4) {
    const float* x = Sb + (size_t)row * LDIM_;
    float s = 0.f;
#pragma unroll
    for (int i = 0; i < 9; ++i) { float v = x[lane + i * 64]; s += v * v; }
#pragma unroll
    for (int off = 32; off > 0; off >>= 1) s += __shfl_down(s, off);
    if (lane == 0) sinv_s[row] = 1.f / fmaxf(sqrtf(s), 1e-12f);
  }
  for (int row = w; row < N_; row += 4) {
    const ushort* x = Tb + (size_t)row * LDIM_;
    float s = 0.f;
#pragma unroll
    for (int i = 0; i < 9; ++i) { float v = bf2f(x[lane + i * 64]); s += v * v; }
#pragma unroll
    for (int off = 32; off > 0; off >>= 1) s += __shfl_down(s, off);
    if (lane == 0) tinv_s[row] = 1.f / fmaxf(sqrtf(s), 1e-12f);
  }

  // per-thread staging chunk assignment (3 chunks max)
  bool val[3], isS[3];
  const float* pS[3];
  const ushort* pT[3];
  int lrow[3], cidx[3];
#pragma unroll
  for (int j = 0; j < 3; ++j) {
    int c = tid + j * 256;
    cidx[j] = c;
    val[j] = (c < NC);
    isS[j] = (c < NS);
    if (c < NS) {
      int tile = c >> 6;
      int r = M0 + tile * 16 + (c & 15);
      int rr = r < 196 ? r : 195;
      int ks = ((c >> 4) & 3) * 8;
      pS[j] = S + ((size_t)b * M_ + rr) * LDIM_ + ks;
      lrow[j] = rr - M0;
      pT[j] = T;
    } else {
      int cc = c - NS;
      int tile = cc >> 6;
      int r = tile * 16 + (cc & 15);
      int rr = r < 77 ? r : 76;
      int ks = ((cc >> 4) & 3) * 8;
      pT[j] = Tb + (size_t)rr * LDIM_ + ks;
      pS[j] = S;
      lrow[j] = 0;
    }
  }
  __syncthreads();   // sinv/tinv ready

  fx8 fS[3]; sx8 tS[3];
#pragma unroll
  for (int j = 0; j < 3; ++j) {
    if (!val[j]) continue;
    if (isS[j]) fS[j] = *(const fx8*)pS[j];
    else tS[j] = *(const sx8*)pT[j];
  }

  fx4 acc[2][5];
  const fx4 zz = {0.f, 0.f, 0.f, 0.f};
#pragma unroll
  for (int i = 0; i < 2; ++i)
#pragma unroll
    for (int j = 0; j < 5; ++j) acc[i][j] = zz;

  for (int kt = 0; kt < 18; ++kt) {
    if (kt) __syncthreads();
#pragma unroll
    for (int j = 0; j < 3; ++j) {
      if (!val[j]) continue;
      if (isS[j]) *(sx8*)&lds[cidx[j] * 8] = cvt8s(fS[j], sinv_s[lrow[j]]);
      else        *(sx8*)&lds[cidx[j] * 8] = tS[j];
    }
    __syncthreads();
    if (kt < 17) {
      const int ko = (kt + 1) * 32;
#pragma unroll
      for (int j = 0; j < 3; ++j) {
        if (!val[j]) continue;
        if (isS[j]) fS[j] = *(const fx8*)(pS[j] + ko);
        else tS[j] = *(const sx8*)(pT[j] + ko);
      }
    }
    sx8 bfr[5];
#pragma unroll
    for (int ni = 0; ni < 5; ++ni) bfr[ni] = *(sx8*)&lds[(NS + ni * 64 + lane) * 8];
#pragma unroll
    for (int mi = 0; mi < 2; ++mi) {
      int lt = w + mi * 4;
      if (lt < NTILE) {
        sx8 af = *(sx8*)&lds[(lt * 64 + lane) * 8];
#pragma unroll
        for (int ni = 0; ni < 5; ++ni) acc[mi][ni] = mfma16(af, bfr[ni], acc[mi][ni]);
      }
    }
  }

#pragma unroll
  for (int mi = 0; mi < 2; ++mi) {
    int lt = w + mi * 4;
    if (lt >= NTILE) continue;
    int rbase = M0 + lt * 16 + ((lane >> 4) << 2);
#pragma unroll
    for (int ni = 0; ni < 5; ++ni) {
      int col = ni * 16 + (lane & 15);
      if (col < 77) {
        float tv = tinv_s[col];
#pragma unroll
        for (int r = 0; r < 4; ++r) {
          int row = rbase + r;
          if (row < 196) sim[((size_t)b * M_ + row) * N_ + col] = acc[mi][ni][r] * tv;
        }
      }
    }
  }
}

__global__ __launch_bounds__(256) void sim_mfma2(const float* __restrict__ S,
                                                 const ushort* __restrict__ T,
                                                 float* __restrict__ sim) {
  __shared__ __align__(16) ushort lds[768 * 8];
  __shared__ float sinv_s[112];
  __shared__ float tinv_s[80];
  const int b = blockIdx.x >> 1;
  if (blockIdx.x & 1) sim_body<1>(b, S, T, sim, lds, sinv_s, tinv_s);
  else                sim_body<0>(b, S, T, sim, lds, sinv_s, tinv_s);
}

// ---------------- generic tiled f32 GEMM (student path, exact) -------------
template<int BM, int BN, int BK, int TM, int TN>
__global__ __launch_bounds__(256) void gemm_nt(const float* __restrict__ A,
                                               const float* __restrict__ W,
                                               const float* __restrict__ bias,
                                               float* __restrict__ C,
                                               int M, int N, int K) {
  __shared__ float As[BM][BK + 1];
  __shared__ float Ws[BN][BK + 1];
  const int tid = threadIdx.x;
  const int tx = tid & 15, ty = tid >> 4;
  const int row0 = blockIdx.y * BM;
  const int col0 = blockIdx.x * BN;
  float acc[TM][TN];
#pragma unroll
  for (int i = 0; i < TM; ++i)
#pragma unroll
    for (int j = 0; j < TN; ++j) acc[i][j] = 0.f;

  for (int k0 = 0; k0 < K; k0 += BK) {
#pragma unroll
    for (int e = tid; e < BM * BK; e += 256) {
      int r = e / BK, c = e % BK;
      int gr = row0 + r, gc = k0 + c;
      As[r][c] = (gr < M && gc < K) ? A[(size_t)gr * K + gc] : 0.f;
    }
#pragma unroll
    for (int e = tid; e < BN * BK; e += 256) {
      int r = e / BK, c = e % BK;
      int gr = col0 + r, gc = k0 + c;
      Ws[r][c] = (gr < N && gc < K) ? W[(size_t)gr * K + gc] : 0.f;
    }
    __syncthreads();
#pragma unroll
    for (int kk = 0; kk < BK; ++kk) {
      float a[TM], wv[TN];
#pragma unroll
      for (int i = 0; i < TM; ++i) a[i] = As[ty * TM + i][kk];
#pragma unroll
      for (int j = 0; j < TN; ++j) wv[j] = Ws[tx * TN + j][kk];
#pragma unroll
      for (int i = 0; i < TM; ++i)
#pragma unroll
        for (int j = 0; j < TN; ++j) acc[i][j] += a[i] * wv[j];
    }
    __syncthreads();
  }
#pragma unroll
  for (int i = 0; i < TM; ++i) {
    int gr = row0 + ty * TM + i;
    if (gr >= M) continue;
#pragma unroll
    for (int j = 0; j < TN; ++j) {
      int gc = col0 + tx * TN + j;
      if (gc >= N) continue;
      float v = acc[i][j];
      if (bias) v += bias[gc];
      C[(size_t)gr * N + gc] = v;
    }
  }
}

// ---------------- batchnorm (train) over axis 0 ----------------------------
__global__ __launch_bounds__(256) void bn_kernel(const float* __restrict__ X,
                                                 float* __restrict__ Y,
                                                 const float* __restrict__ g,
                                                 const float* __restrict__ b) {
  const int j = blockIdx.x;
  const int tid = threadIdx.x;
  __shared__ float sf[256];
  float vals[2];
  float s = 0.f, s2 = 0.f;
  int idx = 0;
  for (int i = tid; i < B_; i += 256, ++idx) {
    float v = X[(size_t)i * FEAT_ + j];
    vals[idx] = v;
    s += v; s2 += v * v;
  }
  sf[tid] = s; __syncthreads();
  for (int k = 128; k > 0; k >>= 1) { if (tid < k) sf[tid] += sf[tid + k]; __syncthreads(); }
  float mu = sf[0] * (1.f / B_); __syncthreads();
  sf[tid] = s2; __syncthreads();
  for (int k = 128; k > 0; k >>= 1) { if (tid < k) sf[tid] += sf[tid + k]; __syncthreads(); }
  float var = sf[0] * (1.f / B_) - mu * mu;
  float scale = rsqrtf(var + BN_EPS_) * g[j];
  float shift = b[j];
  idx = 0;
  for (int i = tid; i < B_; i += 256, ++idx)
    Y[(size_t)i * FEAT_ + j] = (vals[idx] - mu) * scale + shift;
}

// ---------------- fused CE(teacher) + CE(student+preds) + KL ---------------
__global__ __launch_bounds__(256) void ce_kl_kernel(const float* __restrict__ TL,
                                                    const float* __restrict__ SL,
                                                    const int* __restrict__ label,
                                                    float* __restrict__ acc,
                                                    float* __restrict__ preds) {
  const int row = blockIdx.x;
  const int tid = threadIdx.x;
  const float* tp = TL + (size_t)row * NCLS_;
  const float* sp = SL + (size_t)row * NCLS_;
  __shared__ float red[4][256];
  __shared__ int ridx[256];
  __shared__ float sxl[2];

  float tv[3], sv[3];
#pragma unroll
  for (int k = 0; k < 3; ++k) {
    int j = tid + k * 256;
    tv[k] = (j < NCLS_) ? tp[j] : -INFINITY;
    sv[k] = (j < NCLS_) ? sp[j] : -INFINITY;
  }
  // phase 1: maxT, maxS(+argmax), sumT, sumS
  float mT = -INFINITY, mS = -INFINITY, sT = 0.f, sS = 0.f;
  int ai = NCLS_;
#pragma unroll
  for (int k = 0; k < 3; ++k) {
    int j = tid + k * 256;
    if (j < NCLS_) {
      mT = fmaxf(mT, tv[k]);
      sT += tv[k]; sS += sv[k];
      if (sv[k] > mS) { mS = sv[k]; ai = j; }
    }
  }
  red[0][tid] = mT; red[1][tid] = mS; red[2][tid] = sT; red[3][tid] = sS; ridx[tid] = ai;
  __syncthreads();
  for (int k = 128; k > 0; k >>= 1) {
    if (tid < k) {
      red[0][tid] = fmaxf(red[0][tid], red[0][tid + k]);
      float om = red[1][tid + k]; int oi = ridx[tid + k];
      if (om > red[1][tid] || (om == red[1][tid] && oi < ridx[tid])) { red[1][tid] = om; ridx[tid] = oi; }
      red[2][tid] += red[2][tid + k];
      red[3][tid] += red[3][tid + k];
    }
    __syncthreads();
  }
  const float MT = red[0][0], MS = red[1][0], sumT = red[2][0], sumS = red[3][0];
  const int amax = ridx[0];
  __syncthreads();
  // phase 2: 4 exp-sums
  float etr = 0.f, esr = 0.f, eth = 0.f, esh = 0.f;
#pragma unroll
  for (int k = 0; k < 3; ++k) {
    int j = tid + k * 256;
    if (j < NCLS_) {
      etr += expf(tv[k] - MT);
      esr += expf(sv[k] - MS);
      eth += expf(0.5f * (tv[k] - MT));
      esh += expf(0.5f * (sv[k] - MS));
    }
  }
  red[0][tid] = etr; red[1][tid] = esr; red[2][tid] = eth; red[3][tid] = esh;
  __syncthreads();
  for (int k = 128; k > 0; k >>= 1) {
    if (tid < k) {
      red[0][tid] += red[0][tid + k];
      red[1][tid] += red[1][tid + k];
      red[2][tid] += red[2][tid + k];
      red[3][tid] += red[3][tid + k];
    }
    __syncthreads();
  }
  const float lseT = MT + logf(red[0][0]);
  const float lseS = MS + logf(red[1][0]);
  const float ltH = 0.5f * MT + logf(red[2][0]);
  const float lsH = 0.5f * MS + logf(red[3][0]);
  __syncthreads();
  // phase 3: KL partial + label pick
  const int lab = label[row];
  float klp = 0.f;
#pragma unroll
  for (int k = 0; k < 3; ++k) {
    int j = tid + k * 256;
    if (j < NCLS_) {
      float tlp = 0.5f * tv[k] - ltH;
      float slp = 0.5f * sv[k] - lsH;
      klp += expf(tlp) * (tlp - slp);
      if (j == lab) { sxl[0] = tv[k]; sxl[1] = sv[k]; }
    }
  }
  red[0][tid] = klp;
  __syncthreads();
  for (int k = 128; k > 0; k >>= 1) {
    if (tid < k) red[0][tid] += red[0][tid + k];
    __syncthreads();
  }
  if (tid == 0) {
    float ce_t = -((1.f - LS_EPS_) * (sxl[0] - lseT) + (LS_EPS_ / NCLS_) * (sumT - NCLS_ * lseT));
    float ce_s = -((1.f - LS_EPS_) * (sxl[1] - lseS) + (LS_EPS_ / NCLS_) * (sumS - NCLS_ * lseS));
    atomicAdd(acc + 0, ce_t * (1.f / B_));
    atomicAdd(acc + 2, ce_s * (1.f / B_));
    atomicAdd(acc + 4, red[0][0] * (1.f / B_));
    preds[row] = (float)amax;
  }
}

// ---------------- fused triplet (teacher + student) ------------------------
__global__ __launch_bounds__(256) void triplet2_kernel(const float* __restrict__ Gt,
                                                       const float* __restrict__ Gs,
                                                       const int* __restrict__ label,
                                                       float* __restrict__ acc) {
  const int which = blockIdx.x >> 9;
  const int i = blockIdx.x & 511;
  const float* G = which ? Gs : Gt;
  float* a = acc + (which ? 3 : 1);
  const int tid = threadIdx.x;
  const int li = label[i];
  __shared__ float sap[256], san[256];
  const float sqi = G[(size_t)i * B_ + i];
  float ap = -INFINITY, an = INFINITY;
  for (int j = tid; j < B_; j += 256) {
    float sqj = G[(size_t)j * B_ + j];
    float d2 = sqi + sqj - 2.f * G[(size_t)i * B_ + j];
    float d = sqrtf(fmaxf(d2, 1e-12f));
    if (label[j] == li) ap = fmaxf(ap, d); else an = fminf(an, d);
  }
  sap[tid] = ap; san[tid] = an; __syncthreads();
  for (int k = 128; k > 0; k >>= 1) {
    if (tid < k) {
      sap[tid] = fmaxf(sap[tid], sap[tid + k]);
      san[tid] = fminf(san[tid], san[tid + k]);
    }
    __syncthreads();
  }
  if (tid == 0) atomicAdd(a, fmaxf(sap[0] - san[0] + MARGIN_, 0.f) * (1.f / B_));
}

// ---------------- per-batch Sinkhorn (bf16 K + K^T in LDS) + sim_op --------
#define SKLD 88
#define SKTLD 200
__global__ __launch_bounds__(256) void sinkhorn_kernel(const float* __restrict__ sim,
                                                       float* __restrict__ acc) {
  const int b = blockIdx.x;
  const int tid = threadIdx.x;
  __shared__ __align__(16) ushort Kb[196 * SKLD];    // row-major, 34496 B
  __shared__ __align__(16) ushort KbT[77 * SKTLD];   // col-major, 30800 B
  __shared__ float r[196];
  __shared__ float c[SKLD];
  __shared__ float sf[256];
  __shared__ float cs1[96];
  const float* simb = sim + (size_t)b * (M_ * N_);
  for (int e = tid; e < 196 * SKLD; e += 256) {
    int m = e / SKLD, n = e - m * SKLD;
    if (n < 77) {
      float kv = __expf((simb[m * 77 + n] - 1.f) * 10.f);
      ushort h = f2bf(kv);
      Kb[e] = h;
      KbT[n * SKTLD + m] = h;
    } else Kb[e] = 0;
  }
  if (tid < SKLD) c[tid] = (tid < 77) ? 1.f : 0.f;
  __syncthreads();
  const float uu = 1.f / 196.f, vv = 1.f / 77.f;
  for (int it = 0; it < SINK_ITERS; ++it) {
    if (tid < 196) {
      const ushort* Km = &Kb[tid * SKLD];
      float s = 0.f;
#pragma unroll
      for (int j = 0; j < 11; ++j) {
        fx8 kf = b2f8(*(const sx8*)&Km[j * 8]);
#pragma unroll
        for (int q = 0; q < 8; ++q) s += kf[q] * c[j * 8 + q];
      }
      r[tid] = uu / s;
    }
    __syncthreads();
    if (tid < 154) {
      const int half = (tid >= 77) ? 1 : 0;
      const int n = tid - 77 * half;
      const ushort* Kn = &KbT[n * SKTLD + 96 * half];
      const int m0 = 96 * half;
      float s = 0.f;
#pragma unroll
      for (int j = 0; j < 12; ++j) {
        fx8 kf = b2f8(*(const sx8*)&Kn[j * 8]);
#pragma unroll
        for (int q = 0; q < 8; ++q) s += kf[q] * r[m0 + j * 8 + q];
      }
      if (half) {
        s += bf2f(Kn[96]) * r[192] + bf2f(Kn[97]) * r[193]
           + bf2f(Kn[98]) * r[194] + bf2f(Kn[99]) * r[195];
        cs1[n] = s;
      } else sf[n] = s;
    }
    __syncthreads();
    if (tid < 77) c[tid] = vv / (sf[tid] + cs1[tid]);
    __syncthreads();
  }
  float part = 0.f;
  for (int e = tid; e < M_ * N_; e += 256) {
    int m = e / 77, n = e - m * 77;
    part += r[m] * c[n] * bf2f(Kb[m * SKLD + n]) * simb[e];
  }
  sf[tid] = part; __syncthreads();
  for (int k = 128; k > 0; k >>= 1) { if (tid < k) sf[tid] += sf[tid + k]; __syncthreads(); }
  if (tid == 0) atomicAdd(acc, sf[0] * (1.f / B_));
}

// ---------------- small utils ----------------------------------------------
__global__ void zero_kernel(float* p, int n) {
  int i = blockIdx.x * blockDim.x + threadIdx.x;
  if (i < n) p[i] = 0.f;
}

__global__ void finalize_kernel(const float* __restrict__ acc, float* __restrict__ out) {
  if (threadIdx.x == 0)
    out[0] = acc[0] + acc[1] + acc[2] + acc[3] + acc[4] + (1.f - acc[5]);
}

// ---------------------------------------------------------------------------
extern "C" void kernel_launch(void* const* d_in, const int* in_sizes, int n_in,
                              void* d_out, int out_size, void* d_ws, size_t ws_size,
                              hipStream_t stream) {
  const float* text_feat  = (const float*)d_in[0];
  const float* t_img_raw  = (const float*)d_in[1];
  const float* s_glob_raw = (const float*)d_in[2];
  const float* s_local    = (const float*)d_in[3];
  const int*   label      = (const int*)d_in[4];
  const float* W_tv = (const float*)d_in[5];
  const float* b_tv = (const float*)d_in[6];
  const float* W_tt = (const float*)d_in[7];
  const float* b_tt = (const float*)d_in[8];
  const float* W_sv = (const float*)d_in[9];
  const float* b_sv = (const float*)d_in[10];
  const float* bn_g = (const float*)d_in[11];
  const float* bn_b = (const float*)d_in[12];
  const float* W_ct = (const float*)d_in[13];
  const float* b_ct = (const float*)d_in[14];
  const float* W_cs = (const float*)d_in[15];
  const float* b_cs = (const float*)d_in[16];
  float* out = (float*)d_out;
  float* ws = (float*)d_ws;

  float* tlin   = ws;
  float* timg   = tlin + 262144;
  float* sglob  = timg + 262144;
  float* tlog   = sglob + 262144;
  float* slog   = tlog + 323584;
  float* gram_t = slog + 323584;
  float* gram_s = gram_t + 262144;
  float* acc    = gram_s + 262144;
  ushort* Wbuf  = (ushort*)(acc + 8);
  ushort* ttext = Wbuf + 491520;
  ushort* Abuf  = ttext + 22708224;
  float* sim    = (float*)Abuf;   // alias; Abuf dead before sim written

  dim3 blk(256);
  zero_kernel<<<1, 64, 0, stream>>>(acc, 8);

  // bf16 pre-conversions for the big GEMM
  cvt_bf16_kernel<<<14784, blk, 0, stream>>>(text_feat, Abuf);
  cvt_w_pad<<<240, blk, 0, stream>>>(W_tt, Wbuf);

  // teacher image: bf16 MFMA linear + BN
  gemm_small_mfma<<<dim3(8, 8), blk, 0, stream>>>(t_img_raw, W_tv, b_tv, tlin, FEAT_, TDIM_);
  bn_kernel<<<FEAT_, blk, 0, stream>>>(tlin, timg, bn_g, bn_b);
  // student global linear (f32 exact — preds path)
  gemm_nt<32, 32, 32, 2, 2><<<dim3(16, 16), blk, 0, stream>>>(s_glob_raw, W_sv, b_sv, sglob, 512, FEAT_, LDIM_);
  // classifier logits
  gemm_small_mfma<<<dim3(10, 8), blk, 0, stream>>>(timg, W_ct, b_ct, tlog, NCLS_, FEAT_);
  gemm_nt<32, 32, 32, 2, 2><<<dim3(20, 16), blk, 0, stream>>>(sglob, W_cs, b_cs, slog, 512, NCLS_, FEAT_);
  // fused CE + KL (+ preds)
  ce_kl_kernel<<<B_, blk, 0, stream>>>(tlog, slog, label, acc, out + 1);
  // Gram matrices + fused triplets
  gemm_small_mfma<<<dim3(8, 8), blk, 0, stream>>>(timg, timg, nullptr, gram_t, 512, FEAT_);
  gemm_small_mfma<<<dim3(8, 8), blk, 0, stream>>>(sglob, sglob, nullptr, gram_s, 512, LDIM_);
  triplet2_kernel<<<1024, blk, 0, stream>>>(gram_t, gram_s, label, acc);
  // teacher text features
  gemm_bf16_128<<<dim3(5, 308), blk, 0, stream>>>(Abuf, Wbuf, b_tt, ttext);
  // batched cosine sim (norms fused, M-split, reg-prefetch)
  sim_mfma2<<<dim3(1024), blk, 0, stream>>>(s_local, ttext, sim);
  // sinkhorn + OT loss
  sinkhorn_kernel<<<B_, blk, 0, stream>>>(sim, acc + 5);
  // combine
  finalize_kernel<<<1, 1, 0, stream>>>(acc, out);
}

// Round 6
// 558.703 us; speedup vs baseline: 5.2588x; 1.0531x over previous
//
#include <hip/hip_runtime.h>
#include <math.h>

#define B_     512
#define M_     196
#define N_     77
#define FEAT_  512
#define NCLS_  632
#define TDIM_  768
#define LDIM_  576
#define LS_EPS_ 0.1f
#define MARGIN_ 0.3f
#define BN_EPS_ 1e-5f
#define SINK_ITERS 12

typedef float fx4 __attribute__((ext_vector_type(4)));
typedef float fx8 __attribute__((ext_vector_type(8)));
typedef short sx8 __attribute__((ext_vector_type(8)));
typedef __bf16 bfx8 __attribute__((ext_vector_type(8)));

__device__ inline ushort f2bf(float f) {
  union { float f; uint u; } v; v.f = f;
  uint u = v.u;
  return (ushort)((u + 0x7FFFu + ((u >> 16) & 1u)) >> 16);
}
__device__ inline float bf2f(ushort b) {
  union { uint u; float f; } v; v.u = ((uint)b) << 16;
  return v.f;
}
__device__ inline sx8 cvt8(fx8 f) {
  bfx8 h = __builtin_convertvector(f, bfx8);
  return __builtin_bit_cast(sx8, h);
}
__device__ inline fx8 b2f8(sx8 s) {
  bfx8 h = __builtin_bit_cast(bfx8, s);
  return __builtin_convertvector(h, fx8);
}
__device__ inline fx4 mfma16(sx8 a, sx8 b, fx4 c) {
  return __builtin_amdgcn_mfma_f32_16x16x32_bf16(
      __builtin_bit_cast(bfx8, a), __builtin_bit_cast(bfx8, b), c, 0, 0, 0);
}
__device__ inline void gload_lds16(const void* g, void* l) {
  auto gp = (const __attribute__((address_space(1))) uint*)(uintptr_t)g;
  auto lp = (__attribute__((address_space(3))) uint*)(uintptr_t)l;
  __builtin_amdgcn_global_load_lds(gp, lp, 16, 0, 0);
}

// ---------------- f32 -> bf16 conversions ----------------------------------
__global__ __launch_bounds__(256) void cvt_bf16_kernel(const float* __restrict__ X,
                                                       ushort* __restrict__ Y) {
  size_t i = (size_t)blockIdx.x * 256 + threadIdx.x;
  fx8 f = *(const fx8*)(X + i * 8);
  *(sx8*)(Y + i * 8) = cvt8(f);
}

__global__ __launch_bounds__(256) void cvt_w_pad(const float* __restrict__ W,
                                                 ushort* __restrict__ Y) {
  int i = blockIdx.x * 256 + threadIdx.x;  // chunk of 8; 640*96 chunks
  int row = i / 96;
  if (row < 576) {
    fx8 f = *(const fx8*)(W + (size_t)i * 8);
    *(sx8*)(Y + (size_t)i * 8) = cvt8(f);
  } else {
    sx8 z = {0, 0, 0, 0, 0, 0, 0, 0};
    *(sx8*)(Y + (size_t)i * 8) = z;
  }
}

// ============ ttext GEMM (m97 structure): C[39424,576] = A @ Wb^T + bias ====
__global__ __launch_bounds__(256) void gemm_bf16_128(const ushort* __restrict__ A,
                                                     const ushort* __restrict__ Bm,
                                                     const float* __restrict__ bias,
                                                     ushort* __restrict__ C) {
  __shared__ __align__(16) ushort ldsA[4096];
  __shared__ __align__(16) ushort ldsB[4096];
  const int tid = threadIdx.x;
  const int lane = tid & 63;
  const int w = tid >> 6;
  const int wr = w >> 1, wc = w & 1;
  const int row0 = blockIdx.y * 128;
  const int col0 = blockIdx.x * 128;
  const int l16 = lane & 15, k8 = (lane >> 4) * 8;

  const ushort* gA0 = A + (size_t)(row0 + (2 * w) * 16 + l16) * TDIM_ + k8;
  const ushort* gA1 = A + (size_t)(row0 + (2 * w + 1) * 16 + l16) * TDIM_ + k8;
  const ushort* gB0 = Bm + (size_t)(col0 + (2 * w) * 16 + l16) * TDIM_ + k8;
  const ushort* gB1 = Bm + (size_t)(col0 + (2 * w + 1) * 16 + l16) * TDIM_ + k8;
  ushort* lA0 = &ldsA[(2 * w) * 512];
  ushort* lA1 = &ldsA[(2 * w + 1) * 512];
  ushort* lB0 = &ldsB[(2 * w) * 512];
  ushort* lB1 = &ldsB[(2 * w + 1) * 512];

  fx4 acc[4][4];
  const fx4 zz = {0.f, 0.f, 0.f, 0.f};
#pragma unroll
  for (int i = 0; i < 4; ++i)
#pragma unroll
    for (int j = 0; j < 4; ++j) acc[i][j] = zz;

  for (int kt = 0; kt < 24; ++kt) {
    if (kt) __syncthreads();
    const int ko = kt * 32;
    gload_lds16(gA0 + ko, lA0);
    gload_lds16(gA1 + ko, lA1);
    gload_lds16(gB0 + ko, lB0);
    gload_lds16(gB1 + ko, lB1);
    asm volatile("s_waitcnt vmcnt(0)" ::: "memory");
    __syncthreads();
    sx8 af[4], bf[4];
#pragma unroll
    for (int mi = 0; mi < 4; ++mi) af[mi] = *(sx8*)&ldsA[((wr * 4 + mi) * 64 + lane) * 8];
#pragma unroll
    for (int ni = 0; ni < 4; ++ni) bf[ni] = *(sx8*)&ldsB[((wc * 4 + ni) * 64 + lane) * 8];
#pragma unroll
    for (int mi = 0; mi < 4; ++mi)
#pragma unroll
      for (int ni = 0; ni < 4; ++ni) acc[mi][ni] = mfma16(af[mi], bf[ni], acc[mi][ni]);
  }

#pragma unroll
  for (int mi = 0; mi < 4; ++mi) {
    int rbase = row0 + wr * 64 + mi * 16 + ((lane >> 4) << 2);
#pragma unroll
    for (int ni = 0; ni < 4; ++ni) {
      int col = col0 + wc * 64 + ni * 16 + l16;
      if (col < 576) {
        float bv = bias[col];
#pragma unroll
        for (int r = 0; r < 4; ++r)
          C[(size_t)(rbase + r) * 576 + col] = f2bf(acc[mi][ni][r] + bv);
      }
    }
  }
}

// ============ small bf16 MFMA GEMM ==========================================
__global__ __launch_bounds__(256) void gemm_small_mfma(const float* __restrict__ A,
                                                       const float* __restrict__ Wm,
                                                       const float* __restrict__ bias,
                                                       float* __restrict__ C,
                                                       int N, int K) {
  __shared__ __align__(16) ushort ldsA[2048];
  __shared__ __align__(16) ushort ldsW[2048];
  const int tid = threadIdx.x;
  const int lane = tid & 63;
  const int wv = tid >> 6;
  const int wr = wv >> 1, wc = wv & 1;
  const int row0 = blockIdx.y * 64;
  const int col0 = blockIdx.x * 64;
  const int mt = tid >> 6;
  const int l16 = lane & 15;
  const int k8 = lane >> 4;

  const float* pA = A + (size_t)(row0 + mt * 16 + l16) * K + k8 * 8;
  int wcl = col0 + mt * 16 + l16;
  if (wcl >= N) wcl = N - 1;
  const float* pW = Wm + (size_t)wcl * K + k8 * 8;

  fx4 acc[2][2];
  const fx4 zz = {0.f, 0.f, 0.f, 0.f};
  acc[0][0] = zz; acc[0][1] = zz; acc[1][0] = zz; acc[1][1] = zz;

  sx8 ua = cvt8(*(const fx8*)pA);
  sx8 uw = cvt8(*(const fx8*)pW);
  const int NT = K >> 5;
  for (int kt = 0; kt < NT; ++kt) {
    if (kt) __syncthreads();
    *(sx8*)&ldsA[tid * 8] = ua;
    *(sx8*)&ldsW[tid * 8] = uw;
    __syncthreads();
    if (kt + 1 < NT) {
      ua = cvt8(*(const fx8*)(pA + (kt + 1) * 32));
      uw = cvt8(*(const fx8*)(pW + (kt + 1) * 32));
    }
    sx8 af[2], bf[2];
#pragma unroll
    for (int mi = 0; mi < 2; ++mi) af[mi] = *(sx8*)&ldsA[((wr * 2 + mi) * 64 + lane) * 8];
#pragma unroll
    for (int ni = 0; ni < 2; ++ni) bf[ni] = *(sx8*)&ldsW[((wc * 2 + ni) * 64 + lane) * 8];
#pragma unroll
    for (int mi = 0; mi < 2; ++mi)
#pragma unroll
      for (int ni = 0; ni < 2; ++ni) acc[mi][ni] = mfma16(af[mi], bf[ni], acc[mi][ni]);
  }
#pragma unroll
  for (int mi = 0; mi < 2; ++mi) {
    int rbase = row0 + (wr * 2 + mi) * 16 + ((lane >> 4) << 2);
#pragma unroll
    for (int ni = 0; ni < 2; ++ni) {
      int col = col0 + (wc * 2 + ni) * 16 + l16;
      if (col < N) {
        float bv = bias ? bias[col] : 0.f;
#pragma unroll
        for (int r = 0; r < 4; ++r)
          C[(size_t)(rbase + r) * N + col] = acc[mi][ni][r] + bv;
      }
    }
  }
}

// ============ batched cosine sim, 3-way M-split, norms fused into K-loop ====
// sim = (s.t) * sinv * tinv  — norms accumulated DURING staging (each row is
// covered by exactly 4 lanes of one wave; combine via shfl_xor 16/32).
template<int H>
__device__ void sim_body(int b, const float* __restrict__ S, const ushort* __restrict__ T,
                         float* __restrict__ sim, ushort* lds, float* sinv_s, float* tinv_s) {
  constexpr int NTILE = (H == 2) ? 5 : 4;        // S row tiles of 16
  constexpr int NS = NTILE * 64;                 // S staging chunks
  constexpr int NC = NS + 320;                   // + 5 T tiles
  constexpr int M0 = H * 64;
  const int tid = threadIdx.x;
  const int lane = tid & 63;
  const int w = tid >> 6;

  // per-thread staging chunk assignment (3 chunks max)
  bool val[3], isS[3];
  const float* pS[3];
  const ushort* pT[3];
  int rowi[3], cidx[3];
  bool k0lane[3];
#pragma unroll
  for (int j = 0; j < 3; ++j) {
    int c = tid + j * 256;
    cidx[j] = c;
    val[j] = (c < NC);
    isS[j] = (c < NS);
    k0lane[j] = (((c >> 4) & 3) == 0);
    if (c < NS) {
      int tile = c >> 6;
      int r = M0 + tile * 16 + (c & 15);
      int rr = r < 196 ? r : 195;
      int ks = ((c >> 4) & 3) * 8;
      pS[j] = S + ((size_t)b * M_ + rr) * LDIM_ + ks;
      rowi[j] = rr - M0;
      pT[j] = T;
    } else {
      int cc = c - NS;
      int tile = cc >> 6;
      int r = tile * 16 + (cc & 15);
      int rr = r < 77 ? r : 76;
      int ks = ((cc >> 4) & 3) * 8;
      pT[j] = T + ((size_t)b * N_ + rr) * LDIM_ + ks;
      pS[j] = S;
      rowi[j] = rr;
    }
  }

  // prefetch kt=0
  fx8 fS[3]; sx8 tS[3];
#pragma unroll
  for (int j = 0; j < 3; ++j) {
    if (!val[j]) continue;
    if (isS[j]) fS[j] = *(const fx8*)pS[j];
    else tS[j] = *(const sx8*)pT[j];
  }

  float ss[3] = {0.f, 0.f, 0.f};
  fx4 acc[2][5];
  const fx4 zz = {0.f, 0.f, 0.f, 0.f};
#pragma unroll
  for (int i = 0; i < 2; ++i)
#pragma unroll
    for (int j = 0; j < 5; ++j) acc[i][j] = zz;

  for (int kt = 0; kt < 18; ++kt) {
    if (kt) __syncthreads();
#pragma unroll
    for (int j = 0; j < 3; ++j) {
      if (!val[j]) continue;
      if (isS[j]) {
        *(sx8*)&lds[cidx[j] * 8] = cvt8(fS[j]);
#pragma unroll
        for (int q = 0; q < 8; ++q) ss[j] += fS[j][q] * fS[j][q];
      } else {
        *(sx8*)&lds[cidx[j] * 8] = tS[j];
        fx8 tf = b2f8(tS[j]);
#pragma unroll
        for (int q = 0; q < 8; ++q) ss[j] += tf[q] * tf[q];
      }
    }
    __syncthreads();
    if (kt < 17) {
      const int ko = (kt + 1) * 32;
#pragma unroll
      for (int j = 0; j < 3; ++j) {
        if (!val[j]) continue;
        if (isS[j]) fS[j] = *(const fx8*)(pS[j] + ko);
        else tS[j] = *(const sx8*)(pT[j] + ko);
      }
    }
    sx8 bfr[5];
#pragma unroll
    for (int ni = 0; ni < 5; ++ni) bfr[ni] = *(sx8*)&lds[(NS + ni * 64 + lane) * 8];
#pragma unroll
    for (int mi = 0; mi < 2; ++mi) {
      int lt = w + mi * 4;
      if (lt < NTILE) {
        sx8 af = *(sx8*)&lds[(lt * 64 + lane) * 8];
#pragma unroll
        for (int ni = 0; ni < 5; ++ni) acc[mi][ni] = mfma16(af, bfr[ni], acc[mi][ni]);
      }
    }
  }

  // combine 4 partial sumsq per row (lanes l16, +16, +32, +48 of same wave)
#pragma unroll
  for (int j = 0; j < 3; ++j) {
    if (!val[j]) continue;
    float s = ss[j];
    s += __shfl_xor(s, 16);
    s += __shfl_xor(s, 32);
    if (k0lane[j]) {
      float inv = 1.f / fmaxf(sqrtf(s), 1e-12f);
      if (isS[j]) sinv_s[rowi[j]] = inv;
      else        tinv_s[rowi[j]] = inv;
    }
  }
  __syncthreads();

#pragma unroll
  for (int mi = 0; mi < 2; ++mi) {
    int lt = w + mi * 4;
    if (lt >= NTILE) continue;
    int lrbase = lt * 16 + ((lane >> 4) << 2);
#pragma unroll
    for (int ni = 0; ni < 5; ++ni) {
      int col = ni * 16 + (lane & 15);
      if (col < 77) {
        float tv = tinv_s[col];
#pragma unroll
        for (int r = 0; r < 4; ++r) {
          int lrow = lrbase + r;
          int row = M0 + lrow;
          if (row < 196)
            sim[((size_t)b * M_ + row) * N_ + col] = acc[mi][ni][r] * sinv_s[lrow] * tv;
        }
      }
    }
  }
}

__global__ __launch_bounds__(256) void sim_mfma3(const float* __restrict__ S,
                                                 const ushort* __restrict__ T,
                                                 float* __restrict__ sim) {
  __shared__ __align__(16) ushort lds[640 * 8];
  __shared__ float sinv_s[80];
  __shared__ float tinv_s[80];
  const int q = blockIdx.x >> 9;
  const int b = blockIdx.x & 511;
  if (q == 0)      sim_body<0>(b, S, T, sim, lds, sinv_s, tinv_s);
  else if (q == 1) sim_body<1>(b, S, T, sim, lds, sinv_s, tinv_s);
  else             sim_body<2>(b, S, T, sim, lds, sinv_s, tinv_s);
}

// ---------------- generic tiled f32 GEMM (student path, exact) -------------
template<int BM, int BN, int BK, int TM, int TN>
__global__ __launch_bounds__(256) void gemm_nt(const float* __restrict__ A,
                                               const float* __restrict__ W,
                                               const float* __restrict__ bias,
                                               float* __restrict__ C,
                                               int M, int N, int K) {
  __shared__ float As[BM][BK + 1];
  __shared__ float Ws[BN][BK + 1];
  const int tid = threadIdx.x;
  const int tx = tid & 15, ty = tid >> 4;
  const int row0 = blockIdx.y * BM;
  const int col0 = blockIdx.x * BN;
  float acc[TM][TN];
#pragma unroll
  for (int i = 0; i < TM; ++i)
#pragma unroll
    for (int j = 0; j < TN; ++j) acc[i][j] = 0.f;

  for (int k0 = 0; k0 < K; k0 += BK) {
#pragma unroll
    for (int e = tid; e < BM * BK; e += 256) {
      int r = e / BK, c = e % BK;
      int gr = row0 + r, gc = k0 + c;
      As[r][c] = (gr < M && gc < K) ? A[(size_t)gr * K + gc] : 0.f;
    }
#pragma unroll
    for (int e = tid; e < BN * BK; e += 256) {
      int r = e / BK, c = e % BK;
      int gr = col0 + r, gc = k0 + c;
      Ws[r][c] = (gr < N && gc < K) ? W[(size_t)gr * K + gc] : 0.f;
    }
    __syncthreads();
#pragma unroll
    for (int kk = 0; kk < BK; ++kk) {
      float a[TM], wv[TN];
#pragma unroll
      for (int i = 0; i < TM; ++i) a[i] = As[ty * TM + i][kk];
#pragma unroll
      for (int j = 0; j < TN; ++j) wv[j] = Ws[tx * TN + j][kk];
#pragma unroll
      for (int i = 0; i < TM; ++i)
#pragma unroll
        for (int j = 0; j < TN; ++j) acc[i][j] += a[i] * wv[j];
    }
    __syncthreads();
  }
#pragma unroll
  for (int i = 0; i < TM; ++i) {
    int gr = row0 + ty * TM + i;
    if (gr >= M) continue;
#pragma unroll
    for (int j = 0; j < TN; ++j) {
      int gc = col0 + tx * TN + j;
      if (gc >= N) continue;
      float v = acc[i][j];
      if (bias) v += bias[gc];
      C[(size_t)gr * N + gc] = v;
    }
  }
}

// ---------------- batchnorm (train) over axis 0 ----------------------------
__global__ __launch_bounds__(256) void bn_kernel(const float* __restrict__ X,
                                                 float* __restrict__ Y,
                                                 const float* __restrict__ g,
                                                 const float* __restrict__ b) {
  const int j = blockIdx.x;
  const int tid = threadIdx.x;
  __shared__ float sf[256];
  float vals[2];
  float s = 0.f, s2 = 0.f;
  int idx = 0;
  for (int i = tid; i < B_; i += 256, ++idx) {
    float v = X[(size_t)i * FEAT_ + j];
    vals[idx] = v;
    s += v; s2 += v * v;
  }
  sf[tid] = s; __syncthreads();
  for (int k = 128; k > 0; k >>= 1) { if (tid < k) sf[tid] += sf[tid + k]; __syncthreads(); }
  float mu = sf[0] * (1.f / B_); __syncthreads();
  sf[tid] = s2; __syncthreads();
  for (int k = 128; k > 0; k >>= 1) { if (tid < k) sf[tid] += sf[tid + k]; __syncthreads(); }
  float var = sf[0] * (1.f / B_) - mu * mu;
  float scale = rsqrtf(var + BN_EPS_) * g[j];
  float shift = b[j];
  idx = 0;
  for (int i = tid; i < B_; i += 256, ++idx)
    Y[(size_t)i * FEAT_ + j] = (vals[idx] - mu) * scale + shift;
}

// ---------------- fused CE(teacher) + CE(student+preds) + KL ---------------
__global__ __launch_bounds__(256) void ce_kl_kernel(const float* __restrict__ TL,
                                                    const float* __restrict__ SL,
                                                    const int* __restrict__ label,
                                                    float* __restrict__ acc,
                                                    float* __restrict__ preds) {
  const int row = blockIdx.x;
  const int tid = threadIdx.x;
  const float* tp = TL + (size_t)row * NCLS_;
  const float* sp = SL + (size_t)row * NCLS_;
  __shared__ float red[4][256];
  __shared__ int ridx[256];
  __shared__ float sxl[2];

  float tv[3], sv[3];
#pragma unroll
  for (int k = 0; k < 3; ++k) {
    int j = tid + k * 256;
    tv[k] = (j < NCLS_) ? tp[j] : -INFINITY;
    sv[k] = (j < NCLS_) ? sp[j] : -INFINITY;
  }
  float mT = -INFINITY, mS = -INFINITY, sT = 0.f, sS = 0.f;
  int ai = NCLS_;
#pragma unroll
  for (int k = 0; k < 3; ++k) {
    int j = tid + k * 256;
    if (j < NCLS_) {
      mT = fmaxf(mT, tv[k]);
      sT += tv[k]; sS += sv[k];
      if (sv[k] > mS) { mS = sv[k]; ai = j; }
    }
  }
  red[0][tid] = mT; red[1][tid] = mS; red[2][tid] = sT; red[3][tid] = sS; ridx[tid] = ai;
  __syncthreads();
  for (int k = 128; k > 0; k >>= 1) {
    if (tid < k) {
      red[0][tid] = fmaxf(red[0][tid], red[0][tid + k]);
      float om = red[1][tid + k]; int oi = ridx[tid + k];
      if (om > red[1][tid] || (om == red[1][tid] && oi < ridx[tid])) { red[1][tid] = om; ridx[tid] = oi; }
      red[2][tid] += red[2][tid + k];
      red[3][tid] += red[3][tid + k];
    }
    __syncthreads();
  }
  const float MT = red[0][0], MS = red[1][0], sumT = red[2][0], sumS = red[3][0];
  const int amax = ridx[0];
  __syncthreads();
  float etr = 0.f, esr = 0.f, eth = 0.f, esh = 0.f;
#pragma unroll
  for (int k = 0; k < 3; ++k) {
    int j = tid + k * 256;
    if (j < NCLS_) {
      etr += expf(tv[k] - MT);
      esr += expf(sv[k] - MS);
      eth += expf(0.5f * (tv[k] - MT));
      esh += expf(0.5f * (sv[k] - MS));
    }
  }
  red[0][tid] = etr; red[1][tid] = esr; red[2][tid] = eth; red[3][tid] = esh;
  __syncthreads();
  for (int k = 128; k > 0; k >>= 1) {
    if (tid < k) {
      red[0][tid] += red[0][tid + k];
      red[1][tid] += red[1][tid + k];
      red[2][tid] += red[2][tid + k];
      red[3][tid] += red[3][tid + k];
    }
    __syncthreads();
  }
  const float lseT = MT + logf(red[0][0]);
  const float lseS = MS + logf(red[1][0]);
  const float ltH = 0.5f * MT + logf(red[2][0]);
  const float lsH = 0.5f * MS + logf(red[3][0]);
  __syncthreads();
  const int lab = label[row];
  float klp = 0.f;
#pragma unroll
  for (int k = 0; k < 3; ++k) {
    int j = tid + k * 256;
    if (j < NCLS_) {
      float tlp = 0.5f * tv[k] - ltH;
      float slp = 0.5f * sv[k] - lsH;
      klp += expf(tlp) * (tlp - slp);
      if (j == lab) { sxl[0] = tv[k]; sxl[1] = sv[k]; }
    }
  }
  red[0][tid] = klp;
  __syncthreads();
  for (int k = 128; k > 0; k >>= 1) {
    if (tid < k) red[0][tid] += red[0][tid + k];
    __syncthreads();
  }
  if (tid == 0) {
    float ce_t = -((1.f - LS_EPS_) * (sxl[0] - lseT) + (LS_EPS_ / NCLS_) * (sumT - NCLS_ * lseT));
    float ce_s = -((1.f - LS_EPS_) * (sxl[1] - lseS) + (LS_EPS_ / NCLS_) * (sumS - NCLS_ * lseS));
    atomicAdd(acc + 0, ce_t * (1.f / B_));
    atomicAdd(acc + 2, ce_s * (1.f / B_));
    atomicAdd(acc + 4, red[0][0] * (1.f / B_));
    preds[row] = (float)amax;
  }
}

// ---------------- fused triplet (teacher + student) ------------------------
__global__ __launch_bounds__(256) void triplet2_kernel(const float* __restrict__ Gt,
                                                       const float* __restrict__ Gs,
                                                       const int* __restrict__ label,
                                                       float* __restrict__ acc) {
  const int which = blockIdx.x >> 9;
  const int i = blockIdx.x & 511;
  const float* G = which ? Gs : Gt;
  float* a = acc + (which ? 3 : 1);
  const int tid = threadIdx.x;
  const int li = label[i];
  __shared__ float sap[256], san[256];
  const float sqi = G[(size_t)i * B_ + i];
  float ap = -INFINITY, an = INFINITY;
  for (int j = tid; j < B_; j += 256) {
    float sqj = G[(size_t)j * B_ + j];
    float d2 = sqi + sqj - 2.f * G[(size_t)i * B_ + j];
    float d = sqrtf(fmaxf(d2, 1e-12f));
    if (label[j] == li) ap = fmaxf(ap, d); else an = fminf(an, d);
  }
  sap[tid] = ap; san[tid] = an; __syncthreads();
  for (int k = 128; k > 0; k >>= 1) {
    if (tid < k) {
      sap[tid] = fmaxf(sap[tid], sap[tid + k]);
      san[tid] = fminf(san[tid], san[tid + k]);
    }
    __syncthreads();
  }
  if (tid == 0) atomicAdd(a, fmaxf(sap[0] - san[0] + MARGIN_, 0.f) * (1.f / B_));
}

// ---------------- per-batch Sinkhorn (bf16 K + K^T in LDS) + sim_op --------
#define SKLD 88
#define SKTLD 200
__global__ __launch_bounds__(256) void sinkhorn_kernel(const float* __restrict__ sim,
                                                       float* __restrict__ acc) {
  const int b = blockIdx.x;
  const int tid = threadIdx.x;
  __shared__ __align__(16) ushort Kb[196 * SKLD];
  __shared__ __align__(16) ushort KbT[77 * SKTLD];
  __shared__ float r[196];
  __shared__ float c[SKLD];
  __shared__ float sf[256];
  __shared__ float cs1[96];
  const float* simb = sim + (size_t)b * (M_ * N_);
  for (int e = tid; e < 196 * SKLD; e += 256) {
    int m = e / SKLD, n = e - m * SKLD;
    if (n < 77) {
      float kv = __expf((simb[m * 77 + n] - 1.f) * 10.f);
      ushort h = f2bf(kv);
      Kb[e] = h;
      KbT[n * SKTLD + m] = h;
    } else Kb[e] = 0;
  }
  if (tid < SKLD) c[tid] = (tid < 77) ? 1.f : 0.f;
  __syncthreads();
  const float uu = 1.f / 196.f, vv = 1.f / 77.f;
  for (int it = 0; it < SINK_ITERS; ++it) {
    if (tid < 196) {
      const ushort* Km = &Kb[tid * SKLD];
      float s = 0.f;
#pragma unroll
      for (int j = 0; j < 11; ++j) {
        fx8 kf = b2f8(*(const sx8*)&Km[j * 8]);
#pragma unroll
        for (int q = 0; q < 8; ++q) s += kf[q] * c[j * 8 + q];
      }
      r[tid] = uu / s;
    }
    __syncthreads();
    if (tid < 154) {
      const int half = (tid >= 77) ? 1 : 0;
      const int n = tid - 77 * half;
      const ushort* Kn = &KbT[n * SKTLD + 96 * half];
      const int m0 = 96 * half;
      float s = 0.f;
#pragma unroll
      for (int j = 0; j < 12; ++j) {
        fx8 kf = b2f8(*(const sx8*)&Kn[j * 8]);
#pragma unroll
        for (int q = 0; q < 8; ++q) s += kf[q] * r[m0 + j * 8 + q];
      }
      if (half) {
        s += bf2f(Kn[96]) * r[192] + bf2f(Kn[97]) * r[193]
           + bf2f(Kn[98]) * r[194] + bf2f(Kn[99]) * r[195];
        cs1[n] = s;
      } else sf[n] = s;
    }
    __syncthreads();
    if (tid < 77) c[tid] = vv / (sf[tid] + cs1[tid]);
    __syncthreads();
  }
  float part = 0.f;
  for (int e = tid; e < M_ * N_; e += 256) {
    int m = e / 77, n = e - m * 77;
    part += r[m] * c[n] * bf2f(Kb[m * SKLD + n]) * simb[e];
  }
  sf[tid] = part; __syncthreads();
  for (int k = 128; k > 0; k >>= 1) { if (tid < k) sf[tid] += sf[tid + k]; __syncthreads(); }
  if (tid == 0) atomicAdd(acc, sf[0] * (1.f / B_));
}

// ---------------- small utils ----------------------------------------------
__global__ void zero_kernel(float* p, int n) {
  int i = blockIdx.x * blockDim.x + threadIdx.x;
  if (i < n) p[i] = 0.f;
}

__global__ void finalize_kernel(const float* __restrict__ acc, float* __restrict__ out) {
  if (threadIdx.x == 0)
    out[0] = acc[0] + acc[1] + acc[2] + acc[3] + acc[4] + (1.f - acc[5]);
}

// ---------------------------------------------------------------------------
extern "C" void kernel_launch(void* const* d_in, const int* in_sizes, int n_in,
                              void* d_out, int out_size, void* d_ws, size_t ws_size,
                              hipStream_t stream) {
  const float* text_feat  = (const float*)d_in[0];
  const float* t_img_raw  = (const float*)d_in[1];
  const float* s_glob_raw = (const float*)d_in[2];
  const float* s_local    = (const float*)d_in[3];
  const int*   label      = (const int*)d_in[4];
  const float* W_tv = (const float*)d_in[5];
  const float* b_tv = (const float*)d_in[6];
  const float* W_tt = (const float*)d_in[7];
  const float* b_tt = (const float*)d_in[8];
  const float* W_sv = (const float*)d_in[9];
  const float* b_sv = (const float*)d_in[10];
  const float* bn_g = (const float*)d_in[11];
  const float* bn_b = (const float*)d_in[12];
  const float* W_ct = (const float*)d_in[13];
  const float* b_ct = (const float*)d_in[14];
  const float* W_cs = (const float*)d_in[15];
  const float* b_cs = (const float*)d_in[16];
  float* out = (float*)d_out;
  float* ws = (float*)d_ws;

  float* tlin   = ws;
  float* timg   = tlin + 262144;
  float* sglob  = timg + 262144;
  float* tlog   = sglob + 262144;
  float* slog   = tlog + 323584;
  float* gram_t = slog + 323584;
  float* gram_s = gram_t + 262144;
  float* acc    = gram_s + 262144;
  ushort* Wbuf  = (ushort*)(acc + 8);
  ushort* ttext = Wbuf + 491520;
  ushort* Abuf  = ttext + 22708224;
  float* sim    = (float*)Abuf;   // alias; Abuf dead before sim written

  dim3 blk(256);
  zero_kernel<<<1, 64, 0, stream>>>(acc, 8);

  // bf16 pre-conversions for the big GEMM
  cvt_bf16_kernel<<<14784, blk, 0, stream>>>(text_feat, Abuf);
  cvt_w_pad<<<240, blk, 0, stream>>>(W_tt, Wbuf);

  // teacher image: bf16 MFMA linear + BN
  gemm_small_mfma<<<dim3(8, 8), blk, 0, stream>>>(t_img_raw, W_tv, b_tv, tlin, FEAT_, TDIM_);
  bn_kernel<<<FEAT_, blk, 0, stream>>>(tlin, timg, bn_g, bn_b);
  // student global linear (f32 exact — preds path)
  gemm_nt<32, 32, 32, 2, 2><<<dim3(16, 16), blk, 0, stream>>>(s_glob_raw, W_sv, b_sv, sglob, 512, FEAT_, LDIM_);
  // classifier logits
  gemm_small_mfma<<<dim3(10, 8), blk, 0, stream>>>(timg, W_ct, b_ct, tlog, NCLS_, FEAT_);
  gemm_nt<32, 32, 32, 2, 2><<<dim3(20, 16), blk, 0, stream>>>(sglob, W_cs, b_cs, slog, 512, NCLS_, FEAT_);
  // fused CE + KL (+ preds)
  ce_kl_kernel<<<B_, blk, 0, stream>>>(tlog, slog, label, acc, out + 1);
  // Gram matrices + fused triplets
  gemm_small_mfma<<<dim3(8, 8), blk, 0, stream>>>(timg, timg, nullptr, gram_t, 512, FEAT_);
  gemm_small_mfma<<<dim3(8, 8), blk, 0, stream>>>(sglob, sglob, nullptr, gram_s, 512, LDIM_);
  triplet2_kernel<<<1024, blk, 0, stream>>>(gram_t, gram_s, label, acc);
  // teacher text features
  gemm_bf16_128<<<dim3(5, 308), blk, 0, stream>>>(Abuf, Wbuf, b_tt, ttext);
  // batched cosine sim (3-way M-split, norms fused into K-loop)
  sim_mfma3<<<dim3(1536), blk, 0, stream>>>(s_local, ttext, sim);
  // sinkhorn + OT loss
  sinkhorn_kernel<<<B_, blk, 0, stream>>>(sim, acc + 5);
  // combine
  finalize_kernel<<<1, 1, 0, stream>>>(acc, out);
}

// Round 7
// 436.501 us; speedup vs baseline: 6.7311x; 1.2800x over previous
//
#include <hip/hip_runtime.h>
#include <math.h>

#define B_     512
#define M_     196
#define N_     77
#define FEAT_  512
#define NCLS_  632
#define TDIM_  768
#define LDIM_  576
#define LS_EPS_ 0.1f
#define MARGIN_ 0.3f
#define BN_EPS_ 1e-5f
#define SINK_ITERS 12

typedef float fx4 __attribute__((ext_vector_type(4)));
typedef float fx8 __attribute__((ext_vector_type(8)));
typedef short sx8 __attribute__((ext_vector_type(8)));
typedef __bf16 bfx8 __attribute__((ext_vector_type(8)));

__device__ inline ushort f2bf(float f) {
  union { float f; uint u; } v; v.f = f;
  uint u = v.u;
  return (ushort)((u + 0x7FFFu + ((u >> 16) & 1u)) >> 16);
}
__device__ inline float bf2f(ushort b) {
  union { uint u; float f; } v; v.u = ((uint)b) << 16;
  return v.f;
}
__device__ inline sx8 cvt8(fx8 f) {
  bfx8 h = __builtin_convertvector(f, bfx8);
  return __builtin_bit_cast(sx8, h);
}
__device__ inline fx8 b2f8(sx8 s) {
  bfx8 h = __builtin_bit_cast(bfx8, s);
  return __builtin_convertvector(h, fx8);
}
__device__ inline fx4 mfma16(sx8 a, sx8 b, fx4 c) {
  return __builtin_amdgcn_mfma_f32_16x16x32_bf16(
      __builtin_bit_cast(bfx8, a), __builtin_bit_cast(bfx8, b), c, 0, 0, 0);
}
__device__ inline void gload_lds16(const void* g, void* l) {
  auto gp = (const __attribute__((address_space(1))) uint*)(uintptr_t)g;
  auto lp = (__attribute__((address_space(3))) uint*)(uintptr_t)l;
  __builtin_amdgcn_global_load_lds(gp, lp, 16, 0, 0);
}

// ---------------- prep: zero acc + W_tt -> bf16 padded ---------------------
__global__ __launch_bounds__(256) void prep_kernel(const float* __restrict__ W,
                                                   ushort* __restrict__ Y,
                                                   float* __restrict__ acc) {
  const int bid = blockIdx.x;
  if (bid == 240) {
    if (threadIdx.x < 8) acc[threadIdx.x] = 0.f;
    return;
  }
  int i = bid * 256 + threadIdx.x;  // chunk of 8; 640*96 chunks
  int row = i / 96;
  if (row < 576) {
    fx8 f = *(const fx8*)(W + (size_t)i * 8);
    *(sx8*)(Y + (size_t)i * 8) = cvt8(f);
  } else {
    sx8 z = {0, 0, 0, 0, 0, 0, 0, 0};
    *(sx8*)(Y + (size_t)i * 8) = z;
  }
}

// ---------------- text_feat f32 -> bf16 ------------------------------------
__global__ __launch_bounds__(256) void cvt_bf16_kernel(const float* __restrict__ X,
                                                       ushort* __restrict__ Y) {
  size_t i = (size_t)blockIdx.x * 256 + threadIdx.x;
  fx8 f = *(const fx8*)(X + i * 8);
  *(sx8*)(Y + i * 8) = cvt8(f);
}

// ============ device bodies for merged stages ===============================
// small bf16 MFMA GEMM body: C[*,N] = A @ W^T (+bias); tile 64x64, BK=32
__device__ inline void small_mfma_body(char* smem, int bx, int by,
                                       const float* __restrict__ A,
                                       const float* __restrict__ Wm,
                                       const float* __restrict__ bias,
                                       float* __restrict__ C, int N, int K) {
  ushort* ldsA = (ushort*)smem;
  ushort* ldsW = (ushort*)(smem + 4096);
  const int tid = threadIdx.x;
  const int lane = tid & 63;
  const int wv = tid >> 6;
  const int wr = wv >> 1, wc = wv & 1;
  const int row0 = by * 64;
  const int col0 = bx * 64;
  const int mt = tid >> 6;
  const int l16 = lane & 15;
  const int k8 = lane >> 4;

  const float* pA = A + (size_t)(row0 + mt * 16 + l16) * K + k8 * 8;
  int wcl = col0 + mt * 16 + l16;
  if (wcl >= N) wcl = N - 1;
  const float* pW = Wm + (size_t)wcl * K + k8 * 8;

  fx4 acc[2][2];
  const fx4 zz = {0.f, 0.f, 0.f, 0.f};
  acc[0][0] = zz; acc[0][1] = zz; acc[1][0] = zz; acc[1][1] = zz;

  sx8 ua = cvt8(*(const fx8*)pA);
  sx8 uw = cvt8(*(const fx8*)pW);
  const int NT = K >> 5;
  for (int kt = 0; kt < NT; ++kt) {
    if (kt) __syncthreads();
    *(sx8*)&ldsA[tid * 8] = ua;
    *(sx8*)&ldsW[tid * 8] = uw;
    __syncthreads();
    if (kt + 1 < NT) {
      ua = cvt8(*(const fx8*)(pA + (kt + 1) * 32));
      uw = cvt8(*(const fx8*)(pW + (kt + 1) * 32));
    }
    sx8 af[2], bf[2];
#pragma unroll
    for (int mi = 0; mi < 2; ++mi) af[mi] = *(sx8*)&ldsA[((wr * 2 + mi) * 64 + lane) * 8];
#pragma unroll
    for (int ni = 0; ni < 2; ++ni) bf[ni] = *(sx8*)&ldsW[((wc * 2 + ni) * 64 + lane) * 8];
#pragma unroll
    for (int mi = 0; mi < 2; ++mi)
#pragma unroll
      for (int ni = 0; ni < 2; ++ni) acc[mi][ni] = mfma16(af[mi], bf[ni], acc[mi][ni]);
  }
#pragma unroll
  for (int mi = 0; mi < 2; ++mi) {
    int rbase = row0 + (wr * 2 + mi) * 16 + ((lane >> 4) << 2);
#pragma unroll
    for (int ni = 0; ni < 2; ++ni) {
      int col = col0 + (wc * 2 + ni) * 16 + l16;
      if (col < N) {
        float bv = bias ? bias[col] : 0.f;
#pragma unroll
        for (int r = 0; r < 4; ++r)
          C[(size_t)(rbase + r) * N + col] = acc[mi][ni][r] + bv;
      }
    }
  }
}

// f32 exact GEMM body (student path): tile 32x32, BK=32, TM=TN=2
__device__ inline void gemm_nt32_body(char* smem, int bx, int by,
                                      const float* __restrict__ A,
                                      const float* __restrict__ W,
                                      const float* __restrict__ bias,
                                      float* __restrict__ C, int Mr, int N, int K) {
  float (*As)[33] = (float (*)[33])smem;
  float (*Ws)[33] = (float (*)[33])(smem + 4224);
  const int tid = threadIdx.x;
  const int tx = tid & 15, ty = tid >> 4;
  const int row0 = by * 32;
  const int col0 = bx * 32;
  float acc[2][2] = {{0.f, 0.f}, {0.f, 0.f}};

  for (int k0 = 0; k0 < K; k0 += 32) {
#pragma unroll
    for (int e = tid; e < 32 * 32; e += 256) {
      int r = e / 32, c = e % 32;
      int gr = row0 + r, gc = k0 + c;
      As[r][c] = (gr < Mr && gc < K) ? A[(size_t)gr * K + gc] : 0.f;
    }
#pragma unroll
    for (int e = tid; e < 32 * 32; e += 256) {
      int r = e / 32, c = e % 32;
      int gr = col0 + r, gc = k0 + c;
      Ws[r][c] = (gr < N && gc < K) ? W[(size_t)gr * K + gc] : 0.f;
    }
    __syncthreads();
#pragma unroll
    for (int kk = 0; kk < 32; ++kk) {
      float a[2], wv[2];
#pragma unroll
      for (int i = 0; i < 2; ++i) a[i] = As[ty * 2 + i][kk];
#pragma unroll
      for (int j = 0; j < 2; ++j) wv[j] = Ws[tx * 2 + j][kk];
#pragma unroll
      for (int i = 0; i < 2; ++i)
#pragma unroll
        for (int j = 0; j < 2; ++j) acc[i][j] += a[i] * wv[j];
    }
    __syncthreads();
  }
#pragma unroll
  for (int i = 0; i < 2; ++i) {
    int gr = row0 + ty * 2 + i;
    if (gr >= Mr) continue;
#pragma unroll
    for (int j = 0; j < 2; ++j) {
      int gc = col0 + tx * 2 + j;
      if (gc >= N) continue;
      float v = acc[i][j];
      if (bias) v += bias[gc];
      C[(size_t)gr * N + gc] = v;
    }
  }
}

// ---------------- stage1: tlin (MFMA, 64 blk) || sglob (f32, 256 blk) ------
__global__ __launch_bounds__(256) void stage1_kernel(const float* __restrict__ t_img_raw,
                                                     const float* __restrict__ W_tv,
                                                     const float* __restrict__ b_tv,
                                                     float* __restrict__ tlin,
                                                     const float* __restrict__ s_glob_raw,
                                                     const float* __restrict__ W_sv,
                                                     const float* __restrict__ b_sv,
                                                     float* __restrict__ sglob) {
  __shared__ __align__(16) char pool[8448];
  const int bid = blockIdx.x;
  if (bid < 64) {
    small_mfma_body(pool, bid & 7, bid >> 3, t_img_raw, W_tv, b_tv, tlin, FEAT_, TDIM_);
  } else {
    int i = bid - 64;
    gemm_nt32_body(pool, i & 15, i >> 4, s_glob_raw, W_sv, b_sv, sglob, 512, FEAT_, LDIM_);
  }
}

// ---------------- batchnorm (train) over axis 0 ----------------------------
__global__ __launch_bounds__(256) void bn_kernel(const float* __restrict__ X,
                                                 float* __restrict__ Y,
                                                 const float* __restrict__ g,
                                                 const float* __restrict__ b) {
  const int j = blockIdx.x;
  const int tid = threadIdx.x;
  __shared__ float sf[256];
  float vals[2];
  float s = 0.f, s2 = 0.f;
  int idx = 0;
  for (int i = tid; i < B_; i += 256, ++idx) {
    float v = X[(size_t)i * FEAT_ + j];
    vals[idx] = v;
    s += v; s2 += v * v;
  }
  sf[tid] = s; __syncthreads();
  for (int k = 128; k > 0; k >>= 1) { if (tid < k) sf[tid] += sf[tid + k]; __syncthreads(); }
  float mu = sf[0] * (1.f / B_); __syncthreads();
  sf[tid] = s2; __syncthreads();
  for (int k = 128; k > 0; k >>= 1) { if (tid < k) sf[tid] += sf[tid + k]; __syncthreads(); }
  float var = sf[0] * (1.f / B_) - mu * mu;
  float scale = rsqrtf(var + BN_EPS_) * g[j];
  float shift = b[j];
  idx = 0;
  for (int i = tid; i < B_; i += 256, ++idx)
    Y[(size_t)i * FEAT_ + j] = (vals[idx] - mu) * scale + shift;
}

// ---------------- stage2: tlog || slog || gram_t || gram_s -----------------
__global__ __launch_bounds__(256) void stage2_kernel(const float* __restrict__ timg,
                                                     const float* __restrict__ W_ct,
                                                     const float* __restrict__ b_ct,
                                                     float* __restrict__ tlog,
                                                     const float* __restrict__ sglob,
                                                     const float* __restrict__ W_cs,
                                                     const float* __restrict__ b_cs,
                                                     float* __restrict__ slog,
                                                     float* __restrict__ gram_t,
                                                     float* __restrict__ gram_s) {
  __shared__ __align__(16) char pool[8448];
  const int bid = blockIdx.x;
  if (bid < 80) {
    small_mfma_body(pool, bid % 10, bid / 10, timg, W_ct, b_ct, tlog, NCLS_, FEAT_);
  } else if (bid < 400) {
    int i = bid - 80;
    gemm_nt32_body(pool, i % 20, i / 20, sglob, W_cs, b_cs, slog, 512, NCLS_, FEAT_);
  } else if (bid < 464) {
    int i = bid - 400;
    small_mfma_body(pool, i & 7, i >> 3, timg, timg, nullptr, gram_t, 512, FEAT_);
  } else {
    int i = bid - 464;
    small_mfma_body(pool, i & 7, i >> 3, sglob, sglob, nullptr, gram_s, 512, LDIM_);
  }
}

// ============ stage3 bodies: ce_kl + triplet ================================
__device__ inline void ce_kl_body(char* pool, int row,
                                  const float* __restrict__ TL,
                                  const float* __restrict__ SL,
                                  const int* __restrict__ label,
                                  float* __restrict__ acc,
                                  float* __restrict__ preds) {
  const int tid = threadIdx.x;
  const float* tp = TL + (size_t)row * NCLS_;
  const float* sp = SL + (size_t)row * NCLS_;
  float (*red)[256] = (float (*)[256])pool;          // 4096 B
  int* ridx = (int*)(pool + 4096);                   // 1024 B
  float* sxl = (float*)(pool + 5120);                // 8 B

  float tv[3], sv[3];
#pragma unroll
  for (int k = 0; k < 3; ++k) {
    int j = tid + k * 256;
    tv[k] = (j < NCLS_) ? tp[j] : -INFINITY;
    sv[k] = (j < NCLS_) ? sp[j] : -INFINITY;
  }
  float mT = -INFINITY, mS = -INFINITY, sT = 0.f, sS = 0.f;
  int ai = NCLS_;
#pragma unroll
  for (int k = 0; k < 3; ++k) {
    int j = tid + k * 256;
    if (j < NCLS_) {
      mT = fmaxf(mT, tv[k]);
      sT += tv[k]; sS += sv[k];
      if (sv[k] > mS) { mS = sv[k]; ai = j; }
    }
  }
  red[0][tid] = mT; red[1][tid] = mS; red[2][tid] = sT; red[3][tid] = sS; ridx[tid] = ai;
  __syncthreads();
  for (int k = 128; k > 0; k >>= 1) {
    if (tid < k) {
      red[0][tid] = fmaxf(red[0][tid], red[0][tid + k]);
      float om = red[1][tid + k]; int oi = ridx[tid + k];
      if (om > red[1][tid] || (om == red[1][tid] && oi < ridx[tid])) { red[1][tid] = om; ridx[tid] = oi; }
      red[2][tid] += red[2][tid + k];
      red[3][tid] += red[3][tid + k];
    }
    __syncthreads();
  }
  const float MT = red[0][0], MS = red[1][0], sumT = red[2][0], sumS = red[3][0];
  const int amax = ridx[0];
  __syncthreads();
  float etr = 0.f, esr = 0.f, eth = 0.f, esh = 0.f;
#pragma unroll
  for (int k = 0; k < 3; ++k) {
    int j = tid + k * 256;
    if (j < NCLS_) {
      etr += expf(tv[k] - MT);
      esr += expf(sv[k] - MS);
      eth += expf(0.5f * (tv[k] - MT));
      esh += expf(0.5f * (sv[k] - MS));
    }
  }
  red[0][tid] = etr; red[1][tid] = esr; red[2][tid] = eth; red[3][tid] = esh;
  __syncthreads();
  for (int k = 128; k > 0; k >>= 1) {
    if (tid < k) {
      red[0][tid] += red[0][tid + k];
      red[1][tid] += red[1][tid + k];
      red[2][tid] += red[2][tid + k];
      red[3][tid] += red[3][tid + k];
    }
    __syncthreads();
  }
  const float lseT = MT + logf(red[0][0]);
  const float lseS = MS + logf(red[1][0]);
  const float ltH = 0.5f * MT + logf(red[2][0]);
  const float lsH = 0.5f * MS + logf(red[3][0]);
  __syncthreads();
  const int lab = label[row];
  float klp = 0.f;
#pragma unroll
  for (int k = 0; k < 3; ++k) {
    int j = tid + k * 256;
    if (j < NCLS_) {
      float tlp = 0.5f * tv[k] - ltH;
      float slp = 0.5f * sv[k] - lsH;
      klp += expf(tlp) * (tlp - slp);
      if (j == lab) { sxl[0] = tv[k]; sxl[1] = sv[k]; }
    }
  }
  red[0][tid] = klp;
  __syncthreads();
  for (int k = 128; k > 0; k >>= 1) {
    if (tid < k) red[0][tid] += red[0][tid + k];
    __syncthreads();
  }
  if (tid == 0) {
    float ce_t = -((1.f - LS_EPS_) * (sxl[0] - lseT) + (LS_EPS_ / NCLS_) * (sumT - NCLS_ * lseT));
    float ce_s = -((1.f - LS_EPS_) * (sxl[1] - lseS) + (LS_EPS_ / NCLS_) * (sumS - NCLS_ * lseS));
    atomicAdd(acc + 0, ce_t * (1.f / B_));
    atomicAdd(acc + 2, ce_s * (1.f / B_));
    atomicAdd(acc + 4, red[0][0] * (1.f / B_));
    preds[row] = (float)amax;
  }
}

__device__ inline void triplet_body(char* pool, int which, int i,
                                    const float* __restrict__ Gt,
                                    const float* __restrict__ Gs,
                                    const int* __restrict__ label,
                                    float* __restrict__ acc) {
  const float* G = which ? Gs : Gt;
  float* a = acc + (which ? 3 : 1);
  const int tid = threadIdx.x;
  const int li = label[i];
  float* sap = (float*)pool;
  float* san = (float*)(pool + 1024);
  const float sqi = G[(size_t)i * B_ + i];
  float ap = -INFINITY, an = INFINITY;
  for (int j = tid; j < B_; j += 256) {
    float sqj = G[(size_t)j * B_ + j];
    float d2 = sqi + sqj - 2.f * G[(size_t)i * B_ + j];
    float d = sqrtf(fmaxf(d2, 1e-12f));
    if (label[j] == li) ap = fmaxf(ap, d); else an = fminf(an, d);
  }
  sap[tid] = ap; san[tid] = an; __syncthreads();
  for (int k = 128; k > 0; k >>= 1) {
    if (tid < k) {
      sap[tid] = fmaxf(sap[tid], sap[tid + k]);
      san[tid] = fminf(san[tid], san[tid + k]);
    }
    __syncthreads();
  }
  if (tid == 0) atomicAdd(a, fmaxf(sap[0] - san[0] + MARGIN_, 0.f) * (1.f / B_));
}

__global__ __launch_bounds__(256) void stage3_kernel(const float* __restrict__ tlog,
                                                     const float* __restrict__ slog,
                                                     const float* __restrict__ gram_t,
                                                     const float* __restrict__ gram_s,
                                                     const int* __restrict__ label,
                                                     float* __restrict__ acc,
                                                     float* __restrict__ preds) {
  __shared__ __align__(16) char pool[5200];
  const int bid = blockIdx.x;
  if (bid < 512) ce_kl_body(pool, bid, tlog, slog, label, acc, preds);
  else {
    int i = bid - 512;
    triplet_body(pool, i >> 9, i & 511, gram_t, gram_s, label, acc);
  }
}

// ============ ttext GEMM (m97 structure, XCD-swizzled) ======================
__global__ __launch_bounds__(256) void gemm_bf16_128(const ushort* __restrict__ A,
                                                     const ushort* __restrict__ Bm,
                                                     const float* __restrict__ bias,
                                                     ushort* __restrict__ C) {
  __shared__ __align__(16) ushort ldsA[4096];
  __shared__ __align__(16) ushort ldsB[4096];
  // bijective XCD swizzle: nwg=1540, q=192, r=4
  const int bid = blockIdx.x;
  const int xcd = bid & 7, wi = bid >> 3;
  const int swz = (xcd < 4 ? xcd * 193 : 772 + (xcd - 4) * 192) + wi;
  const int by = swz / 5, bx = swz - by * 5;

  const int tid = threadIdx.x;
  const int lane = tid & 63;
  const int w = tid >> 6;
  const int wr = w >> 1, wc = w & 1;
  const int row0 = by * 128;
  const int col0 = bx * 128;
  const int l16 = lane & 15, k8 = (lane >> 4) * 8;

  const ushort* gA0 = A + (size_t)(row0 + (2 * w) * 16 + l16) * TDIM_ + k8;
  const ushort* gA1 = A + (size_t)(row0 + (2 * w + 1) * 16 + l16) * TDIM_ + k8;
  const ushort* gB0 = Bm + (size_t)(col0 + (2 * w) * 16 + l16) * TDIM_ + k8;
  const ushort* gB1 = Bm + (size_t)(col0 + (2 * w + 1) * 16 + l16) * TDIM_ + k8;
  ushort* lA0 = &ldsA[(2 * w) * 512];
  ushort* lA1 = &ldsA[(2 * w + 1) * 512];
  ushort* lB0 = &ldsB[(2 * w) * 512];
  ushort* lB1 = &ldsB[(2 * w + 1) * 512];

  fx4 acc[4][4];
  const fx4 zz = {0.f, 0.f, 0.f, 0.f};
#pragma unroll
  for (int i = 0; i < 4; ++i)
#pragma unroll
    for (int j = 0; j < 4; ++j) acc[i][j] = zz;

  for (int kt = 0; kt < 24; ++kt) {
    if (kt) __syncthreads();
    const int ko = kt * 32;
    gload_lds16(gA0 + ko, lA0);
    gload_lds16(gA1 + ko, lA1);
    gload_lds16(gB0 + ko, lB0);
    gload_lds16(gB1 + ko, lB1);
    asm volatile("s_waitcnt vmcnt(0)" ::: "memory");
    __syncthreads();
    sx8 af[4], bf[4];
#pragma unroll
    for (int mi = 0; mi < 4; ++mi) af[mi] = *(sx8*)&ldsA[((wr * 4 + mi) * 64 + lane) * 8];
#pragma unroll
    for (int ni = 0; ni < 4; ++ni) bf[ni] = *(sx8*)&ldsB[((wc * 4 + ni) * 64 + lane) * 8];
#pragma unroll
    for (int mi = 0; mi < 4; ++mi)
#pragma unroll
      for (int ni = 0; ni < 4; ++ni) acc[mi][ni] = mfma16(af[mi], bf[ni], acc[mi][ni]);
  }

#pragma unroll
  for (int mi = 0; mi < 4; ++mi) {
    int rbase = row0 + wr * 64 + mi * 16 + ((lane >> 4) << 2);
#pragma unroll
    for (int ni = 0; ni < 4; ++ni) {
      int col = col0 + wc * 64 + ni * 16 + l16;
      if (col < 576) {
        float bv = bias[col];
#pragma unroll
        for (int r = 0; r < 4; ++r)
          C[(size_t)(rbase + r) * 576 + col] = f2bf(acc[mi][ni][r] + bv);
      }
    }
  }
}

// ============ batched cosine sim, 3-way M-split, bf16 out ===================
template<int H>
__device__ void sim_body(int b, const float* __restrict__ S, const ushort* __restrict__ T,
                         ushort* __restrict__ sim, ushort* lds, float* sinv_s, float* tinv_s) {
  constexpr int NTILE = (H == 2) ? 5 : 4;
  constexpr int NS = NTILE * 64;
  constexpr int NC = NS + 320;
  constexpr int M0 = H * 64;
  const int tid = threadIdx.x;
  const int lane = tid & 63;
  const int w = tid >> 6;

  bool val[3], isS[3];
  const float* pS[3];
  const ushort* pT[3];
  int rowi[3], cidx[3];
  bool k0lane[3];
#pragma unroll
  for (int j = 0; j < 3; ++j) {
    int c = tid + j * 256;
    cidx[j] = c;
    val[j] = (c < NC);
    isS[j] = (c < NS);
    k0lane[j] = (((c >> 4) & 3) == 0);
    if (c < NS) {
      int tile = c >> 6;
      int r = M0 + tile * 16 + (c & 15);
      int rr = r < 196 ? r : 195;
      int ks = ((c >> 4) & 3) * 8;
      pS[j] = S + ((size_t)b * M_ + rr) * LDIM_ + ks;
      rowi[j] = rr - M0;
      pT[j] = T;
    } else {
      int cc = c - NS;
      int tile = cc >> 6;
      int r = tile * 16 + (cc & 15);
      int rr = r < 77 ? r : 76;
      int ks = ((cc >> 4) & 3) * 8;
      pT[j] = T + ((size_t)b * N_ + rr) * LDIM_ + ks;
      pS[j] = S;
      rowi[j] = rr;
    }
  }

  fx8 fS[3]; sx8 tS[3];
#pragma unroll
  for (int j = 0; j < 3; ++j) {
    if (!val[j]) continue;
    if (isS[j]) fS[j] = *(const fx8*)pS[j];
    else tS[j] = *(const sx8*)pT[j];
  }

  float ss[3] = {0.f, 0.f, 0.f};
  fx4 acc[2][5];
  const fx4 zz = {0.f, 0.f, 0.f, 0.f};
#pragma unroll
  for (int i = 0; i < 2; ++i)
#pragma unroll
    for (int j = 0; j < 5; ++j) acc[i][j] = zz;

  for (int kt = 0; kt < 18; ++kt) {
    if (kt) __syncthreads();
#pragma unroll
    for (int j = 0; j < 3; ++j) {
      if (!val[j]) continue;
      if (isS[j]) {
        *(sx8*)&lds[cidx[j] * 8] = cvt8(fS[j]);
#pragma unroll
        for (int q = 0; q < 8; ++q) ss[j] += fS[j][q] * fS[j][q];
      } else {
        *(sx8*)&lds[cidx[j] * 8] = tS[j];
        fx8 tf = b2f8(tS[j]);
#pragma unroll
        for (int q = 0; q < 8; ++q) ss[j] += tf[q] * tf[q];
      }
    }
    __syncthreads();
    if (kt < 17) {
      const int ko = (kt + 1) * 32;
#pragma unroll
      for (int j = 0; j < 3; ++j) {
        if (!val[j]) continue;
        if (isS[j]) fS[j] = *(const fx8*)(pS[j] + ko);
        else tS[j] = *(const sx8*)(pT[j] + ko);
      }
    }
    sx8 bfr[5];
#pragma unroll
    for (int ni = 0; ni < 5; ++ni) bfr[ni] = *(sx8*)&lds[(NS + ni * 64 + lane) * 8];
#pragma unroll
    for (int mi = 0; mi < 2; ++mi) {
      int lt = w + mi * 4;
      if (lt < NTILE) {
        sx8 af = *(sx8*)&lds[(lt * 64 + lane) * 8];
#pragma unroll
        for (int ni = 0; ni < 5; ++ni) acc[mi][ni] = mfma16(af, bfr[ni], acc[mi][ni]);
      }
    }
  }

#pragma unroll
  for (int j = 0; j < 3; ++j) {
    if (!val[j]) continue;
    float s = ss[j];
    s += __shfl_xor(s, 16);
    s += __shfl_xor(s, 32);
    if (k0lane[j]) {
      float inv = 1.f / fmaxf(sqrtf(s), 1e-12f);
      if (isS[j]) sinv_s[rowi[j]] = inv;
      else        tinv_s[rowi[j]] = inv;
    }
  }
  __syncthreads();

#pragma unroll
  for (int mi = 0; mi < 2; ++mi) {
    int lt = w + mi * 4;
    if (lt >= NTILE) continue;
    int lrbase = lt * 16 + ((lane >> 4) << 2);
#pragma unroll
    for (int ni = 0; ni < 5; ++ni) {
      int col = ni * 16 + (lane & 15);
      if (col < 77) {
        float tv = tinv_s[col];
#pragma unroll
        for (int r = 0; r < 4; ++r) {
          int lrow = lrbase + r;
          int row = M0 + lrow;
          if (row < 196)
            sim[((size_t)b * M_ + row) * N_ + col] = f2bf(acc[mi][ni][r] * sinv_s[lrow] * tv);
        }
      }
    }
  }
}

__global__ __launch_bounds__(256) void sim_mfma4(const float* __restrict__ S,
                                                 const ushort* __restrict__ T,
                                                 ushort* __restrict__ sim) {
  __shared__ __align__(16) ushort lds[640 * 8];
  __shared__ float sinv_s[80];
  __shared__ float tinv_s[80];
  // XCD-chunked swizzle (nwg=1536, cpx=192), b-major so 3 splits of b adjacent
  const int bid = blockIdx.x;
  const int swz = (bid & 7) * 192 + (bid >> 3);
  const int b = swz / 3;
  const int q = swz - b * 3;
  if (q == 0)      sim_body<0>(b, S, T, sim, lds, sinv_s, tinv_s);
  else if (q == 1) sim_body<1>(b, S, T, sim, lds, sinv_s, tinv_s);
  else             sim_body<2>(b, S, T, sim, lds, sinv_s, tinv_s);
}

// ---------------- per-batch Sinkhorn (bf16 sim in) + fused finalize --------
#define SKLD 88
#define SKTLD 200
__global__ __launch_bounds__(256) void sinkhorn_kernel(const ushort* __restrict__ sim,
                                                       float* __restrict__ acc,
                                                       float* __restrict__ out) {
  const int b = blockIdx.x;
  const int tid = threadIdx.x;
  __shared__ __align__(16) ushort Kb[196 * SKLD];
  __shared__ __align__(16) ushort KbT[77 * SKTLD];
  __shared__ float r[196];
  __shared__ float c[SKLD];
  __shared__ float sf[256];
  __shared__ float cs1[96];
  const ushort* simb = sim + (size_t)b * (M_ * N_);
  for (int e = tid; e < 196 * SKLD; e += 256) {
    int m = e / SKLD, n = e - m * SKLD;
    if (n < 77) {
      float sv = bf2f(simb[m * 77 + n]);
      ushort h = f2bf(__expf((sv - 1.f) * 10.f));
      Kb[e] = h;
      KbT[n * SKTLD + m] = h;
    } else Kb[e] = 0;
  }
  if (tid < SKLD) c[tid] = (tid < 77) ? 1.f : 0.f;
  __syncthreads();
  const float uu = 1.f / 196.f, vv = 1.f / 77.f;
  for (int it = 0; it < SINK_ITERS; ++it) {
    if (tid < 196) {
      const ushort* Km = &Kb[tid * SKLD];
      float s = 0.f;
#pragma unroll
      for (int j = 0; j < 11; ++j) {
        fx8 kf = b2f8(*(const sx8*)&Km[j * 8]);
#pragma unroll
        for (int q = 0; q < 8; ++q) s += kf[q] * c[j * 8 + q];
      }
      r[tid] = uu / s;
    }
    __syncthreads();
    if (tid < 154) {
      const int half = (tid >= 77) ? 1 : 0;
      const int n = tid - 77 * half;
      const ushort* Kn = &KbT[n * SKTLD + 96 * half];
      const int m0 = 96 * half;
      float s = 0.f;
#pragma unroll
      for (int j = 0; j < 12; ++j) {
        fx8 kf = b2f8(*(const sx8*)&Kn[j * 8]);
#pragma unroll
        for (int q = 0; q < 8; ++q) s += kf[q] * r[m0 + j * 8 + q];
      }
      if (half) {
        s += bf2f(Kn[96]) * r[192] + bf2f(Kn[97]) * r[193]
           + bf2f(Kn[98]) * r[194] + bf2f(Kn[99]) * r[195];
        cs1[n] = s;
      } else sf[n] = s;
    }
    __syncthreads();
    if (tid < 77) c[tid] = vv / (sf[tid] + cs1[tid]);
    __syncthreads();
  }
  float part = 0.f;
  for (int e = tid; e < M_ * N_; e += 256) {
    int m = e / 77, n = e - m * 77;
    part += r[m] * c[n] * bf2f(Kb[m * SKLD + n]) * bf2f(simb[e]);
  }
  sf[tid] = part; __syncthreads();
  for (int k = 128; k > 0; k >>= 1) { if (tid < k) sf[tid] += sf[tid + k]; __syncthreads(); }
  if (tid == 0) {
    atomicAdd(acc + 5, sf[0] * (1.f / B_));
    __threadfence();
    uint prev = atomicAdd((uint*)(acc + 6), 1u);
    if (prev == B_ - 1) {
      // last block: finalize (atomic reads for cross-XCD coherence)
      float a0 = atomicAdd(acc + 0, 0.f);
      float a1 = atomicAdd(acc + 1, 0.f);
      float a2 = atomicAdd(acc + 2, 0.f);
      float a3 = atomicAdd(acc + 3, 0.f);
      float a4 = atomicAdd(acc + 4, 0.f);
      float a5 = atomicAdd(acc + 5, 0.f);
      out[0] = a0 + a1 + a2 + a3 + a4 + (1.f - a5);
    }
  }
}

// ---------------------------------------------------------------------------
extern "C" void kernel_launch(void* const* d_in, const int* in_sizes, int n_in,
                              void* d_out, int out_size, void* d_ws, size_t ws_size,
                              hipStream_t stream) {
  const float* text_feat  = (const float*)d_in[0];
  const float* t_img_raw  = (const float*)d_in[1];
  const float* s_glob_raw = (const float*)d_in[2];
  const float* s_local    = (const float*)d_in[3];
  const int*   label      = (const int*)d_in[4];
  const float* W_tv = (const float*)d_in[5];
  const float* b_tv = (const float*)d_in[6];
  const float* W_tt = (const float*)d_in[7];
  const float* b_tt = (const float*)d_in[8];
  const float* W_sv = (const float*)d_in[9];
  const float* b_sv = (const float*)d_in[10];
  const float* bn_g = (const float*)d_in[11];
  const float* bn_b = (const float*)d_in[12];
  const float* W_ct = (const float*)d_in[13];
  const float* b_ct = (const float*)d_in[14];
  const float* W_cs = (const float*)d_in[15];
  const float* b_cs = (const float*)d_in[16];
  float* out = (float*)d_out;
  float* ws = (float*)d_ws;

  float* tlin   = ws;
  float* timg   = tlin + 262144;
  float* sglob  = timg + 262144;
  float* tlog   = sglob + 262144;
  float* slog   = tlog + 323584;
  float* gram_t = slog + 323584;
  float* gram_s = gram_t + 262144;
  float* acc    = gram_s + 262144;
  ushort* Wbuf  = (ushort*)(acc + 8);
  ushort* ttext = Wbuf + 491520;
  ushort* Abuf  = ttext + 22708224;
  ushort* sim   = Abuf;   // alias; Abuf dead before sim written

  dim3 blk(256);

  // L1: zero acc + W_tt -> bf16 (padded)
  prep_kernel<<<241, blk, 0, stream>>>(W_tt, Wbuf, acc);
  // L2: text_feat -> bf16
  cvt_bf16_kernel<<<14784, blk, 0, stream>>>(text_feat, Abuf);
  // L3: tlin (MFMA) || sglob (f32 exact)
  stage1_kernel<<<320, blk, 0, stream>>>(t_img_raw, W_tv, b_tv, tlin,
                                         s_glob_raw, W_sv, b_sv, sglob);
  // L4: batchnorm
  bn_kernel<<<FEAT_, blk, 0, stream>>>(tlin, timg, bn_g, bn_b);
  // L5: tlog || slog || gram_t || gram_s
  stage2_kernel<<<528, blk, 0, stream>>>(timg, W_ct, b_ct, tlog,
                                         sglob, W_cs, b_cs, slog, gram_t, gram_s);
  // L6: ce_kl (+preds) || triplet x2
  stage3_kernel<<<1536, blk, 0, stream>>>(tlog, slog, gram_t, gram_s, label, acc, out + 1);
  // L7: teacher text features (XCD-swizzled)
  gemm_bf16_128<<<1540, blk, 0, stream>>>(Abuf, Wbuf, b_tt, ttext);
  // L8: batched cosine sim -> bf16
  sim_mfma4<<<1536, blk, 0, stream>>>(s_local, ttext, sim);
  // L9: sinkhorn + OT loss + fused finalize
  sinkhorn_kernel<<<B_, blk, 0, stream>>>(sim, acc, out);
}

// Round 8
// 408.197 us; speedup vs baseline: 7.1978x; 1.0693x over previous
//
#include <hip/hip_runtime.h>
#include <math.h>

#define B_     512
#define M_     196
#define N_     77
#define FEAT_  512
#define NCLS_  632
#define TDIM_  768
#define LDIM_  576
#define LS_EPS_ 0.1f
#define MARGIN_ 0.3f
#define BN_EPS_ 1e-5f
#define SINK_ITERS 12

typedef float fx4 __attribute__((ext_vector_type(4)));
typedef float fx8 __attribute__((ext_vector_type(8)));
typedef short sx8 __attribute__((ext_vector_type(8)));
typedef __bf16 bfx8 __attribute__((ext_vector_type(8)));

__device__ inline ushort f2bf(float f) {
  union { float f; uint u; } v; v.f = f;
  uint u = v.u;
  return (ushort)((u + 0x7FFFu + ((u >> 16) & 1u)) >> 16);
}
__device__ inline float bf2f(ushort b) {
  union { uint u; float f; } v; v.u = ((uint)b) << 16;
  return v.f;
}
__device__ inline sx8 cvt8(fx8 f) {
  bfx8 h = __builtin_convertvector(f, bfx8);
  return __builtin_bit_cast(sx8, h);
}
__device__ inline fx8 b2f8(sx8 s) {
  bfx8 h = __builtin_bit_cast(bfx8, s);
  return __builtin_convertvector(h, fx8);
}
__device__ inline fx4 mfma16(sx8 a, sx8 b, fx4 c) {
  return __builtin_amdgcn_mfma_f32_16x16x32_bf16(
      __builtin_bit_cast(bfx8, a), __builtin_bit_cast(bfx8, b), c, 0, 0, 0);
}
__device__ inline void gload_lds16(const void* g, void* l) {
  auto gp = (const __attribute__((address_space(1))) uint*)(uintptr_t)g;
  auto lp = (__attribute__((address_space(3))) uint*)(uintptr_t)l;
  __builtin_amdgcn_global_load_lds(gp, lp, 16, 0, 0);
}

// ===================== device bodies ========================================

// small bf16 MFMA GEMM body: 64x64 tile, BK=32 (teacher path)
__device__ inline void small_mfma_body(char* smem, int bx, int by,
                                       const float* __restrict__ A,
                                       const float* __restrict__ Wm,
                                       const float* __restrict__ bias,
                                       float* __restrict__ C, int N, int K) {
  ushort* ldsA = (ushort*)smem;
  ushort* ldsW = (ushort*)(smem + 4096);
  const int tid = threadIdx.x;
  const int lane = tid & 63;
  const int wv = tid >> 6;
  const int wr = wv >> 1, wc = wv & 1;
  const int row0 = by * 64;
  const int col0 = bx * 64;
  const int mt = tid >> 6;
  const int l16 = lane & 15;
  const int k8 = lane >> 4;

  const float* pA = A + (size_t)(row0 + mt * 16 + l16) * K + k8 * 8;
  int wcl = col0 + mt * 16 + l16;
  if (wcl >= N) wcl = N - 1;
  const float* pW = Wm + (size_t)wcl * K + k8 * 8;

  fx4 acc[2][2];
  const fx4 zz = {0.f, 0.f, 0.f, 0.f};
  acc[0][0] = zz; acc[0][1] = zz; acc[1][0] = zz; acc[1][1] = zz;

  sx8 ua = cvt8(*(const fx8*)pA);
  sx8 uw = cvt8(*(const fx8*)pW);
  const int NT = K >> 5;
  for (int kt = 0; kt < NT; ++kt) {
    if (kt) __syncthreads();
    *(sx8*)&ldsA[tid * 8] = ua;
    *(sx8*)&ldsW[tid * 8] = uw;
    __syncthreads();
    if (kt + 1 < NT) {
      ua = cvt8(*(const fx8*)(pA + (kt + 1) * 32));
      uw = cvt8(*(const fx8*)(pW + (kt + 1) * 32));
    }
    sx8 af[2], bf[2];
#pragma unroll
    for (int mi = 0; mi < 2; ++mi) af[mi] = *(sx8*)&ldsA[((wr * 2 + mi) * 64 + lane) * 8];
#pragma unroll
    for (int ni = 0; ni < 2; ++ni) bf[ni] = *(sx8*)&ldsW[((wc * 2 + ni) * 64 + lane) * 8];
#pragma unroll
    for (int mi = 0; mi < 2; ++mi)
#pragma unroll
      for (int ni = 0; ni < 2; ++ni) acc[mi][ni] = mfma16(af[mi], bf[ni], acc[mi][ni]);
  }
#pragma unroll
  for (int mi = 0; mi < 2; ++mi) {
    int rbase = row0 + (wr * 2 + mi) * 16 + ((lane >> 4) << 2);
#pragma unroll
    for (int ni = 0; ni < 2; ++ni) {
      int col = col0 + (wc * 2 + ni) * 16 + l16;
      if (col < N) {
        float bv = bias ? bias[col] : 0.f;
#pragma unroll
        for (int r = 0; r < 4; ++r)
          C[(size_t)(rbase + r) * N + col] = acc[mi][ni][r] + bv;
      }
    }
  }
}

// f32 exact GEMM body (student path): 32x32 tile
__device__ inline void gemm_nt32_body(char* smem, int bx, int by,
                                      const float* __restrict__ A,
                                      const float* __restrict__ W,
                                      const float* __restrict__ bias,
                                      float* __restrict__ C, int Mr, int N, int K) {
  float (*As)[33] = (float (*)[33])smem;
  float (*Ws)[33] = (float (*)[33])(smem + 4224);
  const int tid = threadIdx.x;
  const int tx = tid & 15, ty = tid >> 4;
  const int row0 = by * 32;
  const int col0 = bx * 32;
  float acc[2][2] = {{0.f, 0.f}, {0.f, 0.f}};

  for (int k0 = 0; k0 < K; k0 += 32) {
#pragma unroll
    for (int e = tid; e < 32 * 32; e += 256) {
      int r = e / 32, c = e % 32;
      int gr = row0 + r, gc = k0 + c;
      As[r][c] = (gr < Mr && gc < K) ? A[(size_t)gr * K + gc] : 0.f;
    }
#pragma unroll
    for (int e = tid; e < 32 * 32; e += 256) {
      int r = e / 32, c = e % 32;
      int gr = col0 + r, gc = k0 + c;
      Ws[r][c] = (gr < N && gc < K) ? W[(size_t)gr * K + gc] : 0.f;
    }
    __syncthreads();
#pragma unroll
    for (int kk = 0; kk < 32; ++kk) {
      float a[2], wv[2];
#pragma unroll
      for (int i = 0; i < 2; ++i) a[i] = As[ty * 2 + i][kk];
#pragma unroll
      for (int j = 0; j < 2; ++j) wv[j] = Ws[tx * 2 + j][kk];
#pragma unroll
      for (int i = 0; i < 2; ++i)
#pragma unroll
        for (int j = 0; j < 2; ++j) acc[i][j] += a[i] * wv[j];
    }
    __syncthreads();
  }
#pragma unroll
  for (int i = 0; i < 2; ++i) {
    int gr = row0 + ty * 2 + i;
    if (gr >= Mr) continue;
#pragma unroll
    for (int j = 0; j < 2; ++j) {
      int gc = col0 + tx * 2 + j;
      if (gc >= N) continue;
      float v = acc[i][j];
      if (bias) v += bias[gc];
      C[(size_t)gr * N + gc] = v;
    }
  }
}

// batchnorm body (one block per feature)
__device__ inline void bn_body(char* pool, int j,
                               const float* __restrict__ X, float* __restrict__ Y,
                               const float* __restrict__ g, const float* __restrict__ b) {
  const int tid = threadIdx.x;
  float* sf = (float*)pool;
  float vals[2];
  float s = 0.f, s2 = 0.f;
  int idx = 0;
  for (int i = tid; i < B_; i += 256, ++idx) {
    float v = X[(size_t)i * FEAT_ + j];
    vals[idx] = v;
    s += v; s2 += v * v;
  }
  sf[tid] = s; __syncthreads();
  for (int k = 128; k > 0; k >>= 1) { if (tid < k) sf[tid] += sf[tid + k]; __syncthreads(); }
  float mu = sf[0] * (1.f / B_); __syncthreads();
  sf[tid] = s2; __syncthreads();
  for (int k = 128; k > 0; k >>= 1) { if (tid < k) sf[tid] += sf[tid + k]; __syncthreads(); }
  float var = sf[0] * (1.f / B_) - mu * mu;
  float scale = rsqrtf(var + BN_EPS_) * g[j];
  float shift = b[j];
  idx = 0;
  for (int i = tid; i < B_; i += 256, ++idx)
    Y[(size_t)i * FEAT_ + j] = (vals[idx] - mu) * scale + shift;
}

// fused CE(t) + CE(s)+preds + KL body
__device__ inline void ce_kl_body(char* pool, int row,
                                  const float* __restrict__ TL,
                                  const float* __restrict__ SL,
                                  const int* __restrict__ label,
                                  float* __restrict__ acc,
                                  float* __restrict__ preds) {
  const int tid = threadIdx.x;
  const float* tp = TL + (size_t)row * NCLS_;
  const float* sp = SL + (size_t)row * NCLS_;
  float (*red)[256] = (float (*)[256])pool;
  int* ridx = (int*)(pool + 4096);
  float* sxl = (float*)(pool + 5120);

  float tv[3], sv[3];
#pragma unroll
  for (int k = 0; k < 3; ++k) {
    int j = tid + k * 256;
    tv[k] = (j < NCLS_) ? tp[j] : -INFINITY;
    sv[k] = (j < NCLS_) ? sp[j] : -INFINITY;
  }
  float mT = -INFINITY, mS = -INFINITY, sT = 0.f, sS = 0.f;
  int ai = NCLS_;
#pragma unroll
  for (int k = 0; k < 3; ++k) {
    int j = tid + k * 256;
    if (j < NCLS_) {
      mT = fmaxf(mT, tv[k]);
      sT += tv[k]; sS += sv[k];
      if (sv[k] > mS) { mS = sv[k]; ai = j; }
    }
  }
  red[0][tid] = mT; red[1][tid] = mS; red[2][tid] = sT; red[3][tid] = sS; ridx[tid] = ai;
  __syncthreads();
  for (int k = 128; k > 0; k >>= 1) {
    if (tid < k) {
      red[0][tid] = fmaxf(red[0][tid], red[0][tid + k]);
      float om = red[1][tid + k]; int oi = ridx[tid + k];
      if (om > red[1][tid] || (om == red[1][tid] && oi < ridx[tid])) { red[1][tid] = om; ridx[tid] = oi; }
      red[2][tid] += red[2][tid + k];
      red[3][tid] += red[3][tid + k];
    }
    __syncthreads();
  }
  const float MT = red[0][0], MS = red[1][0], sumT = red[2][0], sumS = red[3][0];
  const int amax = ridx[0];
  __syncthreads();
  float etr = 0.f, esr = 0.f, eth = 0.f, esh = 0.f;
#pragma unroll
  for (int k = 0; k < 3; ++k) {
    int j = tid + k * 256;
    if (j < NCLS_) {
      etr += expf(tv[k] - MT);
      esr += expf(sv[k] - MS);
      eth += expf(0.5f * (tv[k] - MT));
      esh += expf(0.5f * (sv[k] - MS));
    }
  }
  red[0][tid] = etr; red[1][tid] = esr; red[2][tid] = eth; red[3][tid] = esh;
  __syncthreads();
  for (int k = 128; k > 0; k >>= 1) {
    if (tid < k) {
      red[0][tid] += red[0][tid + k];
      red[1][tid] += red[1][tid + k];
      red[2][tid] += red[2][tid + k];
      red[3][tid] += red[3][tid + k];
    }
    __syncthreads();
  }
  const float lseT = MT + logf(red[0][0]);
  const float lseS = MS + logf(red[1][0]);
  const float ltH = 0.5f * MT + logf(red[2][0]);
  const float lsH = 0.5f * MS + logf(red[3][0]);
  __syncthreads();
  const int lab = label[row];
  float klp = 0.f;
#pragma unroll
  for (int k = 0; k < 3; ++k) {
    int j = tid + k * 256;
    if (j < NCLS_) {
      float tlp = 0.5f * tv[k] - ltH;
      float slp = 0.5f * sv[k] - lsH;
      klp += expf(tlp) * (tlp - slp);
      if (j == lab) { sxl[0] = tv[k]; sxl[1] = sv[k]; }
    }
  }
  red[0][tid] = klp;
  __syncthreads();
  for (int k = 128; k > 0; k >>= 1) {
    if (tid < k) red[0][tid] += red[0][tid + k];
    __syncthreads();
  }
  if (tid == 0) {
    float ce_t = -((1.f - LS_EPS_) * (sxl[0] - lseT) + (LS_EPS_ / NCLS_) * (sumT - NCLS_ * lseT));
    float ce_s = -((1.f - LS_EPS_) * (sxl[1] - lseS) + (LS_EPS_ / NCLS_) * (sumS - NCLS_ * lseS));
    atomicAdd(acc + 0, ce_t * (1.f / B_));
    atomicAdd(acc + 2, ce_s * (1.f / B_));
    atomicAdd(acc + 4, red[0][0] * (1.f / B_));
    preds[row] = (float)amax;
  }
}

// triplet hard-mining body
__device__ inline void triplet_body(char* pool, int which, int i,
                                    const float* __restrict__ Gt,
                                    const float* __restrict__ Gs,
                                    const int* __restrict__ label,
                                    float* __restrict__ acc) {
  const float* G = which ? Gs : Gt;
  float* a = acc + (which ? 3 : 1);
  const int tid = threadIdx.x;
  const int li = label[i];
  float* sap = (float*)pool;
  float* san = (float*)(pool + 1024);
  const float sqi = G[(size_t)i * B_ + i];
  float ap = -INFINITY, an = INFINITY;
  for (int j = tid; j < B_; j += 256) {
    float sqj = G[(size_t)j * B_ + j];
    float d2 = sqi + sqj - 2.f * G[(size_t)i * B_ + j];
    float d = sqrtf(fmaxf(d2, 1e-12f));
    if (label[j] == li) ap = fmaxf(ap, d); else an = fminf(an, d);
  }
  sap[tid] = ap; san[tid] = an; __syncthreads();
  for (int k = 128; k > 0; k >>= 1) {
    if (tid < k) {
      sap[tid] = fmaxf(sap[tid], sap[tid + k]);
      san[tid] = fminf(san[tid], san[tid + k]);
    }
    __syncthreads();
  }
  if (tid == 0) atomicAdd(a, fmaxf(sap[0] - san[0] + MARGIN_, 0.f) * (1.f / B_));
}

// per-batch Sinkhorn body (bf16 K + K^T in pool LDS)
#define SKLD 88
#define SKTLD 200
__device__ inline void sinkhorn_body(char* pool, int b,
                                     const ushort* __restrict__ sim,
                                     float* __restrict__ acc) {
  const int tid = threadIdx.x;
  ushort* Kb  = (ushort*)pool;               // 34496 B
  ushort* KbT = (ushort*)(pool + 34496);     // 30800 B
  float* r    = (float*)(pool + 65296);      // 784
  float* c    = (float*)(pool + 66080);      // 352
  float* sf   = (float*)(pool + 66432);      // 1024
  float* cs1  = (float*)(pool + 67456);      // 384
  const ushort* simb = sim + (size_t)b * (M_ * N_);
  for (int e = tid; e < 196 * SKLD; e += 256) {
    int m = e / SKLD, n = e - m * SKLD;
    if (n < 77) {
      float sv = bf2f(simb[m * 77 + n]);
      ushort h = f2bf(__expf((sv - 1.f) * 10.f));
      Kb[e] = h;
      KbT[n * SKTLD + m] = h;
    } else Kb[e] = 0;
  }
  if (tid < SKLD) c[tid] = (tid < 77) ? 1.f : 0.f;
  __syncthreads();
  const float uu = 1.f / 196.f, vv = 1.f / 77.f;
  for (int it = 0; it < SINK_ITERS; ++it) {
    if (tid < 196) {
      const ushort* Km = &Kb[tid * SKLD];
      float s = 0.f;
#pragma unroll
      for (int j = 0; j < 11; ++j) {
        fx8 kf = b2f8(*(const sx8*)&Km[j * 8]);
#pragma unroll
        for (int q = 0; q < 8; ++q) s += kf[q] * c[j * 8 + q];
      }
      r[tid] = uu / s;
    }
    __syncthreads();
    if (tid < 154) {
      const int half = (tid >= 77) ? 1 : 0;
      const int n = tid - 77 * half;
      const ushort* Kn = &KbT[n * SKTLD + 96 * half];
      const int m0 = 96 * half;
      float s = 0.f;
#pragma unroll
      for (int j = 0; j < 12; ++j) {
        fx8 kf = b2f8(*(const sx8*)&Kn[j * 8]);
#pragma unroll
        for (int q = 0; q < 8; ++q) s += kf[q] * r[m0 + j * 8 + q];
      }
      if (half) {
        s += bf2f(Kn[96]) * r[192] + bf2f(Kn[97]) * r[193]
           + bf2f(Kn[98]) * r[194] + bf2f(Kn[99]) * r[195];
        cs1[n] = s;
      } else sf[n] = s;
    }
    __syncthreads();
    if (tid < 77) c[tid] = vv / (sf[tid] + cs1[tid]);
    __syncthreads();
  }
  float part = 0.f;
  for (int e = tid; e < M_ * N_; e += 256) {
    int m = e / 77, n = e - m * 77;
    part += r[m] * c[n] * bf2f(Kb[m * SKLD + n]) * bf2f(simb[e]);
  }
  sf[tid] = part; __syncthreads();
  for (int k = 128; k > 0; k >>= 1) { if (tid < k) sf[tid] += sf[tid + k]; __syncthreads(); }
  if (tid == 0) atomicAdd(acc + 5, sf[0] * (1.f / B_));
}

// batched cosine sim body (3-way M-split, norms fused into K-loop, bf16 out)
template<int H>
__device__ void sim_body(int b, const float* __restrict__ S, const ushort* __restrict__ T,
                         ushort* __restrict__ sim, ushort* lds, float* sinv_s, float* tinv_s) {
  constexpr int NTILE = (H == 2) ? 5 : 4;
  constexpr int NS = NTILE * 64;
  constexpr int NC = NS + 320;
  constexpr int M0 = H * 64;
  const int tid = threadIdx.x;
  const int lane = tid & 63;
  const int w = tid >> 6;

  bool val[3], isS[3];
  const float* pS[3];
  const ushort* pT[3];
  int rowi[3], cidx[3];
  bool k0lane[3];
#pragma unroll
  for (int j = 0; j < 3; ++j) {
    int c = tid + j * 256;
    cidx[j] = c;
    val[j] = (c < NC);
    isS[j] = (c < NS);
    k0lane[j] = (((c >> 4) & 3) == 0);
    if (c < NS) {
      int tile = c >> 6;
      int r = M0 + tile * 16 + (c & 15);
      int rr = r < 196 ? r : 195;
      int ks = ((c >> 4) & 3) * 8;
      pS[j] = S + ((size_t)b * M_ + rr) * LDIM_ + ks;
      rowi[j] = rr - M0;
      pT[j] = T;
    } else {
      int cc = c - NS;
      int tile = cc >> 6;
      int r = tile * 16 + (cc & 15);
      int rr = r < 77 ? r : 76;
      int ks = ((cc >> 4) & 3) * 8;
      pT[j] = T + ((size_t)b * N_ + rr) * LDIM_ + ks;
      pS[j] = S;
      rowi[j] = rr;
    }
  }

  fx8 fS[3]; sx8 tS[3];
#pragma unroll
  for (int j = 0; j < 3; ++j) {
    if (!val[j]) continue;
    if (isS[j]) fS[j] = *(const fx8*)pS[j];
    else tS[j] = *(const sx8*)pT[j];
  }

  float ss[3] = {0.f, 0.f, 0.f};
  fx4 acc[2][5];
  const fx4 zz = {0.f, 0.f, 0.f, 0.f};
#pragma unroll
  for (int i = 0; i < 2; ++i)
#pragma unroll
    for (int j = 0; j < 5; ++j) acc[i][j] = zz;

  for (int kt = 0; kt < 18; ++kt) {
    if (kt) __syncthreads();
#pragma unroll
    for (int j = 0; j < 3; ++j) {
      if (!val[j]) continue;
      if (isS[j]) {
        *(sx8*)&lds[cidx[j] * 8] = cvt8(fS[j]);
#pragma unroll
        for (int q = 0; q < 8; ++q) ss[j] += fS[j][q] * fS[j][q];
      } else {
        *(sx8*)&lds[cidx[j] * 8] = tS[j];
        fx8 tf = b2f8(tS[j]);
#pragma unroll
        for (int q = 0; q < 8; ++q) ss[j] += tf[q] * tf[q];
      }
    }
    __syncthreads();
    if (kt < 17) {
      const int ko = (kt + 1) * 32;
#pragma unroll
      for (int j = 0; j < 3; ++j) {
        if (!val[j]) continue;
        if (isS[j]) fS[j] = *(const fx8*)(pS[j] + ko);
        else tS[j] = *(const sx8*)(pT[j] + ko);
      }
    }
    sx8 bfr[5];
#pragma unroll
    for (int ni = 0; ni < 5; ++ni) bfr[ni] = *(sx8*)&lds[(NS + ni * 64 + lane) * 8];
#pragma unroll
    for (int mi = 0; mi < 2; ++mi) {
      int lt = w + mi * 4;
      if (lt < NTILE) {
        sx8 af = *(sx8*)&lds[(lt * 64 + lane) * 8];
#pragma unroll
        for (int ni = 0; ni < 5; ++ni) acc[mi][ni] = mfma16(af, bfr[ni], acc[mi][ni]);
      }
    }
  }

#pragma unroll
  for (int j = 0; j < 3; ++j) {
    if (!val[j]) continue;
    float s = ss[j];
    s += __shfl_xor(s, 16);
    s += __shfl_xor(s, 32);
    if (k0lane[j]) {
      float inv = 1.f / fmaxf(sqrtf(s), 1e-12f);
      if (isS[j]) sinv_s[rowi[j]] = inv;
      else        tinv_s[rowi[j]] = inv;
    }
  }
  __syncthreads();

#pragma unroll
  for (int mi = 0; mi < 2; ++mi) {
    int lt = w + mi * 4;
    if (lt >= NTILE) continue;
    int lrbase = lt * 16 + ((lane >> 4) << 2);
#pragma unroll
    for (int ni = 0; ni < 5; ++ni) {
      int col = ni * 16 + (lane & 15);
      if (col < 77) {
        float tv = tinv_s[col];
#pragma unroll
        for (int r = 0; r < 4; ++r) {
          int lrow = lrbase + r;
          int row = M0 + lrow;
          if (row < 196)
            sim[((size_t)b * M_ + row) * N_ + col] = f2bf(acc[mi][ni][r] * sinv_s[lrow] * tv);
        }
      }
    }
  }
}

// ttext 128x128 GEMM body (m97 structure)
__device__ inline void gemm128_body(char* pool, int bx, int by,
                                    const ushort* __restrict__ A,
                                    const ushort* __restrict__ Bm,
                                    const float* __restrict__ bias,
                                    ushort* __restrict__ C) {
  ushort* ldsA = (ushort*)pool;
  ushort* ldsB = (ushort*)(pool + 8192);
  const int tid = threadIdx.x;
  const int lane = tid & 63;
  const int w = tid >> 6;
  const int wr = w >> 1, wc = w & 1;
  const int row0 = by * 128;
  const int col0 = bx * 128;
  const int l16 = lane & 15, k8 = (lane >> 4) * 8;

  const ushort* gA0 = A + (size_t)(row0 + (2 * w) * 16 + l16) * TDIM_ + k8;
  const ushort* gA1 = A + (size_t)(row0 + (2 * w + 1) * 16 + l16) * TDIM_ + k8;
  const ushort* gB0 = Bm + (size_t)(col0 + (2 * w) * 16 + l16) * TDIM_ + k8;
  const ushort* gB1 = Bm + (size_t)(col0 + (2 * w + 1) * 16 + l16) * TDIM_ + k8;
  ushort* lA0 = &ldsA[(2 * w) * 512];
  ushort* lA1 = &ldsA[(2 * w + 1) * 512];
  ushort* lB0 = &ldsB[(2 * w) * 512];
  ushort* lB1 = &ldsB[(2 * w + 1) * 512];

  fx4 acc[4][4];
  const fx4 zz = {0.f, 0.f, 0.f, 0.f};
#pragma unroll
  for (int i = 0; i < 4; ++i)
#pragma unroll
    for (int j = 0; j < 4; ++j) acc[i][j] = zz;

  for (int kt = 0; kt < 24; ++kt) {
    if (kt) __syncthreads();
    const int ko = kt * 32;
    gload_lds16(gA0 + ko, lA0);
    gload_lds16(gA1 + ko, lA1);
    gload_lds16(gB0 + ko, lB0);
    gload_lds16(gB1 + ko, lB1);
    asm volatile("s_waitcnt vmcnt(0)" ::: "memory");
    __syncthreads();
    sx8 af[4], bf[4];
#pragma unroll
    for (int mi = 0; mi < 4; ++mi) af[mi] = *(sx8*)&ldsA[((wr * 4 + mi) * 64 + lane) * 8];
#pragma unroll
    for (int ni = 0; ni < 4; ++ni) bf[ni] = *(sx8*)&ldsB[((wc * 4 + ni) * 64 + lane) * 8];
#pragma unroll
    for (int mi = 0; mi < 4; ++mi)
#pragma unroll
      for (int ni = 0; ni < 4; ++ni) acc[mi][ni] = mfma16(af[mi], bf[ni], acc[mi][ni]);
  }

#pragma unroll
  for (int mi = 0; mi < 4; ++mi) {
    int rbase = row0 + wr * 64 + mi * 16 + ((lane >> 4) << 2);
#pragma unroll
    for (int ni = 0; ni < 4; ++ni) {
      int col = col0 + wc * 64 + ni * 16 + l16;
      if (col < 576) {
        float bv = bias[col];
#pragma unroll
        for (int r = 0; r < 4; ++r)
          C[(size_t)(rbase + r) * 576 + col] = f2bf(acc[mi][ni][r] + bv);
      }
    }
  }
}

// ===================== merged launch kernels ================================

// LA: stage1 (tlin MFMA + sglob f32) || prep (W cvt + acc zero) || cvt text
__global__ __launch_bounds__(256) void kernel_A(const float* __restrict__ t_img_raw,
                                                const float* __restrict__ W_tv,
                                                const float* __restrict__ b_tv,
                                                float* __restrict__ tlin,
                                                const float* __restrict__ s_glob_raw,
                                                const float* __restrict__ W_sv,
                                                const float* __restrict__ b_sv,
                                                float* __restrict__ sglob,
                                                const float* __restrict__ W_tt,
                                                ushort* __restrict__ Wbuf,
                                                float* __restrict__ acc,
                                                const float* __restrict__ text_feat,
                                                ushort* __restrict__ Abuf) {
  __shared__ __align__(16) char pool[8448];
  const int bid = blockIdx.x;
  const int tid = threadIdx.x;
  if (bid < 64) {
    small_mfma_body(pool, bid & 7, bid >> 3, t_img_raw, W_tv, b_tv, tlin, FEAT_, TDIM_);
  } else if (bid < 320) {
    int i = bid - 64;
    gemm_nt32_body(pool, i & 15, i >> 4, s_glob_raw, W_sv, b_sv, sglob, 512, FEAT_, LDIM_);
  } else if (bid < 561) {
    int pbid = bid - 320;
    if (pbid == 240) {
      if (tid < 8) acc[tid] = 0.f;
      return;
    }
    int i = pbid * 256 + tid;
    int row = i / 96;
    if (row < 576) {
      fx8 f = *(const fx8*)(W_tt + (size_t)i * 8);
      *(sx8*)(Wbuf + (size_t)i * 8) = cvt8(f);
    } else {
      sx8 z = {0, 0, 0, 0, 0, 0, 0, 0};
      *(sx8*)(Wbuf + (size_t)i * 8) = z;
    }
  } else {
    size_t i = (size_t)(bid - 561) * 256 + tid;
    fx8 f = *(const fx8*)(text_feat + i * 8);
    *(sx8*)(Abuf + i * 8) = cvt8(f);
  }
}

// LB: gemm_bf16_128 (XCD-swizzled) || bn
__global__ __launch_bounds__(256) void kernel_B(const ushort* __restrict__ Abuf,
                                                const ushort* __restrict__ Wbuf,
                                                const float* __restrict__ b_tt,
                                                ushort* __restrict__ ttext,
                                                const float* __restrict__ tlin,
                                                float* __restrict__ timg,
                                                const float* __restrict__ bn_g,
                                                const float* __restrict__ bn_b) {
  __shared__ __align__(16) char pool[16384];
  const int bid = blockIdx.x;
  if (bid < 1540) {
    // bijective XCD swizzle: nwg=1540, q=192, r=4
    const int xcd = bid & 7, wi = bid >> 3;
    const int swz = (xcd < 4 ? xcd * 193 : 772 + (xcd - 4) * 192) + wi;
    const int by = swz / 5, bx = swz - by * 5;
    gemm128_body(pool, bx, by, Abuf, Wbuf, b_tt, ttext);
  } else {
    bn_body(pool, bid - 1540, tlin, timg, bn_g, bn_b);
  }
}

// LC: sim (XCD-swizzled) || stage2 (tlog, slog, gram_t, gram_s)
__global__ __launch_bounds__(256) void kernel_C(const float* __restrict__ s_local,
                                                const ushort* __restrict__ ttext,
                                                ushort* __restrict__ sim,
                                                const float* __restrict__ timg,
                                                const float* __restrict__ W_ct,
                                                const float* __restrict__ b_ct,
                                                float* __restrict__ tlog,
                                                const float* __restrict__ sglob,
                                                const float* __restrict__ W_cs,
                                                const float* __restrict__ b_cs,
                                                float* __restrict__ slog,
                                                float* __restrict__ gram_t,
                                                float* __restrict__ gram_s) {
  __shared__ __align__(16) char pool[10880];
  const int bid = blockIdx.x;
  if (bid < 1536) {
    ushort* lds = (ushort*)pool;
    float* sinv_s = (float*)(pool + 10240);
    float* tinv_s = (float*)(pool + 10560);
    const int swz = (bid & 7) * 192 + (bid >> 3);
    const int b = swz / 3;
    const int q = swz - b * 3;
    if (q == 0)      sim_body<0>(b, s_local, ttext, sim, lds, sinv_s, tinv_s);
    else if (q == 1) sim_body<1>(b, s_local, ttext, sim, lds, sinv_s, tinv_s);
    else             sim_body<2>(b, s_local, ttext, sim, lds, sinv_s, tinv_s);
  } else {
    int i = bid - 1536;
    if (i < 80) {
      small_mfma_body(pool, i % 10, i / 10, timg, W_ct, b_ct, tlog, NCLS_, FEAT_);
    } else if (i < 400) {
      int j = i - 80;
      gemm_nt32_body(pool, j % 20, j / 20, sglob, W_cs, b_cs, slog, 512, NCLS_, FEAT_);
    } else if (i < 464) {
      int j = i - 400;
      small_mfma_body(pool, j & 7, j >> 3, timg, timg, nullptr, gram_t, 512, FEAT_);
    } else {
      int j = i - 464;
      small_mfma_body(pool, j & 7, j >> 3, sglob, sglob, nullptr, gram_s, 512, LDIM_);
    }
  }
}

// LD: sinkhorn || ce_kl (+preds) || triplet x2, with device-wide completion
__global__ __launch_bounds__(256) void kernel_D(const ushort* __restrict__ sim,
                                                const float* __restrict__ tlog,
                                                const float* __restrict__ slog,
                                                const float* __restrict__ gram_t,
                                                const float* __restrict__ gram_s,
                                                const int* __restrict__ label,
                                                float* __restrict__ acc,
                                                float* __restrict__ out) {
  __shared__ __align__(16) char pool[67840];
  const int bid = blockIdx.x;
  if (bid < 512) {
    sinkhorn_body(pool, bid, sim, acc);
  } else if (bid < 1024) {
    ce_kl_body(pool, bid - 512, tlog, slog, label, acc, out + 1);
  } else {
    int i = bid - 1024;
    triplet_body(pool, i >> 9, i & 511, gram_t, gram_s, label, acc);
  }
  if (threadIdx.x == 0) {
    __threadfence();
    uint prev = atomicAdd((uint*)(acc + 6), 1u);
    if (prev == 2047u) {
      float a0 = atomicAdd(acc + 0, 0.f);
      float a1 = atomicAdd(acc + 1, 0.f);
      float a2 = atomicAdd(acc + 2, 0.f);
      float a3 = atomicAdd(acc + 3, 0.f);
      float a4 = atomicAdd(acc + 4, 0.f);
      float a5 = atomicAdd(acc + 5, 0.f);
      out[0] = a0 + a1 + a2 + a3 + a4 + (1.f - a5);
    }
  }
}

// ---------------------------------------------------------------------------
extern "C" void kernel_launch(void* const* d_in, const int* in_sizes, int n_in,
                              void* d_out, int out_size, void* d_ws, size_t ws_size,
                              hipStream_t stream) {
  const float* text_feat  = (const float*)d_in[0];
  const float* t_img_raw  = (const float*)d_in[1];
  const float* s_glob_raw = (const float*)d_in[2];
  const float* s_local    = (const float*)d_in[3];
  const int*   label      = (const int*)d_in[4];
  const float* W_tv = (const float*)d_in[5];
  const float* b_tv = (const float*)d_in[6];
  const float* W_tt = (const float*)d_in[7];
  const float* b_tt = (const float*)d_in[8];
  const float* W_sv = (const float*)d_in[9];
  const float* b_sv = (const float*)d_in[10];
  const float* bn_g = (const float*)d_in[11];
  const float* bn_b = (const float*)d_in[12];
  const float* W_ct = (const float*)d_in[13];
  const float* b_ct = (const float*)d_in[14];
  const float* W_cs = (const float*)d_in[15];
  const float* b_cs = (const float*)d_in[16];
  float* out = (float*)d_out;
  float* ws = (float*)d_ws;

  float* tlin   = ws;
  float* timg   = tlin + 262144;
  float* sglob  = timg + 262144;
  float* tlog   = sglob + 262144;
  float* slog   = tlog + 323584;
  float* gram_t = slog + 323584;
  float* gram_s = gram_t + 262144;
  float* acc    = gram_s + 262144;
  ushort* Wbuf  = (ushort*)(acc + 8);
  ushort* ttext = Wbuf + 491520;
  ushort* Abuf  = ttext + 22708224;
  ushort* sim   = Abuf;   // alias; Abuf dead before sim written

  dim3 blk(256);

  // LA: stage1 || prep || cvt
  kernel_A<<<15345, blk, 0, stream>>>(t_img_raw, W_tv, b_tv, tlin,
                                      s_glob_raw, W_sv, b_sv, sglob,
                                      W_tt, Wbuf, acc, text_feat, Abuf);
  // LB: ttext GEMM || bn
  kernel_B<<<2052, blk, 0, stream>>>(Abuf, Wbuf, b_tt, ttext, tlin, timg, bn_g, bn_b);
  // LC: sim || stage2
  kernel_C<<<2064, blk, 0, stream>>>(s_local, ttext, sim,
                                     timg, W_ct, b_ct, tlog,
                                     sglob, W_cs, b_cs, slog, gram_t, gram_s);
  // LD: sinkhorn || ce_kl || triplet, fused finalize
  kernel_D<<<2048, blk, 0, stream>>>(sim, tlog, slog, gram_t, gram_s, label, acc, out);
}